// Round 1
// baseline (8043.074 us; speedup 1.0000x reference)
//
#include <hip/hip_runtime.h>
#include <hip/hip_bf16.h>
#include <math.h>

#define H 8
#define DK 64
#define DIM 512
#define DFF 2048
#define DEPTH 8
#define BB 16
#define LS 128
#define LT 128
#define VOCAB 32000
#define NTOK 2048

// ---------------- embed: out = emb[tok] + pos[pidx] ----------------
__global__ void embed_kernel(const float* __restrict__ emb, const int* __restrict__ tok,
                             const float* __restrict__ pos, const int* __restrict__ pidx,
                             float* __restrict__ out, int n4) {
    int idx = blockIdx.x * blockDim.x + threadIdx.x;
    if (idx >= n4) return;
    int i = idx >> 7, d = idx & 127;  // DIM/4 = 128 float4 per row
    float4 a = ((const float4*)emb)[(size_t)tok[i] * 128 + d];
    float4 b = ((const float4*)pos)[(size_t)pidx[i] * 128 + d];
    ((float4*)out)[idx] = make_float4(a.x + b.x, a.y + b.y, a.z + b.z, a.w + b.w);
}

// ---------------- addpt: out = x + pos[pidx] + time_row ----------------
__global__ void addpt_kernel(const float* __restrict__ x, const float* __restrict__ pos,
                             const int* __restrict__ pidx, const float* __restrict__ trow,
                             float* __restrict__ out, int n4) {
    int idx = blockIdx.x * blockDim.x + threadIdx.x;
    if (idx >= n4) return;
    int i = idx >> 7, d = idx & 127;
    float4 a = ((const float4*)x)[idx];
    float4 b = ((const float4*)pos)[(size_t)pidx[i] * 128 + d];
    float4 c = ((const float4*)trow)[d];
    ((float4*)out)[idx] = make_float4(a.x + b.x + c.x, a.y + b.y + c.y,
                                      a.z + b.z + c.z, a.w + b.w + c.w);
}

// ---------------- GEMM f32: C = A[M,K] @ W[K,N], epilogue variants ----------------
// EPI 0: none; 1: relu; 2: C = R + A@W
// M,N multiples of 64; K multiple of 16 (true for all calls here).
template<int EPI>
__global__ __launch_bounds__(256) void gemm_f32(
    const float* __restrict__ A, const float* __restrict__ W,
    const float* __restrict__ R, float* __restrict__ C,
    int M, int N, int K)
{
    __shared__ float As[16][68];  // [k][m], +4 pad keeps rows 16B-aligned, breaks bank aliasing
    __shared__ float Bs[16][68];  // [k][n]
    const int tid = threadIdx.x;
    const int tx = tid & 15, ty = tid >> 4;
    const int m0 = blockIdx.y * 64, n0 = blockIdx.x * 64;
    float acc[4][4] = {{0.f}};
    for (int k0 = 0; k0 < K; k0 += 16) {
#pragma unroll
        for (int i = 0; i < 4; i++) {
            int idx = tid + i * 256;
            int m = idx >> 4, kk = idx & 15;
            As[kk][m] = A[(size_t)(m0 + m) * K + k0 + kk];
        }
#pragma unroll
        for (int i = 0; i < 4; i++) {
            int idx = tid + i * 256;
            int kk = idx >> 6, n = idx & 63;
            Bs[kk][n] = W[(size_t)(k0 + kk) * N + n0 + n];
        }
        __syncthreads();
#pragma unroll
        for (int kk = 0; kk < 16; kk++) {
            float4 a4 = *(const float4*)&As[kk][ty * 4];
            float4 b4 = *(const float4*)&Bs[kk][tx * 4];
            float av[4] = {a4.x, a4.y, a4.z, a4.w};
            float bv[4] = {b4.x, b4.y, b4.z, b4.w};
#pragma unroll
            for (int i = 0; i < 4; i++)
#pragma unroll
                for (int j = 0; j < 4; j++)
                    acc[i][j] = fmaf(av[i], bv[j], acc[i][j]);
        }
        __syncthreads();
    }
#pragma unroll
    for (int i = 0; i < 4; i++) {
        int row = m0 + ty * 4 + i;
        size_t base = (size_t)row * N + n0 + tx * 4;
        float4 v = make_float4(acc[i][0], acc[i][1], acc[i][2], acc[i][3]);
        if (EPI == 1) {
            v.x = fmaxf(v.x, 0.f); v.y = fmaxf(v.y, 0.f);
            v.z = fmaxf(v.z, 0.f); v.w = fmaxf(v.w, 0.f);
        }
        if (EPI == 2) {
            float4 r = *(const float4*)&R[base];
            v.x += r.x; v.y += r.y; v.z += r.z; v.w += r.w;
        }
        *(float4*)&C[base] = v;
    }
}

// ---------------- attention ----------------
// One block = (batch, head, query-half). 64 threads; thread = one query row.
// Q/K/V base pointers are pre-offset to the right column block (q/k/v section);
// per-head column offset h*64 applied inside. exp without max-subtraction matches
// the reference exactly (scores are small); denominator z + 1e-9 matches too.
__global__ __launch_bounds__(64) void attn_kernel(
    const float* __restrict__ Qb, int ldq,
    const float* __restrict__ Kb, int ldk,
    const float* __restrict__ Vb, int ldv,
    float* __restrict__ O, int causal)
{
    __shared__ float Ks[128][64];
    __shared__ float Vs[128][64];
    const int tid = threadIdx.x;
    const int blk = blockIdx.x;
    const int qhalf = blk & 1;
    const int h = (blk >> 1) & 7;
    const int b = blk >> 4;
    const int q0 = qhalf * 64;
    const int kl = causal ? (q0 + 64) : 128;  // causal: first half only needs 64 keys
    for (int j = 0; j < kl; j++) {
        Ks[j][tid] = Kb[(size_t)(b * 128 + j) * ldk + h * 64 + tid];
        Vs[j][tid] = Vb[(size_t)(b * 128 + j) * ldv + h * 64 + tid];
    }
    __syncthreads();
    const int qi = q0 + tid;
    const int qrow = b * 128 + qi;
    float4 q[16];
    const float4* qp = (const float4*)(Qb + (size_t)qrow * ldq + h * 64);
#pragma unroll
    for (int i = 0; i < 16; i++) q[i] = qp[i];
    float4 acc[16];
#pragma unroll
    for (int i = 0; i < 16; i++) acc[i] = make_float4(0.f, 0.f, 0.f, 0.f);
    float z = 0.f;
    const int jend = causal ? (qi + 1) : kl;
    for (int j = 0; j < jend; j++) {
        float s = 0.f;
#pragma unroll
        for (int i = 0; i < 16; i++) {
            float4 k4 = *(const float4*)&Ks[j][i * 4];
            s += q[i].x * k4.x + q[i].y * k4.y + q[i].z * k4.z + q[i].w * k4.w;
        }
        s = expf(s * 0.125f);
        z += s;
#pragma unroll
        for (int i = 0; i < 16; i++) {
            float4 v4 = *(const float4*)&Vs[j][i * 4];
            acc[i].x += s * v4.x; acc[i].y += s * v4.y;
            acc[i].z += s * v4.z; acc[i].w += s * v4.w;
        }
    }
    const float inv = 1.f / (z + 1e-9f);
    float4* op = (float4*)(O + (size_t)qrow * DIM + h * 64);
#pragma unroll
    for (int i = 0; i < 16; i++)
        op[i] = make_float4(acc[i].x * inv, acc[i].y * inv, acc[i].z * inv, acc[i].w * inv);
}

// ---------------- LayerNorm: out = LN(in), row = 512 ----------------
__global__ __launch_bounds__(64) void ln_kernel(const float* __restrict__ in,
                                                float* __restrict__ out) {
    const int row = blockIdx.x, lane = threadIdx.x;
    const float* p = in + (size_t)row * DIM;
    float x[8];
#pragma unroll
    for (int i = 0; i < 8; i++) x[i] = p[lane + i * 64];
    float s = 0.f;
#pragma unroll
    for (int i = 0; i < 8; i++) s += x[i];
#pragma unroll
    for (int off = 32; off > 0; off >>= 1) s += __shfl_xor(s, off);
    const float m = s * (1.f / 512.f);
    float v = 0.f;
#pragma unroll
    for (int i = 0; i < 8; i++) { float d = x[i] - m; v += d * d; }
#pragma unroll
    for (int off = 32; off > 0; off >>= 1) v += __shfl_xor(v, off);
    v *= (1.f / 512.f);
    const float inv = 1.f / sqrtf(v + 1e-5f);
    float* q = out + (size_t)row * DIM;
#pragma unroll
    for (int i = 0; i < 8; i++) q[lane + i * 64] = (x[i] - m) * inv;
}

// ---------------- row log_softmax over VOCAB, in-place ----------------
__global__ __launch_bounds__(256) void logsoftmax_kernel(float* __restrict__ x) {
    const int row = blockIdx.x, tid = threadIdx.x;
    float* p = x + (size_t)row * VOCAB;
    __shared__ float red[4];
    const int lane = tid & 63, wid = tid >> 6;
    float mx = -1e30f;
    for (int i = tid; i < VOCAB; i += 256) mx = fmaxf(mx, p[i]);
#pragma unroll
    for (int off = 32; off > 0; off >>= 1) mx = fmaxf(mx, __shfl_xor(mx, off));
    if (lane == 0) red[wid] = mx;
    __syncthreads();
    mx = fmaxf(fmaxf(red[0], red[1]), fmaxf(red[2], red[3]));
    float s = 0.f;
    for (int i = tid; i < VOCAB; i += 256) s += expf(p[i] - mx);
#pragma unroll
    for (int off = 32; off > 0; off >>= 1) s += __shfl_xor(s, off);
    __syncthreads();
    if (lane == 0) red[wid] = s;
    __syncthreads();
    const float lse = mx + logf(red[0] + red[1] + red[2] + red[3]);
    for (int i = tid; i < VOCAB; i += 256) p[i] = p[i] - lse;
}

// ---------------- orchestration ----------------
extern "C" void kernel_launch(void* const* d_in, const int* in_sizes, int n_in,
                              void* d_out, int out_size, void* d_ws, size_t ws_size,
                              hipStream_t stream) {
    const float* emb_src  = (const float*)d_in[0];
    const float* emb_tgt  = (const float*)d_in[1];
    const float* pos_emb  = (const float*)d_in[2];
    const float* time_emb = (const float*)d_in[3];
    const float* Wqkv_e   = (const float*)d_in[4];
    const float* Wo_e     = (const float*)d_in[5];
    const float* W1_e     = (const float*)d_in[6];
    const float* W2_e     = (const float*)d_in[7];
    const float* Wqkv_d   = (const float*)d_in[8];
    const float* Wo_d     = (const float*)d_in[9];
    const float* W1_d     = (const float*)d_in[10];
    const float* W2_d     = (const float*)d_in[11];
    const float* Wq_x     = (const float*)d_in[12];
    const float* Wkv_x    = (const float*)d_in[13];
    const float* Wo_x     = (const float*)d_in[14];
    const float* Wgen     = (const float*)d_in[15];
    const int* src_tokens = (const int*)d_in[16];
    const int* tgt_tokens = (const int*)d_in[17];
    const int* src_pos    = (const int*)d_in[18];
    const int* tgt_pos    = (const int*)d_in[19];
    // edge lists d_in[20..25] unused: structure is dense (full / causal / full-cross)

    float* ws = (float*)d_ws;
    const size_t SZ = 1048576;        // 2048*512 floats
    float* x_e = ws;                  // [2048,512]
    float* x_d = ws + SZ;             // [2048,512]
    float* xp  = ws + 2 * SZ;         // [2048,512] scratch
    float* tmp = ws + 3 * SZ;         // [2048,512] scratch
    float* o   = ws + 4 * SZ;         // [2048,512] attention out
    float* big = ws + 5 * SZ;         // [2048,2048] max: qkv [2048,1536] or ffn hidden
    float* kvx = ws + 9 * SZ;         // [2048,1024]
    float* out = (float*)d_out;       // [2048,32000]

    const int n4 = NTOK * (DIM / 4);  // 262144
    dim3 eb(256), eg((n4 + 255) / 256);

    embed_kernel<<<eg, eb, 0, stream>>>(emb_src, src_tokens, pos_emb, src_pos, x_e, n4);
    embed_kernel<<<eg, eb, 0, stream>>>(emb_tgt, tgt_tokens, pos_emb, tgt_pos, x_d, n4);

    // -------- encoder --------
    for (int t = 0; t < DEPTH; t++) {
        const float* trow = time_emb + (size_t)t * DIM;
        addpt_kernel<<<eg, eb, 0, stream>>>(x_e, pos_emb, src_pos, trow, xp, n4);
        gemm_f32<0><<<dim3(1536 / 64, NTOK / 64), 256, 0, stream>>>(xp, Wqkv_e, nullptr, big, NTOK, 1536, DIM);
        attn_kernel<<<256, 64, 0, stream>>>(big, 1536, big + 512, 1536, big + 1024, 1536, o, 0);
        gemm_f32<2><<<dim3(DIM / 64, NTOK / 64), 256, 0, stream>>>(o, Wo_e, x_e, tmp, NTOK, DIM, DIM);
        ln_kernel<<<NTOK, 64, 0, stream>>>(tmp, x_e);
        gemm_f32<1><<<dim3(DFF / 64, NTOK / 64), 256, 0, stream>>>(x_e, W1_e, nullptr, big, NTOK, DFF, DIM);
        gemm_f32<2><<<dim3(DIM / 64, NTOK / 64), 256, 0, stream>>>(big, W2_e, x_e, tmp, NTOK, DIM, DFF);
        ln_kernel<<<NTOK, 64, 0, stream>>>(tmp, x_e);
    }

    // cross-attn K/V from final encoder state (t-invariant -> hoisted)
    gemm_f32<0><<<dim3(1024 / 64, NTOK / 64), 256, 0, stream>>>(x_e, Wkv_x, nullptr, kvx, NTOK, 1024, DIM);

    // -------- decoder --------
    for (int t = 0; t < DEPTH; t++) {
        const float* trow = time_emb + (size_t)t * DIM;
        // self-attn (causal)
        addpt_kernel<<<eg, eb, 0, stream>>>(x_d, pos_emb, tgt_pos, trow, xp, n4);
        gemm_f32<0><<<dim3(1536 / 64, NTOK / 64), 256, 0, stream>>>(xp, Wqkv_d, nullptr, big, NTOK, 1536, DIM);
        attn_kernel<<<256, 64, 0, stream>>>(big, 1536, big + 512, 1536, big + 1024, 1536, o, 1);
        gemm_f32<2><<<dim3(DIM / 64, NTOK / 64), 256, 0, stream>>>(o, Wo_d, x_d, tmp, NTOK, DIM, DIM);
        ln_kernel<<<NTOK, 64, 0, stream>>>(tmp, x_d);
        // cross-attn
        addpt_kernel<<<eg, eb, 0, stream>>>(x_d, pos_emb, tgt_pos, trow, xp, n4);
        gemm_f32<0><<<dim3(DIM / 64, NTOK / 64), 256, 0, stream>>>(xp, Wq_x, nullptr, tmp, NTOK, DIM, DIM);
        attn_kernel<<<256, 64, 0, stream>>>(tmp, DIM, kvx, 1024, kvx + 512, 1024, o, 0);
        gemm_f32<2><<<dim3(DIM / 64, NTOK / 64), 256, 0, stream>>>(o, Wo_x, x_d, xp, NTOK, DIM, DIM);
        ln_kernel<<<NTOK, 64, 0, stream>>>(xp, x_d);
        // FFN
        gemm_f32<1><<<dim3(DFF / 64, NTOK / 64), 256, 0, stream>>>(x_d, W1_d, nullptr, big, NTOK, DFF, DIM);
        gemm_f32<2><<<dim3(DIM / 64, NTOK / 64), 256, 0, stream>>>(big, W2_d, x_d, tmp, NTOK, DIM, DFF);
        ln_kernel<<<NTOK, 64, 0, stream>>>(tmp, x_d);
    }

    // -------- generator --------
    gemm_f32<0><<<dim3(VOCAB / 64, NTOK / 64), 256, 0, stream>>>(x_d, Wgen, nullptr, out, NTOK, VOCAB, DIM);
    logsoftmax_kernel<<<NTOK, 256, 0, stream>>>(out);
}

// Round 2
// 4078.074 us; speedup vs baseline: 1.9723x; 1.9723x over previous
//
#include <hip/hip_runtime.h>
#include <hip/hip_bf16.h>
#include <math.h>

#define H 8
#define DK 64
#define DIM 512
#define DFF 2048
#define DEPTH 8
#define BB 16
#define VOCAB 32000
#define NTOK 2048

typedef float f32x4 __attribute__((ext_vector_type(4)));
typedef short bf16x8 __attribute__((ext_vector_type(8)));

static __device__ __forceinline__ unsigned short f2bf(float f) {
    unsigned u = __float_as_uint(f);
    return (unsigned short)((u + 0x7FFFu + ((u >> 16) & 1u)) >> 16);
}

// ---------------- embed: out = emb[tok] + pos[pidx] (f32) ----------------
__global__ void embed_kernel(const float* __restrict__ emb, const int* __restrict__ tok,
                             const float* __restrict__ pos, const int* __restrict__ pidx,
                             float* __restrict__ out, int n4) {
    int idx = blockIdx.x * blockDim.x + threadIdx.x;
    if (idx >= n4) return;
    int i = idx >> 7, d = idx & 127;
    float4 a = ((const float4*)emb)[(size_t)tok[i] * 128 + d];
    float4 b = ((const float4*)pos)[(size_t)pidx[i] * 128 + d];
    ((float4*)out)[idx] = make_float4(a.x + b.x, a.y + b.y, a.z + b.z, a.w + b.w);
}

// ---------------- addpt: out_bf16 = x + pos[pidx] + time_row ----------------
__global__ void addpt_kernel(const float* __restrict__ x, const float* __restrict__ pos,
                             const int* __restrict__ pidx, const float* __restrict__ trow,
                             unsigned short* __restrict__ out, int n4) {
    int idx = blockIdx.x * blockDim.x + threadIdx.x;
    if (idx >= n4) return;
    int i = idx >> 7, d = idx & 127;
    float4 a = ((const float4*)x)[idx];
    float4 b = ((const float4*)pos)[(size_t)pidx[i] * 128 + d];
    float4 c = ((const float4*)trow)[d];
    ushort4 o;
    o.x = f2bf(a.x + b.x + c.x); o.y = f2bf(a.y + b.y + c.y);
    o.z = f2bf(a.z + b.z + c.z); o.w = f2bf(a.w + b.w + c.w);
    ((ushort4*)out)[idx] = o;
}

// ---------------- weight convert+transpose: Wt[n][k] = bf16(W[k][n]) ----------------
__global__ __launch_bounds__(256) void wconv_kernel(const float* __restrict__ W,
                                                    unsigned short* __restrict__ Wt,
                                                    int K, int N) {
    __shared__ float t[32][33];
    const int tid = threadIdx.x;
    const int tx = tid & 31, ty = tid >> 5;
    const int n0 = blockIdx.x * 32, k0 = blockIdx.y * 32;
#pragma unroll
    for (int i = 0; i < 32; i += 8)
        t[ty + i][tx] = W[(size_t)(k0 + ty + i) * N + n0 + tx];
    __syncthreads();
#pragma unroll
    for (int i = 0; i < 32; i += 8)
        Wt[(size_t)(n0 + ty + i) * K + k0 + tx] = f2bf(t[tx][ty + i]);
}

// ---------------- bf16 MFMA GEMM: C = A[M,K] @ Bt[N,K]^T ----------------
// 128x128 tile, BK=64, 4 waves (each 64x64 via 4x4 frags of 16x16x32 MFMA).
// Staging: global_load_lds 16B with source-side XOR chunk swizzle (chunk^=row&7)
// so ds_read_b128 fragment reads hit <=2 lanes per 16B slot.
// EPI 0: f32 store; 1: relu -> bf16 store; 2: (+R) f32 store.
template<int EPI>
__global__ __launch_bounds__(256) void gemm_bf16(
    const unsigned short* __restrict__ A,   // [M,K] bf16
    const unsigned short* __restrict__ Bt,  // [N,K] bf16
    const float* __restrict__ R,
    float* __restrict__ Cf,
    unsigned short* __restrict__ Cb,
    int M, int N, int K)
{
    __shared__ __align__(16) unsigned short Asm[128 * 64];
    __shared__ __align__(16) unsigned short Bsm[128 * 64];
    const int tid = threadIdx.x;
    const int lane = tid & 63, wid = tid >> 6;
    const int m0 = blockIdx.y * 128, n0 = blockIdx.x * 128;
    const int wm = (wid >> 1) * 64, wn = (wid & 1) * 64;

    f32x4 acc[4][4];
#pragma unroll
    for (int i = 0; i < 4; i++)
#pragma unroll
        for (int j = 0; j < 4; j++)
            acc[i][j] = (f32x4){0.f, 0.f, 0.f, 0.f};

    for (int k0 = 0; k0 < K; k0 += 64) {
        if (k0) __syncthreads();
#pragma unroll
        for (int it = 0; it < 4; it++) {
            int q = (wid * 4 + it) * 64 + lane;   // linear 16B chunk id, [0,1024)
            int row = q >> 3;
            int cs = (q & 7) ^ (row & 7);          // inverse-swizzled source chunk
            const unsigned short* srcA = A + (size_t)(m0 + row) * K + k0 + cs * 8;
            const unsigned short* srcB = Bt + (size_t)(n0 + row) * K + k0 + cs * 8;
            __builtin_amdgcn_global_load_lds(
                (const __attribute__((address_space(1))) unsigned int*)srcA,
                (__attribute__((address_space(3))) unsigned int*)&Asm[(wid * 4 + it) * 512],
                16, 0, 0);
            __builtin_amdgcn_global_load_lds(
                (const __attribute__((address_space(1))) unsigned int*)srcB,
                (__attribute__((address_space(3))) unsigned int*)&Bsm[(wid * 4 + it) * 512],
                16, 0, 0);
        }
        __syncthreads();
#pragma unroll
        for (int kk = 0; kk < 2; kk++) {
            bf16x8 af[4], bfr[4];
#pragma unroll
            for (int i = 0; i < 4; i++) {
                int rowA = wm + i * 16 + (lane & 15);
                int ca = (kk * 4 + (lane >> 4)) ^ (rowA & 7);
                af[i] = *(const bf16x8*)&Asm[rowA * 64 + ca * 8];
                int rowB = wn + i * 16 + (lane & 15);
                int cb = (kk * 4 + (lane >> 4)) ^ (rowB & 7);
                bfr[i] = *(const bf16x8*)&Bsm[rowB * 64 + cb * 8];
            }
#pragma unroll
            for (int i = 0; i < 4; i++)
#pragma unroll
                for (int j = 0; j < 4; j++)
                    acc[i][j] = __builtin_amdgcn_mfma_f32_16x16x32_bf16(af[i], bfr[j], acc[i][j], 0, 0, 0);
        }
    }
    // epilogue: D col = lane&15 (n), row = (lane>>4)*4 + r (m)  [m89-verified]
#pragma unroll
    for (int i = 0; i < 4; i++) {
#pragma unroll
        for (int j = 0; j < 4; j++) {
#pragma unroll
            for (int r = 0; r < 4; r++) {
                int row = m0 + wm + i * 16 + (lane >> 4) * 4 + r;
                int col = n0 + wn + j * 16 + (lane & 15);
                size_t idx = (size_t)row * N + col;
                float v = acc[i][j][r];
                if (EPI == 0) Cf[idx] = v;
                if (EPI == 1) Cb[idx] = f2bf(fmaxf(v, 0.f));
                if (EPI == 2) Cf[idx] = v + R[idx];
            }
        }
    }
}

// ---------------- attention (f32 in, bf16 out) ----------------
__global__ __launch_bounds__(64) void attn_kernel(
    const float* __restrict__ Qb, int ldq,
    const float* __restrict__ Kb, int ldk,
    const float* __restrict__ Vb, int ldv,
    unsigned short* __restrict__ O, int causal)
{
    __shared__ float Ks[128][64];
    __shared__ float Vs[128][64];
    const int tid = threadIdx.x;
    const int blk = blockIdx.x;
    const int qhalf = blk & 1;
    const int h = (blk >> 1) & 7;
    const int b = blk >> 4;
    const int q0 = qhalf * 64;
    const int kl = causal ? (q0 + 64) : 128;
    for (int j = 0; j < kl; j++) {
        Ks[j][tid] = Kb[(size_t)(b * 128 + j) * ldk + h * 64 + tid];
        Vs[j][tid] = Vb[(size_t)(b * 128 + j) * ldv + h * 64 + tid];
    }
    __syncthreads();
    const int qi = q0 + tid;
    const int qrow = b * 128 + qi;
    float4 q[16];
    const float4* qp = (const float4*)(Qb + (size_t)qrow * ldq + h * 64);
#pragma unroll
    for (int i = 0; i < 16; i++) q[i] = qp[i];
    float4 acc[16];
#pragma unroll
    for (int i = 0; i < 16; i++) acc[i] = make_float4(0.f, 0.f, 0.f, 0.f);
    float z = 0.f;
    const int jend = causal ? (qi + 1) : kl;
    for (int j = 0; j < jend; j++) {
        float s = 0.f;
#pragma unroll
        for (int i = 0; i < 16; i++) {
            float4 k4 = *(const float4*)&Ks[j][i * 4];
            s += q[i].x * k4.x + q[i].y * k4.y + q[i].z * k4.z + q[i].w * k4.w;
        }
        s = expf(s * 0.125f);
        z += s;
#pragma unroll
        for (int i = 0; i < 16; i++) {
            float4 v4 = *(const float4*)&Vs[j][i * 4];
            acc[i].x += s * v4.x; acc[i].y += s * v4.y;
            acc[i].z += s * v4.z; acc[i].w += s * v4.w;
        }
    }
    const float inv = 1.f / (z + 1e-9f);
    unsigned short* op = O + (size_t)qrow * DIM + h * 64;
#pragma unroll
    for (int i = 0; i < 16; i++) {
        ushort4 o4;
        o4.x = f2bf(acc[i].x * inv); o4.y = f2bf(acc[i].y * inv);
        o4.z = f2bf(acc[i].z * inv); o4.w = f2bf(acc[i].w * inv);
        *(ushort4*)&op[i * 4] = o4;
    }
}

// ---------------- LayerNorm: f32 out + bf16 out ----------------
__global__ __launch_bounds__(64) void ln_kernel(const float* __restrict__ in,
                                                float* __restrict__ out,
                                                unsigned short* __restrict__ outb) {
    const int row = blockIdx.x, lane = threadIdx.x;
    const float* p = in + (size_t)row * DIM;
    float x[8];
#pragma unroll
    for (int i = 0; i < 8; i++) x[i] = p[lane + i * 64];
    float s = 0.f;
#pragma unroll
    for (int i = 0; i < 8; i++) s += x[i];
#pragma unroll
    for (int off = 32; off > 0; off >>= 1) s += __shfl_xor(s, off);
    const float m = s * (1.f / 512.f);
    float v = 0.f;
#pragma unroll
    for (int i = 0; i < 8; i++) { float d = x[i] - m; v += d * d; }
#pragma unroll
    for (int off = 32; off > 0; off >>= 1) v += __shfl_xor(v, off);
    v *= (1.f / 512.f);
    const float inv = 1.f / sqrtf(v + 1e-5f);
    float* q = out + (size_t)row * DIM;
    unsigned short* qb = outb + (size_t)row * DIM;
#pragma unroll
    for (int i = 0; i < 8; i++) {
        float y = (x[i] - m) * inv;
        q[lane + i * 64] = y;
        qb[lane + i * 64] = f2bf(y);
    }
}

// ---------------- row log_softmax over VOCAB, in-place, online 2-pass ----------------
__global__ __launch_bounds__(256) void logsoftmax_kernel(float* __restrict__ x) {
    const int row = blockIdx.x, tid = threadIdx.x;
    float* p = x + (size_t)row * VOCAB;
    const int lane = tid & 63, wid = tid >> 6;
    float m = -1e30f, s = 0.f;
    for (int i = tid; i < VOCAB; i += 256) {
        float v = p[i];
        float M = fmaxf(m, v);
        s = s * expf(m - M) + expf(v - M);
        m = M;
    }
#pragma unroll
    for (int off = 32; off > 0; off >>= 1) {
        float mo = __shfl_xor(m, off), so = __shfl_xor(s, off);
        float M = fmaxf(m, mo);
        s = s * expf(m - M) + so * expf(mo - M);
        m = M;
    }
    __shared__ float ms[4], ss[4];
    if (lane == 0) { ms[wid] = m; ss[wid] = s; }
    __syncthreads();
    float M = fmaxf(fmaxf(ms[0], ms[1]), fmaxf(ms[2], ms[3]));
    float S = ss[0] * expf(ms[0] - M) + ss[1] * expf(ms[1] - M) +
              ss[2] * expf(ms[2] - M) + ss[3] * expf(ms[3] - M);
    const float lse = M + logf(S);
    for (int i = tid; i < VOCAB; i += 256) p[i] -= lse;
}

// ---------------- orchestration ----------------
extern "C" void kernel_launch(void* const* d_in, const int* in_sizes, int n_in,
                              void* d_out, int out_size, void* d_ws, size_t ws_size,
                              hipStream_t stream) {
    const float* emb_src  = (const float*)d_in[0];
    const float* emb_tgt  = (const float*)d_in[1];
    const float* pos_emb  = (const float*)d_in[2];
    const float* time_emb = (const float*)d_in[3];
    const float* Wqkv_e   = (const float*)d_in[4];
    const float* Wo_e     = (const float*)d_in[5];
    const float* W1_e     = (const float*)d_in[6];
    const float* W2_e     = (const float*)d_in[7];
    const float* Wqkv_d   = (const float*)d_in[8];
    const float* Wo_d     = (const float*)d_in[9];
    const float* W1_d     = (const float*)d_in[10];
    const float* W2_d     = (const float*)d_in[11];
    const float* Wq_x     = (const float*)d_in[12];
    const float* Wkv_x    = (const float*)d_in[13];
    const float* Wo_x     = (const float*)d_in[14];
    const float* Wgen     = (const float*)d_in[15];
    const int* src_tokens = (const int*)d_in[16];
    const int* tgt_tokens = (const int*)d_in[17];
    const int* src_pos    = (const int*)d_in[18];
    const int* tgt_pos    = (const int*)d_in[19];

    char* w = (char*)d_ws;
    float* x_e = (float*)(w);                               // 4MB
    float* x_d = (float*)(w + (4u << 20));                  // 4MB
    float* tmp = (float*)(w + (8u << 20));                  // 4MB
    float* big = (float*)(w + (12u << 20));                 // 12MB (qkv out / wo_x out)
    float* kvx = (float*)(w + (24u << 20));                 // 8MB
    unsigned short* xp_bf  = (unsigned short*)(w + (32u << 20));  // 2MB
    unsigned short* o_bf   = (unsigned short*)(w + (34u << 20));  // 2MB
    unsigned short* xe_bf  = (unsigned short*)(w + (36u << 20));  // 2MB
    unsigned short* xd_bf  = (unsigned short*)(w + (38u << 20));  // 2MB
    unsigned short* hid_bf = (unsigned short*)(w + (40u << 20));  // 8MB
    unsigned short* wts    = (unsigned short*)(w + (48u << 20));  // ~47.4MB of bf16 weights

    unsigned short* WqkvE_t = wts;                 // [1536,512]
    unsigned short* WoE_t   = WqkvE_t + 786432;    // [512,512]
    unsigned short* W1E_t   = WoE_t   + 262144;    // [2048,512]
    unsigned short* W2E_t   = W1E_t   + 1048576;   // [512,2048]
    unsigned short* WqkvD_t = W2E_t   + 1048576;   // [1536,512]
    unsigned short* WoD_t   = WqkvD_t + 786432;    // [512,512]
    unsigned short* W1D_t   = WoD_t   + 262144;    // [2048,512]
    unsigned short* W2D_t   = W1D_t   + 1048576;   // [512,2048]
    unsigned short* WqX_t   = W2D_t   + 1048576;   // [512,512]
    unsigned short* WkvX_t  = WqX_t   + 262144;    // [1024,512]
    unsigned short* WoX_t   = WkvX_t  + 524288;    // [512,512]
    unsigned short* Wgen_t  = WoX_t   + 262144;    // [32000,512]

    float* out = (float*)d_out;

    // ---- weight conversion (once per launch; deterministic) ----
    wconv_kernel<<<dim3(1536 / 32, 512 / 32),  256, 0, stream>>>(Wqkv_e, WqkvE_t, 512, 1536);
    wconv_kernel<<<dim3(512 / 32,  512 / 32),  256, 0, stream>>>(Wo_e,   WoE_t,   512, 512);
    wconv_kernel<<<dim3(2048 / 32, 512 / 32),  256, 0, stream>>>(W1_e,   W1E_t,   512, 2048);
    wconv_kernel<<<dim3(512 / 32,  2048 / 32), 256, 0, stream>>>(W2_e,   W2E_t,   2048, 512);
    wconv_kernel<<<dim3(1536 / 32, 512 / 32),  256, 0, stream>>>(Wqkv_d, WqkvD_t, 512, 1536);
    wconv_kernel<<<dim3(512 / 32,  512 / 32),  256, 0, stream>>>(Wo_d,   WoD_t,   512, 512);
    wconv_kernel<<<dim3(2048 / 32, 512 / 32),  256, 0, stream>>>(W1_d,   W1D_t,   512, 2048);
    wconv_kernel<<<dim3(512 / 32,  2048 / 32), 256, 0, stream>>>(W2_d,   W2D_t,   2048, 512);
    wconv_kernel<<<dim3(512 / 32,  512 / 32),  256, 0, stream>>>(Wq_x,   WqX_t,   512, 512);
    wconv_kernel<<<dim3(1024 / 32, 512 / 32),  256, 0, stream>>>(Wkv_x,  WkvX_t,  512, 1024);
    wconv_kernel<<<dim3(512 / 32,  512 / 32),  256, 0, stream>>>(Wo_x,   WoX_t,   512, 512);
    wconv_kernel<<<dim3(32000 / 32, 512 / 32), 256, 0, stream>>>(Wgen,   Wgen_t,  512, 32000);

    const int n4 = NTOK * (DIM / 4);
    dim3 eb(256), eg((n4 + 255) / 256);
    embed_kernel<<<eg, eb, 0, stream>>>(emb_src, src_tokens, pos_emb, src_pos, x_e, n4);
    embed_kernel<<<eg, eb, 0, stream>>>(emb_tgt, tgt_tokens, pos_emb, tgt_pos, x_d, n4);

    const dim3 gQKV(1536 / 128, NTOK / 128), g512(512 / 128, NTOK / 128),
               gFF(DFF / 128, NTOK / 128),  gKV(1024 / 128, NTOK / 128),
               gGEN(VOCAB / 128, NTOK / 128);

    // -------- encoder --------
    for (int t = 0; t < DEPTH; t++) {
        const float* trow = time_emb + (size_t)t * DIM;
        addpt_kernel<<<eg, eb, 0, stream>>>(x_e, pos_emb, src_pos, trow, xp_bf, n4);
        gemm_bf16<0><<<gQKV, 256, 0, stream>>>(xp_bf, WqkvE_t, nullptr, big, nullptr, NTOK, 1536, 512);
        attn_kernel<<<256, 64, 0, stream>>>(big, 1536, big + 512, 1536, big + 1024, 1536, o_bf, 0);
        gemm_bf16<2><<<g512, 256, 0, stream>>>(o_bf, WoE_t, x_e, tmp, nullptr, NTOK, 512, 512);
        ln_kernel<<<NTOK, 64, 0, stream>>>(tmp, x_e, xe_bf);
        gemm_bf16<1><<<gFF, 256, 0, stream>>>(xe_bf, W1E_t, nullptr, nullptr, hid_bf, NTOK, DFF, 512);
        gemm_bf16<2><<<g512, 256, 0, stream>>>(hid_bf, W2E_t, x_e, tmp, nullptr, NTOK, 512, DFF);
        ln_kernel<<<NTOK, 64, 0, stream>>>(tmp, x_e, xe_bf);
    }

    // cross-attn K/V from final encoder state (t-invariant, hoisted)
    gemm_bf16<0><<<gKV, 256, 0, stream>>>(xe_bf, WkvX_t, nullptr, kvx, nullptr, NTOK, 1024, 512);

    // -------- decoder --------
    for (int t = 0; t < DEPTH; t++) {
        const float* trow = time_emb + (size_t)t * DIM;
        addpt_kernel<<<eg, eb, 0, stream>>>(x_d, pos_emb, tgt_pos, trow, xp_bf, n4);
        gemm_bf16<0><<<gQKV, 256, 0, stream>>>(xp_bf, WqkvD_t, nullptr, big, nullptr, NTOK, 1536, 512);
        attn_kernel<<<256, 64, 0, stream>>>(big, 1536, big + 512, 1536, big + 1024, 1536, o_bf, 1);
        gemm_bf16<2><<<g512, 256, 0, stream>>>(o_bf, WoD_t, x_d, tmp, nullptr, NTOK, 512, 512);
        ln_kernel<<<NTOK, 64, 0, stream>>>(tmp, x_d, xd_bf);

        addpt_kernel<<<eg, eb, 0, stream>>>(x_d, pos_emb, tgt_pos, trow, xp_bf, n4);
        gemm_bf16<0><<<g512, 256, 0, stream>>>(xp_bf, WqX_t, nullptr, tmp, nullptr, NTOK, 512, 512);
        attn_kernel<<<256, 64, 0, stream>>>(tmp, 512, kvx, 1024, kvx + 512, 1024, o_bf, 0);
        gemm_bf16<2><<<g512, 256, 0, stream>>>(o_bf, WoX_t, x_d, big, nullptr, NTOK, 512, 512);
        ln_kernel<<<NTOK, 64, 0, stream>>>(big, x_d, xd_bf);

        gemm_bf16<1><<<gFF, 256, 0, stream>>>(xd_bf, W1D_t, nullptr, nullptr, hid_bf, NTOK, DFF, 512);
        gemm_bf16<2><<<g512, 256, 0, stream>>>(hid_bf, W2D_t, x_d, tmp, nullptr, NTOK, 512, DFF);
        ln_kernel<<<NTOK, 64, 0, stream>>>(tmp, x_d, xd_bf);
    }

    // -------- generator --------
    gemm_bf16<0><<<gGEN, 256, 0, stream>>>(xd_bf, Wgen_t, nullptr, out, nullptr, NTOK, VOCAB, 512);
    logsoftmax_kernel<<<NTOK, 256, 0, stream>>>(out);
}

// Round 3
// 2511.264 us; speedup vs baseline: 3.2028x; 1.6239x over previous
//
#include <hip/hip_runtime.h>
#include <hip/hip_bf16.h>
#include <math.h>

#define H 8
#define DK 64
#define DIM 512
#define DFF 2048
#define DEPTH 8
#define VOCAB 32000
#define NTOK 2048

typedef float f32x4 __attribute__((ext_vector_type(4)));
typedef short bf16x8 __attribute__((ext_vector_type(8)));

static __device__ __forceinline__ unsigned short f2bf(float f) {
    unsigned u = __float_as_uint(f);
    return (unsigned short)((u + 0x7FFFu + ((u >> 16) & 1u)) >> 16);
}

// ---------------- embed ----------------
__global__ void embed_kernel(const float* __restrict__ emb, const int* __restrict__ tok,
                             const float* __restrict__ pos, const int* __restrict__ pidx,
                             float* __restrict__ out, int n4) {
    int idx = blockIdx.x * blockDim.x + threadIdx.x;
    if (idx >= n4) return;
    int i = idx >> 7, d = idx & 127;
    float4 a = ((const float4*)emb)[(size_t)tok[i] * 128 + d];
    float4 b = ((const float4*)pos)[(size_t)pidx[i] * 128 + d];
    ((float4*)out)[idx] = make_float4(a.x + b.x, a.y + b.y, a.z + b.z, a.w + b.w);
}

// ---------------- addpt: bf16(x + pos + time) ----------------
__global__ void addpt_kernel(const float* __restrict__ x, const float* __restrict__ pos,
                             const int* __restrict__ pidx, const float* __restrict__ trow,
                             unsigned short* __restrict__ out, int n4) {
    int idx = blockIdx.x * blockDim.x + threadIdx.x;
    if (idx >= n4) return;
    int i = idx >> 7, d = idx & 127;
    float4 a = ((const float4*)x)[idx];
    float4 b = ((const float4*)pos)[(size_t)pidx[i] * 128 + d];
    float4 c = ((const float4*)trow)[d];
    ushort4 o;
    o.x = f2bf(a.x + b.x + c.x); o.y = f2bf(a.y + b.y + c.y);
    o.z = f2bf(a.z + b.z + c.z); o.w = f2bf(a.w + b.w + c.w);
    ((ushort4*)out)[idx] = o;
}

// ---------------- weight convert+transpose ----------------
__global__ __launch_bounds__(256) void wconv_kernel(const float* __restrict__ W,
                                                    unsigned short* __restrict__ Wt,
                                                    int K, int N) {
    __shared__ float t[32][33];
    const int tid = threadIdx.x;
    const int tx = tid & 31, ty = tid >> 5;
    const int n0 = blockIdx.x * 32, k0 = blockIdx.y * 32;
#pragma unroll
    for (int i = 0; i < 32; i += 8)
        t[ty + i][tx] = W[(size_t)(k0 + ty + i) * N + n0 + tx];
    __syncthreads();
#pragma unroll
    for (int i = 0; i < 32; i += 8)
        Wt[(size_t)(n0 + ty + i) * K + k0 + tx] = f2bf(t[tx][ty + i]);
}

// ---------------- bf16 MFMA GEMM: C = A[M,K] @ Bt[N,K]^T ----------------
// EPI 0: f32; 1: relu->bf16; 2: f32 + R; 3: bf16
template<int EPI>
__global__ __launch_bounds__(256) void gemm_bf16(
    const unsigned short* __restrict__ A,
    const unsigned short* __restrict__ Bt,
    const float* __restrict__ R,
    float* __restrict__ Cf,
    unsigned short* __restrict__ Cb,
    int M, int N, int K)
{
    __shared__ __align__(16) unsigned short Asm[128 * 64];
    __shared__ __align__(16) unsigned short Bsm[128 * 64];
    const int tid = threadIdx.x;
    const int lane = tid & 63, wid = tid >> 6;
    const int m0 = blockIdx.y * 128, n0 = blockIdx.x * 128;
    const int wm = (wid >> 1) * 64, wn = (wid & 1) * 64;

    f32x4 acc[4][4];
#pragma unroll
    for (int i = 0; i < 4; i++)
#pragma unroll
        for (int j = 0; j < 4; j++)
            acc[i][j] = (f32x4){0.f, 0.f, 0.f, 0.f};

    for (int k0 = 0; k0 < K; k0 += 64) {
        if (k0) __syncthreads();
#pragma unroll
        for (int it = 0; it < 4; it++) {
            int q = (wid * 4 + it) * 64 + lane;
            int row = q >> 3;
            int cs = (q & 7) ^ (row & 7);
            const unsigned short* srcA = A + (size_t)(m0 + row) * K + k0 + cs * 8;
            const unsigned short* srcB = Bt + (size_t)(n0 + row) * K + k0 + cs * 8;
            __builtin_amdgcn_global_load_lds(
                (const __attribute__((address_space(1))) unsigned int*)srcA,
                (__attribute__((address_space(3))) unsigned int*)&Asm[(wid * 4 + it) * 512],
                16, 0, 0);
            __builtin_amdgcn_global_load_lds(
                (const __attribute__((address_space(1))) unsigned int*)srcB,
                (__attribute__((address_space(3))) unsigned int*)&Bsm[(wid * 4 + it) * 512],
                16, 0, 0);
        }
        __syncthreads();
#pragma unroll
        for (int kk = 0; kk < 2; kk++) {
            bf16x8 af[4], bfr[4];
#pragma unroll
            for (int i = 0; i < 4; i++) {
                int rowA = wm + i * 16 + (lane & 15);
                int ca = (kk * 4 + (lane >> 4)) ^ (rowA & 7);
                af[i] = *(const bf16x8*)&Asm[rowA * 64 + ca * 8];
                int rowB = wn + i * 16 + (lane & 15);
                int cb = (kk * 4 + (lane >> 4)) ^ (rowB & 7);
                bfr[i] = *(const bf16x8*)&Bsm[rowB * 64 + cb * 8];
            }
#pragma unroll
            for (int i = 0; i < 4; i++)
#pragma unroll
                for (int j = 0; j < 4; j++)
                    acc[i][j] = __builtin_amdgcn_mfma_f32_16x16x32_bf16(af[i], bfr[j], acc[i][j], 0, 0, 0);
        }
    }
#pragma unroll
    for (int i = 0; i < 4; i++) {
#pragma unroll
        for (int j = 0; j < 4; j++) {
#pragma unroll
            for (int r = 0; r < 4; r++) {
                int row = m0 + wm + i * 16 + (lane >> 4) * 4 + r;
                int col = n0 + wn + j * 16 + (lane & 15);
                size_t idx = (size_t)row * N + col;
                float v = acc[i][j][r];
                if (EPI == 0) Cf[idx] = v;
                if (EPI == 1) Cb[idx] = f2bf(fmaxf(v, 0.f));
                if (EPI == 2) Cf[idx] = v + R[idx];
                if (EPI == 3) Cb[idx] = f2bf(v);
            }
        }
    }
}

// ---------------- MFMA attention ----------------
// block = (b,h); 4 waves x 32 q-rows. Q/K/V bf16, strides ldq/ldk/ldv.
// S = Q K^T via mfma (K staged swizzled in LDS), softmax = raw exp (matches ref),
// P -> bf16 -> per-wave swizzled LDS, O = P V via mfma (V transpose-staged, padded).
// K-dim split into two 64-wide blocks to bound LDS & registers.
template<int CAUSAL>
__global__ __launch_bounds__(256) void attn_mfma(
    const unsigned short* __restrict__ Qb, int ldq,
    const unsigned short* __restrict__ Kb, int ldk,
    const unsigned short* __restrict__ Vb, int ldv,
    unsigned short* __restrict__ O)
{
    __shared__ __align__(16) unsigned short Ks[128 * 64];   // 16 KB, chunk-swizzled
    __shared__ __align__(16) unsigned short Vt[64 * 132];   // 16.5 KB, V^T padded (132 -> bank-clean)
    __shared__ __align__(16) unsigned short Ps[4][32 * 64]; // 16 KB, per-wave P (k-block of 64)
    const int tid = threadIdx.x;
    const int lane = tid & 63, wid = tid >> 6;
    const int b = blockIdx.x >> 3, h = blockIdx.x & 7;
    const int tok0 = b * 128;
    const int wq = wid * 32;

    // ---- stage K (swizzled) and V^T ----
    {
        const unsigned short* Kg = Kb + (size_t)tok0 * ldk + h * 64;
        const unsigned short* Vg = Vb + (size_t)tok0 * ldv + h * 64;
        int r = tid >> 1, cb = (tid & 1) * 4;
#pragma unroll
        for (int c = cb; c < cb + 4; c++) {
            bf16x8 kv = *(const bf16x8*)&Kg[(size_t)r * ldk + c * 8];
            *(bf16x8*)&Ks[r * 64 + ((c ^ (r & 7)) * 8)] = kv;
            bf16x8 vv = *(const bf16x8*)&Vg[(size_t)r * ldv + c * 8];
#pragma unroll
            for (int j = 0; j < 8; j++)
                Vt[(c * 8 + j) * 132 + r] = (unsigned short)vv[j];
        }
    }

    // ---- Q fragments direct from global ----
    bf16x8 qa[2][2];
    {
        const unsigned short* Qg = Qb + (size_t)tok0 * ldq + h * 64;
#pragma unroll
        for (int i = 0; i < 2; i++)
#pragma unroll
            for (int kd = 0; kd < 2; kd++) {
                int qr = wq + i * 16 + (lane & 15);
                qa[i][kd] = *(const bf16x8*)&Qg[(size_t)qr * ldq + kd * 32 + (lane >> 4) * 8];
            }
    }
    __syncthreads();

    const int jmax = CAUSAL ? ((wq >> 4) + 2) : 8;   // # 16-wide k tiles needed
    const int kcmax = CAUSAL ? ((wq >> 5) + 1) : 4;  // # 32-wide k chunks needed (== jmax*16/32)

    float zr[2][4];
#pragma unroll
    for (int i = 0; i < 2; i++)
#pragma unroll
        for (int rr = 0; rr < 4; rr++) zr[i][rr] = 0.f;

    f32x4 oacc[2][4];
#pragma unroll
    for (int i = 0; i < 2; i++)
#pragma unroll
        for (int dt = 0; dt < 4; dt++) oacc[i][dt] = (f32x4){0.f, 0.f, 0.f, 0.f};

    for (int kb = 0; kb < 2; kb++) {
        int j0 = kb * 4;
        if (j0 >= jmax) break;
        int jn = jmax - j0; if (jn > 4) jn = 4;
        // ---- QK^T for this k-block ----
        f32x4 sacc[2][4];
#pragma unroll
        for (int i = 0; i < 2; i++)
#pragma unroll
            for (int j = 0; j < 4; j++) sacc[i][j] = (f32x4){0.f, 0.f, 0.f, 0.f};
#pragma unroll 2
        for (int kd = 0; kd < 2; kd++) {
            for (int jj = 0; jj < jn; jj++) {
                int kr = (j0 + jj) * 16 + (lane & 15);
                int ch = (kd * 4 + (lane >> 4)) ^ (kr & 7);
                bf16x8 kf = *(const bf16x8*)&Ks[kr * 64 + ch * 8];
                sacc[0][jj] = __builtin_amdgcn_mfma_f32_16x16x32_bf16(qa[0][kd], kf, sacc[0][jj], 0, 0, 0);
                sacc[1][jj] = __builtin_amdgcn_mfma_f32_16x16x32_bf16(qa[1][kd], kf, sacc[1][jj], 0, 0, 0);
            }
        }
        // ---- softmax (raw exp), mask, z-accumulate, pack P->LDS ----
#pragma unroll
        for (int i = 0; i < 2; i++) {
            int qbase = wq + i * 16 + (lane >> 4) * 4;
            for (int jj = 0; jj < jn; jj++) {
                int kcol = (j0 + jj) * 16 + (lane & 15);
#pragma unroll
                for (int rr = 0; rr < 4; rr++) {
                    float p = __expf(sacc[i][jj][rr] * 0.125f);
                    if (CAUSAL && kcol > qbase + rr) p = 0.f;
                    zr[i][rr] += p;
                    int prow = i * 16 + (lane >> 4) * 4 + rr;
                    int ch = ((jj * 2 + ((lane & 15) >> 3)) ^ (prow & 7));
                    Ps[wid][prow * 64 + ch * 8 + (lane & 7)] = f2bf(p);
                }
            }
        }
        // ---- PV for this k-block ----
        int kcn = kcmax - kb * 2; if (kcn > 2) kcn = 2;
        for (int kcl = 0; kcl < kcn; kcl++) {
            bf16x8 pa[2];
#pragma unroll
            for (int i = 0; i < 2; i++) {
                int prow = i * 16 + (lane & 15);
                int ch = (kcl * 4 + (lane >> 4)) ^ (prow & 7);
                pa[i] = *(const bf16x8*)&Ps[wid][prow * 64 + ch * 8];
            }
            int kcg = kb * 2 + kcl;
#pragma unroll
            for (int dt = 0; dt < 4; dt++) {
                int d = dt * 16 + (lane & 15);
                bf16x8 vf = *(const bf16x8*)&Vt[d * 132 + (kcg * 4 + (lane >> 4)) * 8];
                oacc[0][dt] = __builtin_amdgcn_mfma_f32_16x16x32_bf16(pa[0], vf, oacc[0][dt], 0, 0, 0);
                oacc[1][dt] = __builtin_amdgcn_mfma_f32_16x16x32_bf16(pa[1], vf, oacc[1][dt], 0, 0, 0);
            }
        }
    }
    // ---- z wave-group reduce (across the 16 lanes sharing a row-group) ----
#pragma unroll
    for (int i = 0; i < 2; i++)
#pragma unroll
        for (int rr = 0; rr < 4; rr++) {
            float z = zr[i][rr];
            z += __shfl_xor(z, 1); z += __shfl_xor(z, 2);
            z += __shfl_xor(z, 4); z += __shfl_xor(z, 8);
            zr[i][rr] = 1.f / (z + 1e-9f);
        }
    // ---- store O ----
#pragma unroll
    for (int i = 0; i < 2; i++)
#pragma unroll
        for (int dt = 0; dt < 4; dt++)
#pragma unroll
            for (int rr = 0; rr < 4; rr++) {
                int qrow = tok0 + wq + i * 16 + (lane >> 4) * 4 + rr;
                O[(size_t)qrow * DIM + h * 64 + dt * 16 + (lane & 15)] =
                    f2bf(oacc[i][dt][rr] * zr[i][rr]);
            }
}

// ---------------- LayerNorm ----------------
__global__ __launch_bounds__(64) void ln_kernel(const float* __restrict__ in,
                                                float* __restrict__ out,
                                                unsigned short* __restrict__ outb) {
    const int row = blockIdx.x, lane = threadIdx.x;
    const float* p = in + (size_t)row * DIM;
    float x[8];
#pragma unroll
    for (int i = 0; i < 8; i++) x[i] = p[lane + i * 64];
    float s = 0.f;
#pragma unroll
    for (int i = 0; i < 8; i++) s += x[i];
#pragma unroll
    for (int off = 32; off > 0; off >>= 1) s += __shfl_xor(s, off);
    const float m = s * (1.f / 512.f);
    float v = 0.f;
#pragma unroll
    for (int i = 0; i < 8; i++) { float d = x[i] - m; v += d * d; }
#pragma unroll
    for (int off = 32; off > 0; off >>= 1) v += __shfl_xor(v, off);
    v *= (1.f / 512.f);
    const float inv = 1.f / sqrtf(v + 1e-5f);
    float* q = out + (size_t)row * DIM;
    unsigned short* qb = outb + (size_t)row * DIM;
#pragma unroll
    for (int i = 0; i < 8; i++) {
        float y = (x[i] - m) * inv;
        q[lane + i * 64] = y;
        qb[lane + i * 64] = f2bf(y);
    }
}

// ---------------- log_softmax (vectorized online) ----------------
__global__ __launch_bounds__(256) void logsoftmax_kernel(float* __restrict__ x) {
    const int row = blockIdx.x, tid = threadIdx.x;
    float* p = x + (size_t)row * VOCAB;
    const float4* p4 = (const float4*)p;
    float m = -1e30f, s = 0.f;
    for (int i = tid; i < VOCAB / 4; i += 256) {
        float4 v = p4[i];
        float vm = fmaxf(fmaxf(v.x, v.y), fmaxf(v.z, v.w));
        if (vm > m) { s *= __expf(m - vm); m = vm; }
        s += __expf(v.x - m) + __expf(v.y - m) + __expf(v.z - m) + __expf(v.w - m);
    }
#pragma unroll
    for (int off = 32; off > 0; off >>= 1) {
        float mo = __shfl_xor(m, off), so = __shfl_xor(s, off);
        float M = fmaxf(m, mo);
        s = s * __expf(m - M) + so * __expf(mo - M);
        m = M;
    }
    __shared__ float ms[4], ss[4];
    const int lane = tid & 63, wid = tid >> 6;
    if (lane == 0) { ms[wid] = m; ss[wid] = s; }
    __syncthreads();
    float M = fmaxf(fmaxf(ms[0], ms[1]), fmaxf(ms[2], ms[3]));
    float S = ss[0] * __expf(ms[0] - M) + ss[1] * __expf(ms[1] - M) +
              ss[2] * __expf(ms[2] - M) + ss[3] * __expf(ms[3] - M);
    const float lse = M + __logf(S);
    float4* q4 = (float4*)p;
    for (int i = tid; i < VOCAB / 4; i += 256) {
        float4 v = q4[i];
        q4[i] = make_float4(v.x - lse, v.y - lse, v.z - lse, v.w - lse);
    }
}

// ---------------- orchestration ----------------
extern "C" void kernel_launch(void* const* d_in, const int* in_sizes, int n_in,
                              void* d_out, int out_size, void* d_ws, size_t ws_size,
                              hipStream_t stream) {
    const float* emb_src  = (const float*)d_in[0];
    const float* emb_tgt  = (const float*)d_in[1];
    const float* pos_emb  = (const float*)d_in[2];
    const float* time_emb = (const float*)d_in[3];
    const float* Wqkv_e   = (const float*)d_in[4];
    const float* Wo_e     = (const float*)d_in[5];
    const float* W1_e     = (const float*)d_in[6];
    const float* W2_e     = (const float*)d_in[7];
    const float* Wqkv_d   = (const float*)d_in[8];
    const float* Wo_d     = (const float*)d_in[9];
    const float* W1_d     = (const float*)d_in[10];
    const float* W2_d     = (const float*)d_in[11];
    const float* Wq_x     = (const float*)d_in[12];
    const float* Wkv_x    = (const float*)d_in[13];
    const float* Wo_x     = (const float*)d_in[14];
    const float* Wgen     = (const float*)d_in[15];
    const int* src_tokens = (const int*)d_in[16];
    const int* tgt_tokens = (const int*)d_in[17];
    const int* src_pos    = (const int*)d_in[18];
    const int* tgt_pos    = (const int*)d_in[19];

    char* w = (char*)d_ws;
    float* x_e = (float*)(w);                                     // 4MB
    float* x_d = (float*)(w + (4u << 20));                        // 4MB
    float* tmp = (float*)(w + (8u << 20));                        // 4MB
    float* big = (float*)(w + (12u << 20));                       // 4MB
    unsigned short* qkv_bf = (unsigned short*)(w + (16u << 20));  // 6MB [2048,1536]
    unsigned short* kvx_bf = (unsigned short*)(w + (22u << 20));  // 4MB [2048,1024]
    unsigned short* xp_bf  = (unsigned short*)(w + (26u << 20));  // 2MB
    unsigned short* o_bf   = (unsigned short*)(w + (28u << 20));  // 2MB
    unsigned short* xe_bf  = (unsigned short*)(w + (30u << 20));  // 2MB
    unsigned short* xd_bf  = (unsigned short*)(w + (32u << 20));  // 2MB
    unsigned short* q_bf   = (unsigned short*)(w + (34u << 20));  // 2MB
    unsigned short* hid_bf = (unsigned short*)(w + (36u << 20));  // 8MB
    unsigned short* wts    = (unsigned short*)(w + (44u << 20));  // ~47.4MB

    unsigned short* WqkvE_t = wts;
    unsigned short* WoE_t   = WqkvE_t + 786432;
    unsigned short* W1E_t   = WoE_t   + 262144;
    unsigned short* W2E_t   = W1E_t   + 1048576;
    unsigned short* WqkvD_t = W2E_t   + 1048576;
    unsigned short* WoD_t   = WqkvD_t + 786432;
    unsigned short* W1D_t   = WoD_t   + 262144;
    unsigned short* W2D_t   = W1D_t   + 1048576;
    unsigned short* WqX_t   = W2D_t   + 1048576;
    unsigned short* WkvX_t  = WqX_t   + 262144;
    unsigned short* WoX_t   = WkvX_t  + 524288;
    unsigned short* Wgen_t  = WoX_t   + 262144;

    float* out = (float*)d_out;

    wconv_kernel<<<dim3(1536 / 32, 512 / 32),  256, 0, stream>>>(Wqkv_e, WqkvE_t, 512, 1536);
    wconv_kernel<<<dim3(512 / 32,  512 / 32),  256, 0, stream>>>(Wo_e,   WoE_t,   512, 512);
    wconv_kernel<<<dim3(2048 / 32, 512 / 32),  256, 0, stream>>>(W1_e,   W1E_t,   512, 2048);
    wconv_kernel<<<dim3(512 / 32,  2048 / 32), 256, 0, stream>>>(W2_e,   W2E_t,   2048, 512);
    wconv_kernel<<<dim3(1536 / 32, 512 / 32),  256, 0, stream>>>(Wqkv_d, WqkvD_t, 512, 1536);
    wconv_kernel<<<dim3(512 / 32,  512 / 32),  256, 0, stream>>>(Wo_d,   WoD_t,   512, 512);
    wconv_kernel<<<dim3(2048 / 32, 512 / 32),  256, 0, stream>>>(W1_d,   W1D_t,   512, 2048);
    wconv_kernel<<<dim3(512 / 32,  2048 / 32), 256, 0, stream>>>(W2_d,   W2D_t,   2048, 512);
    wconv_kernel<<<dim3(512 / 32,  512 / 32),  256, 0, stream>>>(Wq_x,   WqX_t,   512, 512);
    wconv_kernel<<<dim3(1024 / 32, 512 / 32),  256, 0, stream>>>(Wkv_x,  WkvX_t,  512, 1024);
    wconv_kernel<<<dim3(512 / 32,  512 / 32),  256, 0, stream>>>(Wo_x,   WoX_t,   512, 512);
    wconv_kernel<<<dim3(32000 / 32, 512 / 32), 256, 0, stream>>>(Wgen,   Wgen_t,  512, 32000);

    const int n4 = NTOK * (DIM / 4);
    dim3 eb(256), eg((n4 + 255) / 256);
    embed_kernel<<<eg, eb, 0, stream>>>(emb_src, src_tokens, pos_emb, src_pos, x_e, n4);
    embed_kernel<<<eg, eb, 0, stream>>>(emb_tgt, tgt_tokens, pos_emb, tgt_pos, x_d, n4);

    const dim3 gQKV(1536 / 128, NTOK / 128), g512(512 / 128, NTOK / 128),
               gFF(DFF / 128, NTOK / 128),  gKV(1024 / 128, NTOK / 128),
               gGEN(VOCAB / 128, NTOK / 128);

    // -------- encoder --------
    for (int t = 0; t < DEPTH; t++) {
        const float* trow = time_emb + (size_t)t * DIM;
        addpt_kernel<<<eg, eb, 0, stream>>>(x_e, pos_emb, src_pos, trow, xp_bf, n4);
        gemm_bf16<3><<<gQKV, 256, 0, stream>>>(xp_bf, WqkvE_t, nullptr, nullptr, qkv_bf, NTOK, 1536, 512);
        attn_mfma<0><<<128, 256, 0, stream>>>(qkv_bf, 1536, qkv_bf + 512, 1536, qkv_bf + 1024, 1536, o_bf);
        gemm_bf16<2><<<g512, 256, 0, stream>>>(o_bf, WoE_t, x_e, tmp, nullptr, NTOK, 512, 512);
        ln_kernel<<<NTOK, 64, 0, stream>>>(tmp, x_e, xe_bf);
        gemm_bf16<1><<<gFF, 256, 0, stream>>>(xe_bf, W1E_t, nullptr, nullptr, hid_bf, NTOK, DFF, 512);
        gemm_bf16<2><<<g512, 256, 0, stream>>>(hid_bf, W2E_t, x_e, tmp, nullptr, NTOK, 512, DFF);
        ln_kernel<<<NTOK, 64, 0, stream>>>(tmp, x_e, xe_bf);
    }

    // cross-attn K/V from final encoder state (hoisted)
    gemm_bf16<3><<<gKV, 256, 0, stream>>>(xe_bf, WkvX_t, nullptr, nullptr, kvx_bf, NTOK, 1024, 512);

    // -------- decoder --------
    for (int t = 0; t < DEPTH; t++) {
        const float* trow = time_emb + (size_t)t * DIM;
        addpt_kernel<<<eg, eb, 0, stream>>>(x_d, pos_emb, tgt_pos, trow, xp_bf, n4);
        gemm_bf16<3><<<gQKV, 256, 0, stream>>>(xp_bf, WqkvD_t, nullptr, nullptr, qkv_bf, NTOK, 1536, 512);
        attn_mfma<1><<<128, 256, 0, stream>>>(qkv_bf, 1536, qkv_bf + 512, 1536, qkv_bf + 1024, 1536, o_bf);
        gemm_bf16<2><<<g512, 256, 0, stream>>>(o_bf, WoD_t, x_d, tmp, nullptr, NTOK, 512, 512);
        ln_kernel<<<NTOK, 64, 0, stream>>>(tmp, x_d, xd_bf);

        addpt_kernel<<<eg, eb, 0, stream>>>(x_d, pos_emb, tgt_pos, trow, xp_bf, n4);
        gemm_bf16<3><<<g512, 256, 0, stream>>>(xp_bf, WqX_t, nullptr, nullptr, q_bf, NTOK, 512, 512);
        attn_mfma<0><<<128, 256, 0, stream>>>(q_bf, 512, kvx_bf, 1024, kvx_bf + 512, 1024, o_bf);
        gemm_bf16<2><<<g512, 256, 0, stream>>>(o_bf, WoX_t, x_d, big, nullptr, NTOK, 512, 512);
        ln_kernel<<<NTOK, 64, 0, stream>>>(big, x_d, xd_bf);

        gemm_bf16<1><<<gFF, 256, 0, stream>>>(xd_bf, W1D_t, nullptr, nullptr, hid_bf, NTOK, DFF, 512);
        gemm_bf16<2><<<g512, 256, 0, stream>>>(hid_bf, W2D_t, x_d, tmp, nullptr, NTOK, 512, DFF);
        ln_kernel<<<NTOK, 64, 0, stream>>>(tmp, x_d, xd_bf);
    }

    // -------- generator --------
    gemm_bf16<0><<<gGEN, 256, 0, stream>>>(xd_bf, Wgen_t, nullptr, out, nullptr, NTOK, VOCAB, 512);
    logsoftmax_kernel<<<NTOK, 256, 0, stream>>>(out);
}

// Round 4
// 2420.973 us; speedup vs baseline: 3.3222x; 1.0373x over previous
//
#include <hip/hip_runtime.h>
#include <hip/hip_bf16.h>
#include <math.h>

#define H 8
#define DK 64
#define DIM 512
#define DFF 2048
#define DEPTH 8
#define VOCAB 32000
#define NTOK 2048

typedef float f32x4 __attribute__((ext_vector_type(4)));
typedef short bf16x8 __attribute__((ext_vector_type(8)));

static __device__ __forceinline__ unsigned short f2bf(float f) {
    unsigned u = __float_as_uint(f);
    return (unsigned short)((u + 0x7FFFu + ((u >> 16) & 1u)) >> 16);
}

// ---------------- embed ----------------
__global__ void embed_kernel(const float* __restrict__ emb, const int* __restrict__ tok,
                             const float* __restrict__ pos, const int* __restrict__ pidx,
                             float* __restrict__ out, int n4) {
    int idx = blockIdx.x * blockDim.x + threadIdx.x;
    if (idx >= n4) return;
    int i = idx >> 7, d = idx & 127;
    float4 a = ((const float4*)emb)[(size_t)tok[i] * 128 + d];
    float4 b = ((const float4*)pos)[(size_t)pidx[i] * 128 + d];
    ((float4*)out)[idx] = make_float4(a.x + b.x, a.y + b.y, a.z + b.z, a.w + b.w);
}

// ---------------- batched weight convert+transpose ----------------
struct WD { const float* src; unsigned short* dst; int K; int N; int t0; int pad; };
struct WTab { WD d[12]; };

__global__ __launch_bounds__(256) void wconv_all(WTab tab) {
    __shared__ float t[32][33];
    const int bid = blockIdx.x;
    int w = 0;
#pragma unroll
    for (int i = 1; i < 12; i++) if (bid >= tab.d[i].t0) w = i;
    const float* W = tab.d[w].src;
    unsigned short* Wt = tab.d[w].dst;
    const int K = tab.d[w].K, N = tab.d[w].N;
    const int lt = bid - tab.d[w].t0;
    const int txc = N >> 5;
    const int n0 = (lt % txc) << 5, k0 = (lt / txc) << 5;
    const int tid = threadIdx.x;
    const int tx = tid & 31, ty = tid >> 5;
#pragma unroll
    for (int i = 0; i < 32; i += 8)
        t[ty + i][tx] = W[(size_t)(k0 + ty + i) * N + n0 + tx];
    __syncthreads();
#pragma unroll
    for (int i = 0; i < 32; i += 8)
        Wt[(size_t)(n0 + ty + i) * K + k0 + tx] = f2bf(t[tx][ty + i]);
}

// ---------------- unified bf16 MFMA GEMM: C = A' @ Bt^T ----------------
// AMODE 1: A f32 [M,K], converted to bf16 during reg-staging.
// AMODE 2: A f32 + pos[row&127] + trow, converted during staging (fused addpt).
// EPI 0: f32 store; 1: relu->bf16; 3: bf16.
// 128x128 tile, BK=64, 4 waves. B staged via global_load_lds w/ source XOR swizzle.
template<int AMODE, int EPI>
__global__ __launch_bounds__(256) void gemm_u(
    const float* __restrict__ Af,
    const unsigned short* __restrict__ Bt,
    float* __restrict__ Cf,
    unsigned short* __restrict__ Cb,
    const float* __restrict__ pos,
    const float* __restrict__ trow,
    int M, int N, int K)
{
    __shared__ __align__(16) unsigned short Asm[128 * 64];
    __shared__ __align__(16) unsigned short Bsm[128 * 64];
    const int tid = threadIdx.x;
    const int lane = tid & 63, wid = tid >> 6;
    const int m0 = blockIdx.y * 128, n0 = blockIdx.x * 128;
    const int wm = (wid >> 1) * 64, wn = (wid & 1) * 64;

    f32x4 acc[4][4];
#pragma unroll
    for (int i = 0; i < 4; i++)
#pragma unroll
        for (int j = 0; j < 4; j++)
            acc[i][j] = (f32x4){0.f, 0.f, 0.f, 0.f};

    for (int k0 = 0; k0 < K; k0 += 64) {
        if (k0) __syncthreads();
        // B async direct-to-LDS
#pragma unroll
        for (int it = 0; it < 4; it++) {
            int q = (wid * 4 + it) * 64 + lane;
            int row = q >> 3;
            int cs = (q & 7) ^ (row & 7);
            const unsigned short* srcB = Bt + (size_t)(n0 + row) * K + k0 + cs * 8;
            __builtin_amdgcn_global_load_lds(
                (const __attribute__((address_space(1))) unsigned int*)srcB,
                (__attribute__((address_space(3))) unsigned int*)&Bsm[(wid * 4 + it) * 512],
                16, 0, 0);
        }
        // A reg-stage: f32 -> bf16 (+pos+time for AMODE2), swizzled ds_write
#pragma unroll
        for (int it = 0; it < 4; it++) {
            int q = (wid * 4 + it) * 64 + lane;
            int row = q >> 3;
            int cs = q & 7;
            const float* s = Af + (size_t)(m0 + row) * K + k0 + cs * 8;
            float4 u0 = *(const float4*)s, u1 = *(const float4*)(s + 4);
            if (AMODE == 2) {
                const float* pp = pos + (size_t)((m0 + row) & 127) * DIM + k0 + cs * 8;
                const float* tt = trow + k0 + cs * 8;
                float4 p0 = *(const float4*)pp, p1 = *(const float4*)(pp + 4);
                float4 t0 = *(const float4*)tt, t1 = *(const float4*)(tt + 4);
                u0.x += p0.x + t0.x; u0.y += p0.y + t0.y; u0.z += p0.z + t0.z; u0.w += p0.w + t0.w;
                u1.x += p1.x + t1.x; u1.y += p1.y + t1.y; u1.z += p1.z + t1.z; u1.w += p1.w + t1.w;
            }
            unsigned short c8[8];
            c8[0] = f2bf(u0.x); c8[1] = f2bf(u0.y); c8[2] = f2bf(u0.z); c8[3] = f2bf(u0.w);
            c8[4] = f2bf(u1.x); c8[5] = f2bf(u1.y); c8[6] = f2bf(u1.z); c8[7] = f2bf(u1.w);
            *(bf16x8*)&Asm[row * 64 + ((cs ^ (row & 7)) * 8)] = *(bf16x8*)c8;
        }
        __syncthreads();
#pragma unroll
        for (int kk = 0; kk < 2; kk++) {
            bf16x8 af[4], bfr[4];
#pragma unroll
            for (int i = 0; i < 4; i++) {
                int rowA = wm + i * 16 + (lane & 15);
                int ca = (kk * 4 + (lane >> 4)) ^ (rowA & 7);
                af[i] = *(const bf16x8*)&Asm[rowA * 64 + ca * 8];
                int rowB = wn + i * 16 + (lane & 15);
                int cb = (kk * 4 + (lane >> 4)) ^ (rowB & 7);
                bfr[i] = *(const bf16x8*)&Bsm[rowB * 64 + cb * 8];
            }
#pragma unroll
            for (int i = 0; i < 4; i++)
#pragma unroll
                for (int j = 0; j < 4; j++)
                    acc[i][j] = __builtin_amdgcn_mfma_f32_16x16x32_bf16(af[i], bfr[j], acc[i][j], 0, 0, 0);
        }
    }
#pragma unroll
    for (int i = 0; i < 4; i++) {
#pragma unroll
        for (int j = 0; j < 4; j++) {
#pragma unroll
            for (int r = 0; r < 4; r++) {
                int row = m0 + wm + i * 16 + (lane >> 4) * 4 + r;
                int col = n0 + wn + j * 16 + (lane & 15);
                size_t idx = (size_t)row * N + col;
                float v = acc[i][j][r];
                if (EPI == 0) Cf[idx] = v;
                if (EPI == 1) Cb[idx] = f2bf(fmaxf(v, 0.f));
                if (EPI == 3) Cb[idx] = f2bf(v);
            }
        }
    }
}

// ---------------- fused GEMM + residual + LayerNorm (in-place on X) ----------------
// X = LN(X + A @ Bt^T).  N fixed = 512 (full row per block). BM=32, 8 waves.
// Wave w computes rows 0..31 x cols [w*64, w*64+64). LN via cross-wave LDS reduce.
__global__ __launch_bounds__(512) void gemm_ln(
    const unsigned short* __restrict__ A,   // [M,K] bf16
    const unsigned short* __restrict__ Bt,  // [512,K] bf16
    float* __restrict__ X,                  // [M,512] residual in, LN out
    int K)
{
    __shared__ __align__(16) unsigned short Bsm[512 * 64];  // 64KB
    __shared__ __align__(16) unsigned short Asm[32 * 64];   // 4KB
    __shared__ float red[8][32];
    __shared__ float red2[8][32];
    const int tid = threadIdx.x;
    const int lane = tid & 63, wid = tid >> 6;
    const int m0 = blockIdx.x * 32;

    f32x4 acc[2][4];
#pragma unroll
    for (int i = 0; i < 2; i++)
#pragma unroll
        for (int j = 0; j < 4; j++) acc[i][j] = (f32x4){0.f, 0.f, 0.f, 0.f};

    for (int k0 = 0; k0 < K; k0 += 64) {
        if (k0) __syncthreads();
        if (wid < 4) {
            int q = wid * 64 + lane;
            int row = q >> 3;
            int cs = (q & 7) ^ (row & 7);
            const unsigned short* srcA = A + (size_t)(m0 + row) * K + k0 + cs * 8;
            __builtin_amdgcn_global_load_lds(
                (const __attribute__((address_space(1))) unsigned int*)srcA,
                (__attribute__((address_space(3))) unsigned int*)&Asm[(wid * 64) * 8],
                16, 0, 0);
        }
#pragma unroll
        for (int it = 0; it < 8; it++) {
            int q = it * 512 + tid;
            int row = q >> 3;
            int cs = (q & 7) ^ (row & 7);
            const unsigned short* srcB = Bt + (size_t)row * K + k0 + cs * 8;
            __builtin_amdgcn_global_load_lds(
                (const __attribute__((address_space(1))) unsigned int*)srcB,
                (__attribute__((address_space(3))) unsigned int*)&Bsm[(it * 512 + wid * 64) * 8],
                16, 0, 0);
        }
        __syncthreads();
#pragma unroll
        for (int kd = 0; kd < 2; kd++) {
            bf16x8 af[2], bfr[4];
#pragma unroll
            for (int i = 0; i < 2; i++) {
                int rowA = i * 16 + (lane & 15);
                int ca = (kd * 4 + (lane >> 4)) ^ (rowA & 7);
                af[i] = *(const bf16x8*)&Asm[rowA * 64 + ca * 8];
            }
#pragma unroll
            for (int j = 0; j < 4; j++) {
                int rowB = wid * 64 + j * 16 + (lane & 15);
                int cb = (kd * 4 + (lane >> 4)) ^ (rowB & 7);
                bfr[j] = *(const bf16x8*)&Bsm[rowB * 64 + cb * 8];
            }
#pragma unroll
            for (int i = 0; i < 2; i++)
#pragma unroll
                for (int j = 0; j < 4; j++)
                    acc[i][j] = __builtin_amdgcn_mfma_f32_16x16x32_bf16(af[i], bfr[j], acc[i][j], 0, 0, 0);
        }
    }
    // ---- epilogue: v = acc + X (residual); two-pass LN over the 512-wide row ----
#pragma unroll
    for (int i = 0; i < 2; i++)
#pragma unroll
        for (int j = 0; j < 4; j++)
#pragma unroll
            for (int r = 0; r < 4; r++) {
                int row = m0 + i * 16 + (lane >> 4) * 4 + r;
                int col = wid * 64 + j * 16 + (lane & 15);
                acc[i][j][r] += X[(size_t)row * DIM + col];
            }
    // mean
    float ps[2][4];
#pragma unroll
    for (int i = 0; i < 2; i++)
#pragma unroll
        for (int r = 0; r < 4; r++) {
            float s = acc[i][0][r] + acc[i][1][r] + acc[i][2][r] + acc[i][3][r];
            s += __shfl_xor(s, 1); s += __shfl_xor(s, 2);
            s += __shfl_xor(s, 4); s += __shfl_xor(s, 8);
            ps[i][r] = s;
        }
    if ((lane & 15) == 0)
#pragma unroll
        for (int i = 0; i < 2; i++)
#pragma unroll
            for (int r = 0; r < 4; r++)
                red[wid][i * 16 + (lane >> 4) * 4 + r] = ps[i][r];
    __syncthreads();
    float mean[2][4];
#pragma unroll
    for (int i = 0; i < 2; i++)
#pragma unroll
        for (int r = 0; r < 4; r++) {
            int row = i * 16 + (lane >> 4) * 4 + r;
            float s = 0.f;
#pragma unroll
            for (int w = 0; w < 8; w++) s += red[w][row];
            mean[i][r] = s * (1.f / 512.f);
        }
    // variance
#pragma unroll
    for (int i = 0; i < 2; i++)
#pragma unroll
        for (int r = 0; r < 4; r++) {
            float s = 0.f;
#pragma unroll
            for (int j = 0; j < 4; j++) {
                float d = acc[i][j][r] - mean[i][r];
                s += d * d;
            }
            s += __shfl_xor(s, 1); s += __shfl_xor(s, 2);
            s += __shfl_xor(s, 4); s += __shfl_xor(s, 8);
            ps[i][r] = s;
        }
    if ((lane & 15) == 0)
#pragma unroll
        for (int i = 0; i < 2; i++)
#pragma unroll
            for (int r = 0; r < 4; r++)
                red2[wid][i * 16 + (lane >> 4) * 4 + r] = ps[i][r];
    __syncthreads();
#pragma unroll
    for (int i = 0; i < 2; i++)
#pragma unroll
        for (int r = 0; r < 4; r++) {
            int rrow = i * 16 + (lane >> 4) * 4 + r;
            float s = 0.f;
#pragma unroll
            for (int w = 0; w < 8; w++) s += red2[w][rrow];
            float inv = 1.f / sqrtf(s * (1.f / 512.f) + 1e-5f);
            int row = m0 + rrow;
#pragma unroll
            for (int j = 0; j < 4; j++) {
                int col = wid * 64 + j * 16 + (lane & 15);
                X[(size_t)row * DIM + col] = (acc[i][j][r] - mean[i][r]) * inv;
            }
        }
}

// ---------------- MFMA attention (unchanged from r3) ----------------
template<int CAUSAL>
__global__ __launch_bounds__(256) void attn_mfma(
    const unsigned short* __restrict__ Qb, int ldq,
    const unsigned short* __restrict__ Kb, int ldk,
    const unsigned short* __restrict__ Vb, int ldv,
    unsigned short* __restrict__ O)
{
    __shared__ __align__(16) unsigned short Ks[128 * 64];
    __shared__ __align__(16) unsigned short Vt[64 * 132];
    __shared__ __align__(16) unsigned short Ps[4][32 * 64];
    const int tid = threadIdx.x;
    const int lane = tid & 63, wid = tid >> 6;
    const int b = blockIdx.x >> 3, h = blockIdx.x & 7;
    const int tok0 = b * 128;
    const int wq = wid * 32;

    {
        const unsigned short* Kg = Kb + (size_t)tok0 * ldk + h * 64;
        const unsigned short* Vg = Vb + (size_t)tok0 * ldv + h * 64;
        int r = tid >> 1, cb = (tid & 1) * 4;
#pragma unroll
        for (int c = cb; c < cb + 4; c++) {
            bf16x8 kv = *(const bf16x8*)&Kg[(size_t)r * ldk + c * 8];
            *(bf16x8*)&Ks[r * 64 + ((c ^ (r & 7)) * 8)] = kv;
            bf16x8 vv = *(const bf16x8*)&Vg[(size_t)r * ldv + c * 8];
#pragma unroll
            for (int j = 0; j < 8; j++)
                Vt[(c * 8 + j) * 132 + r] = (unsigned short)vv[j];
        }
    }

    bf16x8 qa[2][2];
    {
        const unsigned short* Qg = Qb + (size_t)tok0 * ldq + h * 64;
#pragma unroll
        for (int i = 0; i < 2; i++)
#pragma unroll
            for (int kd = 0; kd < 2; kd++) {
                int qr = wq + i * 16 + (lane & 15);
                qa[i][kd] = *(const bf16x8*)&Qg[(size_t)qr * ldq + kd * 32 + (lane >> 4) * 8];
            }
    }
    __syncthreads();

    const int jmax = CAUSAL ? ((wq >> 4) + 2) : 8;
    const int kcmax = CAUSAL ? ((wq >> 5) + 1) : 4;

    float zr[2][4];
#pragma unroll
    for (int i = 0; i < 2; i++)
#pragma unroll
        for (int rr = 0; rr < 4; rr++) zr[i][rr] = 0.f;

    f32x4 oacc[2][4];
#pragma unroll
    for (int i = 0; i < 2; i++)
#pragma unroll
        for (int dt = 0; dt < 4; dt++) oacc[i][dt] = (f32x4){0.f, 0.f, 0.f, 0.f};

    for (int kb = 0; kb < 2; kb++) {
        int j0 = kb * 4;
        if (j0 >= jmax) break;
        int jn = jmax - j0; if (jn > 4) jn = 4;
        f32x4 sacc[2][4];
#pragma unroll
        for (int i = 0; i < 2; i++)
#pragma unroll
            for (int j = 0; j < 4; j++) sacc[i][j] = (f32x4){0.f, 0.f, 0.f, 0.f};
#pragma unroll 2
        for (int kd = 0; kd < 2; kd++) {
            for (int jj = 0; jj < jn; jj++) {
                int kr = (j0 + jj) * 16 + (lane & 15);
                int ch = (kd * 4 + (lane >> 4)) ^ (kr & 7);
                bf16x8 kf = *(const bf16x8*)&Ks[kr * 64 + ch * 8];
                sacc[0][jj] = __builtin_amdgcn_mfma_f32_16x16x32_bf16(qa[0][kd], kf, sacc[0][jj], 0, 0, 0);
                sacc[1][jj] = __builtin_amdgcn_mfma_f32_16x16x32_bf16(qa[1][kd], kf, sacc[1][jj], 0, 0, 0);
            }
        }
#pragma unroll
        for (int i = 0; i < 2; i++) {
            int qbase = wq + i * 16 + (lane >> 4) * 4;
            for (int jj = 0; jj < jn; jj++) {
                int kcol = (j0 + jj) * 16 + (lane & 15);
#pragma unroll
                for (int rr = 0; rr < 4; rr++) {
                    float p = __expf(sacc[i][jj][rr] * 0.125f);
                    if (CAUSAL && kcol > qbase + rr) p = 0.f;
                    zr[i][rr] += p;
                    int prow = i * 16 + (lane >> 4) * 4 + rr;
                    int ch = ((jj * 2 + ((lane & 15) >> 3)) ^ (prow & 7));
                    Ps[wid][prow * 64 + ch * 8 + (lane & 7)] = f2bf(p);
                }
            }
        }
        int kcn = kcmax - kb * 2; if (kcn > 2) kcn = 2;
        for (int kcl = 0; kcl < kcn; kcl++) {
            bf16x8 pa[2];
#pragma unroll
            for (int i = 0; i < 2; i++) {
                int prow = i * 16 + (lane & 15);
                int ch = (kcl * 4 + (lane >> 4)) ^ (prow & 7);
                pa[i] = *(const bf16x8*)&Ps[wid][prow * 64 + ch * 8];
            }
            int kcg = kb * 2 + kcl;
#pragma unroll
            for (int dt = 0; dt < 4; dt++) {
                int d = dt * 16 + (lane & 15);
                bf16x8 vf = *(const bf16x8*)&Vt[d * 132 + (kcg * 4 + (lane >> 4)) * 8];
                oacc[0][dt] = __builtin_amdgcn_mfma_f32_16x16x32_bf16(pa[0], vf, oacc[0][dt], 0, 0, 0);
                oacc[1][dt] = __builtin_amdgcn_mfma_f32_16x16x32_bf16(pa[1], vf, oacc[1][dt], 0, 0, 0);
            }
        }
    }
#pragma unroll
    for (int i = 0; i < 2; i++)
#pragma unroll
        for (int rr = 0; rr < 4; rr++) {
            float z = zr[i][rr];
            z += __shfl_xor(z, 1); z += __shfl_xor(z, 2);
            z += __shfl_xor(z, 4); z += __shfl_xor(z, 8);
            zr[i][rr] = 1.f / (z + 1e-9f);
        }
#pragma unroll
    for (int i = 0; i < 2; i++)
#pragma unroll
        for (int dt = 0; dt < 4; dt++)
#pragma unroll
            for (int rr = 0; rr < 4; rr++) {
                int qrow = tok0 + wq + i * 16 + (lane >> 4) * 4 + rr;
                O[(size_t)qrow * DIM + h * 64 + dt * 16 + (lane & 15)] =
                    f2bf(oacc[i][dt][rr] * zr[i][rr]);
            }
}

// ---------------- log_softmax (vectorized online) ----------------
__global__ __launch_bounds__(256) void logsoftmax_kernel(float* __restrict__ x) {
    const int row = blockIdx.x, tid = threadIdx.x;
    float* p = x + (size_t)row * VOCAB;
    const float4* p4 = (const float4*)p;
    float m = -1e30f, s = 0.f;
    for (int i = tid; i < VOCAB / 4; i += 256) {
        float4 v = p4[i];
        float vm = fmaxf(fmaxf(v.x, v.y), fmaxf(v.z, v.w));
        if (vm > m) { s *= __expf(m - vm); m = vm; }
        s += __expf(v.x - m) + __expf(v.y - m) + __expf(v.z - m) + __expf(v.w - m);
    }
#pragma unroll
    for (int off = 32; off > 0; off >>= 1) {
        float mo = __shfl_xor(m, off), so = __shfl_xor(s, off);
        float M = fmaxf(m, mo);
        s = s * __expf(m - M) + so * __expf(mo - M);
        m = M;
    }
    __shared__ float ms[4], ss[4];
    const int lane = tid & 63, wid = tid >> 6;
    if (lane == 0) { ms[wid] = m; ss[wid] = s; }
    __syncthreads();
    float M = fmaxf(fmaxf(ms[0], ms[1]), fmaxf(ms[2], ms[3]));
    float S = ss[0] * __expf(ms[0] - M) + ss[1] * __expf(ms[1] - M) +
              ss[2] * __expf(ms[2] - M) + ss[3] * __expf(ms[3] - M);
    const float lse = M + __logf(S);
    float4* q4 = (float4*)p;
    for (int i = tid; i < VOCAB / 4; i += 256) {
        float4 v = q4[i];
        q4[i] = make_float4(v.x - lse, v.y - lse, v.z - lse, v.w - lse);
    }
}

// ---------------- orchestration ----------------
extern "C" void kernel_launch(void* const* d_in, const int* in_sizes, int n_in,
                              void* d_out, int out_size, void* d_ws, size_t ws_size,
                              hipStream_t stream) {
    const float* emb_src  = (const float*)d_in[0];
    const float* emb_tgt  = (const float*)d_in[1];
    const float* pos_emb  = (const float*)d_in[2];
    const float* time_emb = (const float*)d_in[3];
    const float* Wqkv_e   = (const float*)d_in[4];
    const float* Wo_e     = (const float*)d_in[5];
    const float* W1_e     = (const float*)d_in[6];
    const float* W2_e     = (const float*)d_in[7];
    const float* Wqkv_d   = (const float*)d_in[8];
    const float* Wo_d     = (const float*)d_in[9];
    const float* W1_d     = (const float*)d_in[10];
    const float* W2_d     = (const float*)d_in[11];
    const float* Wq_x     = (const float*)d_in[12];
    const float* Wkv_x    = (const float*)d_in[13];
    const float* Wo_x     = (const float*)d_in[14];
    const float* Wgen     = (const float*)d_in[15];
    const int* src_tokens = (const int*)d_in[16];
    const int* tgt_tokens = (const int*)d_in[17];
    const int* src_pos    = (const int*)d_in[18];
    const int* tgt_pos    = (const int*)d_in[19];

    char* w = (char*)d_ws;
    float* x_e = (float*)(w);                                     // 4MB
    float* x_d = (float*)(w + (4u << 20));                        // 4MB
    unsigned short* qkv_bf = (unsigned short*)(w + (8u << 20));   // 6MB
    unsigned short* kvx_bf = (unsigned short*)(w + (14u << 20));  // 4MB
    unsigned short* o_bf   = (unsigned short*)(w + (18u << 20));  // 2MB
    unsigned short* q_bf   = (unsigned short*)(w + (20u << 20));  // 2MB
    unsigned short* hid_bf = (unsigned short*)(w + (22u << 20));  // 8MB
    unsigned short* wts    = (unsigned short*)(w + (30u << 20));  // ~47.4MB

    unsigned short* WqkvE_t = wts;
    unsigned short* WoE_t   = WqkvE_t + 786432;
    unsigned short* W1E_t   = WoE_t   + 262144;
    unsigned short* W2E_t   = W1E_t   + 1048576;
    unsigned short* WqkvD_t = W2E_t   + 1048576;
    unsigned short* WoD_t   = WqkvD_t + 786432;
    unsigned short* W1D_t   = WoD_t   + 262144;
    unsigned short* W2D_t   = W1D_t   + 1048576;
    unsigned short* WqX_t   = W2D_t   + 1048576;
    unsigned short* WkvX_t  = WqX_t   + 262144;
    unsigned short* WoX_t   = WkvX_t  + 524288;
    unsigned short* Wgen_t  = WoX_t   + 262144;

    float* out = (float*)d_out;

    // ---- batched weight conversion: one kernel ----
    WTab tab;
    auto set = [&](int i, const float* s, unsigned short* d, int K, int N, int t0) {
        tab.d[i].src = s; tab.d[i].dst = d; tab.d[i].K = K; tab.d[i].N = N;
        tab.d[i].t0 = t0; tab.d[i].pad = 0;
    };
    set(0,  Wqkv_e, WqkvE_t, 512, 1536, 0);
    set(1,  Wo_e,   WoE_t,   512, 512,  768);
    set(2,  W1_e,   W1E_t,   512, 2048, 1024);
    set(3,  W2_e,   W2E_t,   2048, 512, 2048);
    set(4,  Wqkv_d, WqkvD_t, 512, 1536, 3072);
    set(5,  Wo_d,   WoD_t,   512, 512,  3840);
    set(6,  W1_d,   W1D_t,   512, 2048, 4096);
    set(7,  W2_d,   W2D_t,   2048, 512, 5120);
    set(8,  Wq_x,   WqX_t,   512, 512,  6144);
    set(9,  Wkv_x,  WkvX_t,  512, 1024, 6400);
    set(10, Wo_x,   WoX_t,   512, 512,  6912);
    set(11, Wgen,   Wgen_t,  512, 32000, 7168);
    wconv_all<<<23168, 256, 0, stream>>>(tab);

    const int n4 = NTOK * (DIM / 4);
    dim3 eb(256), eg((n4 + 255) / 256);
    embed_kernel<<<eg, eb, 0, stream>>>(emb_src, src_tokens, pos_emb, src_pos, x_e, n4);
    embed_kernel<<<eg, eb, 0, stream>>>(emb_tgt, tgt_tokens, pos_emb, tgt_pos, x_d, n4);

    const dim3 gQKV(1536 / 128, NTOK / 128), g512(512 / 128, NTOK / 128),
               gFF(DFF / 128, NTOK / 128),  gKV(1024 / 128, NTOK / 128),
               gGEN(VOCAB / 128, NTOK / 128);
    const int gLN = NTOK / 32;  // 64 blocks

    // -------- encoder --------
    for (int t = 0; t < DEPTH; t++) {
        const float* trow = time_emb + (size_t)t * DIM;
        gemm_u<2, 3><<<gQKV, 256, 0, stream>>>(x_e, WqkvE_t, nullptr, qkv_bf, pos_emb, trow, NTOK, 1536, 512);
        attn_mfma<0><<<128, 256, 0, stream>>>(qkv_bf, 1536, qkv_bf + 512, 1536, qkv_bf + 1024, 1536, o_bf);
        gemm_ln<<<gLN, 512, 0, stream>>>(o_bf, WoE_t, x_e, 512);
        gemm_u<1, 1><<<gFF, 256, 0, stream>>>(x_e, W1E_t, nullptr, hid_bf, nullptr, nullptr, NTOK, DFF, 512);
        gemm_ln<<<gLN, 512, 0, stream>>>(hid_bf, W2E_t, x_e, 2048);
    }

    // cross-attn K/V from final encoder state
    gemm_u<1, 3><<<gKV, 256, 0, stream>>>(x_e, WkvX_t, nullptr, kvx_bf, nullptr, nullptr, NTOK, 1024, 512);

    // -------- decoder --------
    for (int t = 0; t < DEPTH; t++) {
        const float* trow = time_emb + (size_t)t * DIM;
        gemm_u<2, 3><<<gQKV, 256, 0, stream>>>(x_d, WqkvD_t, nullptr, qkv_bf, pos_emb, trow, NTOK, 1536, 512);
        attn_mfma<1><<<128, 256, 0, stream>>>(qkv_bf, 1536, qkv_bf + 512, 1536, qkv_bf + 1024, 1536, o_bf);
        gemm_ln<<<gLN, 512, 0, stream>>>(o_bf, WoD_t, x_d, 512);

        gemm_u<2, 3><<<g512, 256, 0, stream>>>(x_d, WqX_t, nullptr, q_bf, pos_emb, trow, NTOK, 512, 512);
        attn_mfma<0><<<128, 256, 0, stream>>>(q_bf, 512, kvx_bf, 1024, kvx_bf + 512, 1024, o_bf);
        gemm_ln<<<gLN, 512, 0, stream>>>(o_bf, WoX_t, x_d, 512);

        gemm_u<1, 1><<<gFF, 256, 0, stream>>>(x_d, W1D_t, nullptr, hid_bf, nullptr, nullptr, NTOK, DFF, 512);
        gemm_ln<<<gLN, 512, 0, stream>>>(hid_bf, W2D_t, x_d, 2048);
    }

    // -------- generator --------
    gemm_u<1, 0><<<gGEN, 256, 0, stream>>>(x_d, Wgen_t, out, nullptr, nullptr, nullptr, NTOK, VOCAB, 512);
    logsoftmax_kernel<<<NTOK, 256, 0, stream>>>(out);
}

// Round 5
// 2398.908 us; speedup vs baseline: 3.3528x; 1.0092x over previous
//
#include <hip/hip_runtime.h>
#include <hip/hip_bf16.h>
#include <math.h>

#define H 8
#define DK 64
#define DIM 512
#define DFF 2048
#define DEPTH 8
#define VOCAB 32000
#define NTOK 2048

typedef float f32x4 __attribute__((ext_vector_type(4)));
typedef short bf16x8 __attribute__((ext_vector_type(8)));

static __device__ __forceinline__ unsigned short f2bf(float f) {
    unsigned u = __float_as_uint(f);
    return (unsigned short)((u + 0x7FFFu + ((u >> 16) & 1u)) >> 16);
}

// ---------------- embed ----------------
__global__ void embed_kernel(const float* __restrict__ emb, const int* __restrict__ tok,
                             const float* __restrict__ pos, const int* __restrict__ pidx,
                             float* __restrict__ out, int n4) {
    int idx = blockIdx.x * blockDim.x + threadIdx.x;
    if (idx >= n4) return;
    int i = idx >> 7, d = idx & 127;
    float4 a = ((const float4*)emb)[(size_t)tok[i] * 128 + d];
    float4 b = ((const float4*)pos)[(size_t)pidx[i] * 128 + d];
    ((float4*)out)[idx] = make_float4(a.x + b.x, a.y + b.y, a.z + b.z, a.w + b.w);
}

// ---------------- batched weight convert+transpose ----------------
struct WD { const float* src; unsigned short* dst; int K; int N; int t0; int pad; };
struct WTab { WD d[12]; };

__global__ __launch_bounds__(256) void wconv_all(WTab tab) {
    __shared__ float t[32][33];
    const int bid = blockIdx.x;
    int w = 0;
#pragma unroll
    for (int i = 1; i < 12; i++) if (bid >= tab.d[i].t0) w = i;
    const float* W = tab.d[w].src;
    unsigned short* Wt = tab.d[w].dst;
    const int K = tab.d[w].K, N = tab.d[w].N;
    const int lt = bid - tab.d[w].t0;
    const int txc = N >> 5;
    const int n0 = (lt % txc) << 5, k0 = (lt / txc) << 5;
    const int tid = threadIdx.x;
    const int tx = tid & 31, ty = tid >> 5;
#pragma unroll
    for (int i = 0; i < 32; i += 8)
        t[ty + i][tx] = W[(size_t)(k0 + ty + i) * N + n0 + tx];
    __syncthreads();
#pragma unroll
    for (int i = 0; i < 32; i += 8)
        Wt[(size_t)(n0 + ty + i) * K + k0 + tx] = f2bf(t[tx][ty + i]);
}

// ---------------- unified bf16 MFMA GEMM: C = A' @ Bt^T ----------------
// AMODE 1: A f32, converted during reg-staging. AMODE 2: + pos[row&127] + trow.
// EPI 0: f32 store; 1: relu->bf16; 3: bf16.  BN: 128 or 64 (tile width).
template<int AMODE, int EPI, int BN>
__global__ __launch_bounds__(256) void gemm_u(
    const float* __restrict__ Af,
    const unsigned short* __restrict__ Bt,
    float* __restrict__ Cf,
    unsigned short* __restrict__ Cb,
    const float* __restrict__ pos,
    const float* __restrict__ trow,
    int M, int N, int K)
{
    constexpr int JN = BN / 32;        // j-frags per wave
    constexpr int BIT = BN / 32;       // B staging issues per wave
    __shared__ __align__(16) unsigned short Asm[128 * 64];
    __shared__ __align__(16) unsigned short Bsm[BN * 64];
    const int tid = threadIdx.x;
    const int lane = tid & 63, wid = tid >> 6;
    const int m0 = blockIdx.y * 128, n0 = blockIdx.x * BN;
    const int wm = (wid >> 1) * 64, wn = (wid & 1) * (BN / 2);

    f32x4 acc[4][JN];
#pragma unroll
    for (int i = 0; i < 4; i++)
#pragma unroll
        for (int j = 0; j < JN; j++)
            acc[i][j] = (f32x4){0.f, 0.f, 0.f, 0.f};

    for (int k0 = 0; k0 < K; k0 += 64) {
        if (k0) __syncthreads();
#pragma unroll
        for (int it = 0; it < BIT; it++) {
            int q = (wid * BIT + it) * 64 + lane;
            int row = q >> 3;
            int cs = (q & 7) ^ (row & 7);
            const unsigned short* srcB = Bt + (size_t)(n0 + row) * K + k0 + cs * 8;
            __builtin_amdgcn_global_load_lds(
                (const __attribute__((address_space(1))) unsigned int*)srcB,
                (__attribute__((address_space(3))) unsigned int*)&Bsm[(wid * BIT + it) * 512],
                16, 0, 0);
        }
#pragma unroll
        for (int it = 0; it < 4; it++) {
            int q = (wid * 4 + it) * 64 + lane;
            int row = q >> 3;
            int cs = q & 7;
            const float* s = Af + (size_t)(m0 + row) * K + k0 + cs * 8;
            float4 u0 = *(const float4*)s, u1 = *(const float4*)(s + 4);
            if (AMODE == 2) {
                const float* pp = pos + (size_t)((m0 + row) & 127) * DIM + k0 + cs * 8;
                const float* tt = trow + k0 + cs * 8;
                float4 p0 = *(const float4*)pp, p1 = *(const float4*)(pp + 4);
                float4 t0 = *(const float4*)tt, t1 = *(const float4*)(tt + 4);
                u0.x += p0.x + t0.x; u0.y += p0.y + t0.y; u0.z += p0.z + t0.z; u0.w += p0.w + t0.w;
                u1.x += p1.x + t1.x; u1.y += p1.y + t1.y; u1.z += p1.z + t1.z; u1.w += p1.w + t1.w;
            }
            unsigned short c8[8];
            c8[0] = f2bf(u0.x); c8[1] = f2bf(u0.y); c8[2] = f2bf(u0.z); c8[3] = f2bf(u0.w);
            c8[4] = f2bf(u1.x); c8[5] = f2bf(u1.y); c8[6] = f2bf(u1.z); c8[7] = f2bf(u1.w);
            *(bf16x8*)&Asm[row * 64 + ((cs ^ (row & 7)) * 8)] = *(bf16x8*)c8;
        }
        __syncthreads();
#pragma unroll
        for (int kk = 0; kk < 2; kk++) {
            bf16x8 af[4], bfr[JN];
#pragma unroll
            for (int i = 0; i < 4; i++) {
                int rowA = wm + i * 16 + (lane & 15);
                int ca = (kk * 4 + (lane >> 4)) ^ (rowA & 7);
                af[i] = *(const bf16x8*)&Asm[rowA * 64 + ca * 8];
            }
#pragma unroll
            for (int j = 0; j < JN; j++) {
                int rowB = wn + j * 16 + (lane & 15);
                int cb = (kk * 4 + (lane >> 4)) ^ (rowB & 7);
                bfr[j] = *(const bf16x8*)&Bsm[rowB * 64 + cb * 8];
            }
#pragma unroll
            for (int i = 0; i < 4; i++)
#pragma unroll
                for (int j = 0; j < JN; j++)
                    acc[i][j] = __builtin_amdgcn_mfma_f32_16x16x32_bf16(af[i], bfr[j], acc[i][j], 0, 0, 0);
        }
    }
#pragma unroll
    for (int i = 0; i < 4; i++) {
#pragma unroll
        for (int j = 0; j < JN; j++) {
#pragma unroll
            for (int r = 0; r < 4; r++) {
                int row = m0 + wm + i * 16 + (lane >> 4) * 4 + r;
                int col = n0 + wn + j * 16 + (lane & 15);
                size_t idx = (size_t)row * N + col;
                float v = acc[i][j][r];
                if (EPI == 0) Cf[idx] = v;
                if (EPI == 1) Cb[idx] = f2bf(fmaxf(v, 0.f));
                if (EPI == 3) Cb[idx] = f2bf(v);
            }
        }
    }
}

// ---------------- fused GEMM + residual + LayerNorm (in-place on X) ----------------
// X = LN(X + A @ Bt^T).  N = 512 (full row per block). BM=16, 4 waves, 128 blocks.
__global__ __launch_bounds__(256) void gemm_ln(
    const unsigned short* __restrict__ A,   // [M,K] bf16
    const unsigned short* __restrict__ Bt,  // [512,K] bf16
    float* __restrict__ X,                  // [M,512] residual in, LN out
    int K)
{
    __shared__ __align__(16) unsigned short Bsm[512 * 64];  // 64KB
    __shared__ __align__(16) unsigned short Asm[16 * 64];   // 2KB
    __shared__ float red[4][16];
    __shared__ float red2[4][16];
    const int tid = threadIdx.x;
    const int lane = tid & 63, wid = tid >> 6;
    const int m0 = blockIdx.x * 16;

    f32x4 acc[8];
#pragma unroll
    for (int j = 0; j < 8; j++) acc[j] = (f32x4){0.f, 0.f, 0.f, 0.f};

    for (int k0 = 0; k0 < K; k0 += 64) {
        if (k0) __syncthreads();
        if (wid == 0) {
#pragma unroll
            for (int it = 0; it < 2; it++) {
                int q = it * 64 + lane;
                int row = q >> 3;
                int cs = (q & 7) ^ (row & 7);
                const unsigned short* srcA = A + (size_t)(m0 + row) * K + k0 + cs * 8;
                __builtin_amdgcn_global_load_lds(
                    (const __attribute__((address_space(1))) unsigned int*)srcA,
                    (__attribute__((address_space(3))) unsigned int*)&Asm[it * 512],
                    16, 0, 0);
            }
        }
#pragma unroll
        for (int it = 0; it < 16; it++) {
            int q = (wid * 16 + it) * 64 + lane;
            int row = q >> 3;
            int cs = (q & 7) ^ (row & 7);
            const unsigned short* srcB = Bt + (size_t)row * K + k0 + cs * 8;
            __builtin_amdgcn_global_load_lds(
                (const __attribute__((address_space(1))) unsigned int*)srcB,
                (__attribute__((address_space(3))) unsigned int*)&Bsm[(wid * 16 + it) * 512],
                16, 0, 0);
        }
        __syncthreads();
#pragma unroll
        for (int kd = 0; kd < 2; kd++) {
            int rowA = lane & 15;
            int ca = (kd * 4 + (lane >> 4)) ^ (rowA & 7);
            bf16x8 af = *(const bf16x8*)&Asm[rowA * 64 + ca * 8];
#pragma unroll
            for (int j = 0; j < 8; j++) {
                int rowB = wid * 128 + j * 16 + (lane & 15);
                int cb = (kd * 4 + (lane >> 4)) ^ (rowB & 7);
                bf16x8 bfr = *(const bf16x8*)&Bsm[rowB * 64 + cb * 8];
                acc[j] = __builtin_amdgcn_mfma_f32_16x16x32_bf16(af, bfr, acc[j], 0, 0, 0);
            }
        }
    }
    // ---- epilogue: residual add, row LN over 512 cols (4 waves x 128) ----
#pragma unroll
    for (int j = 0; j < 8; j++)
#pragma unroll
        for (int r = 0; r < 4; r++) {
            int row = m0 + (lane >> 4) * 4 + r;
            int col = wid * 128 + j * 16 + (lane & 15);
            acc[j][r] += X[(size_t)row * DIM + col];
        }
    float ps[4];
#pragma unroll
    for (int r = 0; r < 4; r++) {
        float s = 0.f;
#pragma unroll
        for (int j = 0; j < 8; j++) s += acc[j][r];
        s += __shfl_xor(s, 1); s += __shfl_xor(s, 2);
        s += __shfl_xor(s, 4); s += __shfl_xor(s, 8);
        ps[r] = s;
    }
    if ((lane & 15) == 0)
#pragma unroll
        for (int r = 0; r < 4; r++) red[wid][(lane >> 4) * 4 + r] = ps[r];
    __syncthreads();
    float mean[4];
#pragma unroll
    for (int r = 0; r < 4; r++) {
        int rl = (lane >> 4) * 4 + r;
        mean[r] = (red[0][rl] + red[1][rl] + red[2][rl] + red[3][rl]) * (1.f / 512.f);
    }
#pragma unroll
    for (int r = 0; r < 4; r++) {
        float s = 0.f;
#pragma unroll
        for (int j = 0; j < 8; j++) {
            float d = acc[j][r] - mean[r];
            s += d * d;
        }
        s += __shfl_xor(s, 1); s += __shfl_xor(s, 2);
        s += __shfl_xor(s, 4); s += __shfl_xor(s, 8);
        ps[r] = s;
    }
    if ((lane & 15) == 0)
#pragma unroll
        for (int r = 0; r < 4; r++) red2[wid][(lane >> 4) * 4 + r] = ps[r];
    __syncthreads();
#pragma unroll
    for (int r = 0; r < 4; r++) {
        int rl = (lane >> 4) * 4 + r;
        float v = (red2[0][rl] + red2[1][rl] + red2[2][rl] + red2[3][rl]) * (1.f / 512.f);
        float inv = 1.f / sqrtf(v + 1e-5f);
        int row = m0 + rl;
#pragma unroll
        for (int j = 0; j < 8; j++) {
            int col = wid * 128 + j * 16 + (lane & 15);
            X[(size_t)row * DIM + col] = (acc[j][r] - mean[r]) * inv;
        }
    }
}

// ---------------- MFMA attention: block = (b, h, q-half), 2 waves ----------------
template<int CAUSAL>
__global__ __launch_bounds__(128) void attn_mfma(
    const unsigned short* __restrict__ Qb, int ldq,
    const unsigned short* __restrict__ Kb, int ldk,
    const unsigned short* __restrict__ Vb, int ldv,
    unsigned short* __restrict__ O)
{
    __shared__ __align__(16) unsigned short Ks[128 * 64];
    __shared__ __align__(16) unsigned short Vt[64 * 132];
    __shared__ __align__(16) unsigned short Ps[2][32 * 64];
    const int tid = threadIdx.x;
    const int lane = tid & 63, wid = tid >> 6;
    const int blk = blockIdx.x;
    const int qh = blk & 1;
    const int h = (blk >> 1) & 7;
    const int b = blk >> 4;
    const int tok0 = b * 128;
    const int wq = qh * 64 + wid * 32;
    const int kl = (CAUSAL && qh == 0) ? 64 : 128;

    if (tid < kl) {
        const unsigned short* Kg = Kb + (size_t)(tok0 + tid) * ldk + h * 64;
        const unsigned short* Vg = Vb + (size_t)(tok0 + tid) * ldv + h * 64;
        int r = tid;
#pragma unroll
        for (int c = 0; c < 8; c++) {
            bf16x8 kv = *(const bf16x8*)&Kg[c * 8];
            *(bf16x8*)&Ks[r * 64 + ((c ^ (r & 7)) * 8)] = kv;
            bf16x8 vv = *(const bf16x8*)&Vg[c * 8];
#pragma unroll
            for (int j = 0; j < 8; j++)
                Vt[(c * 8 + j) * 132 + r] = (unsigned short)vv[j];
        }
    }

    bf16x8 qa[2][2];
    {
        const unsigned short* Qg = Qb + (size_t)tok0 * ldq + h * 64;
#pragma unroll
        for (int i = 0; i < 2; i++)
#pragma unroll
            for (int kd = 0; kd < 2; kd++) {
                int qr = wq + i * 16 + (lane & 15);
                qa[i][kd] = *(const bf16x8*)&Qg[(size_t)qr * ldq + kd * 32 + (lane >> 4) * 8];
            }
    }
    __syncthreads();

    const int jmax = CAUSAL ? ((wq >> 4) + 2) : 8;
    const int kcmax = CAUSAL ? ((wq >> 5) + 1) : 4;

    float zr[2][4];
#pragma unroll
    for (int i = 0; i < 2; i++)
#pragma unroll
        for (int rr = 0; rr < 4; rr++) zr[i][rr] = 0.f;

    f32x4 oacc[2][4];
#pragma unroll
    for (int i = 0; i < 2; i++)
#pragma unroll
        for (int dt = 0; dt < 4; dt++) oacc[i][dt] = (f32x4){0.f, 0.f, 0.f, 0.f};

    for (int kb = 0; kb < 2; kb++) {
        int j0 = kb * 4;
        if (j0 >= jmax) break;
        int jn = jmax - j0; if (jn > 4) jn = 4;
        f32x4 sacc[2][4];
#pragma unroll
        for (int i = 0; i < 2; i++)
#pragma unroll
            for (int j = 0; j < 4; j++) sacc[i][j] = (f32x4){0.f, 0.f, 0.f, 0.f};
#pragma unroll 2
        for (int kd = 0; kd < 2; kd++) {
            for (int jj = 0; jj < jn; jj++) {
                int kr = (j0 + jj) * 16 + (lane & 15);
                int ch = (kd * 4 + (lane >> 4)) ^ (kr & 7);
                bf16x8 kf = *(const bf16x8*)&Ks[kr * 64 + ch * 8];
                sacc[0][jj] = __builtin_amdgcn_mfma_f32_16x16x32_bf16(qa[0][kd], kf, sacc[0][jj], 0, 0, 0);
                sacc[1][jj] = __builtin_amdgcn_mfma_f32_16x16x32_bf16(qa[1][kd], kf, sacc[1][jj], 0, 0, 0);
            }
        }
#pragma unroll
        for (int i = 0; i < 2; i++) {
            int qbase = wq + i * 16 + (lane >> 4) * 4;
            for (int jj = 0; jj < jn; jj++) {
                int kcol = (j0 + jj) * 16 + (lane & 15);
#pragma unroll
                for (int rr = 0; rr < 4; rr++) {
                    float p = __expf(sacc[i][jj][rr] * 0.125f);
                    if (CAUSAL && kcol > qbase + rr) p = 0.f;
                    zr[i][rr] += p;
                    int prow = i * 16 + (lane >> 4) * 4 + rr;
                    int ch = ((jj * 2 + ((lane & 15) >> 3)) ^ (prow & 7));
                    Ps[wid][prow * 64 + ch * 8 + (lane & 7)] = f2bf(p);
                }
            }
        }
        int kcn = kcmax - kb * 2; if (kcn > 2) kcn = 2;
        for (int kcl = 0; kcl < kcn; kcl++) {
            bf16x8 pa[2];
#pragma unroll
            for (int i = 0; i < 2; i++) {
                int prow = i * 16 + (lane & 15);
                int ch = (kcl * 4 + (lane >> 4)) ^ (prow & 7);
                pa[i] = *(const bf16x8*)&Ps[wid][prow * 64 + ch * 8];
            }
            int kcg = kb * 2 + kcl;
#pragma unroll
            for (int dt = 0; dt < 4; dt++) {
                int d = dt * 16 + (lane & 15);
                bf16x8 vf = *(const bf16x8*)&Vt[d * 132 + (kcg * 4 + (lane >> 4)) * 8];
                oacc[0][dt] = __builtin_amdgcn_mfma_f32_16x16x32_bf16(pa[0], vf, oacc[0][dt], 0, 0, 0);
                oacc[1][dt] = __builtin_amdgcn_mfma_f32_16x16x32_bf16(pa[1], vf, oacc[1][dt], 0, 0, 0);
            }
        }
    }
#pragma unroll
    for (int i = 0; i < 2; i++)
#pragma unroll
        for (int rr = 0; rr < 4; rr++) {
            float z = zr[i][rr];
            z += __shfl_xor(z, 1); z += __shfl_xor(z, 2);
            z += __shfl_xor(z, 4); z += __shfl_xor(z, 8);
            zr[i][rr] = 1.f / (z + 1e-9f);
        }
#pragma unroll
    for (int i = 0; i < 2; i++)
#pragma unroll
        for (int dt = 0; dt < 4; dt++)
#pragma unroll
            for (int rr = 0; rr < 4; rr++) {
                int qrow = tok0 + wq + i * 16 + (lane >> 4) * 4 + rr;
                O[(size_t)qrow * DIM + h * 64 + dt * 16 + (lane & 15)] =
                    f2bf(oacc[i][dt][rr] * zr[i][rr]);
            }
}

// ---------------- generator: persistent column-slab GEMM + lse partials ----------------
// 250 blocks x 512 thr (8 waves: 2 wm x 4 wn). Block owns cols n0..n0+128, loops 16 M-tiles.
__global__ __launch_bounds__(512) void gemm_gen(
    const float* __restrict__ Af,           // [2048,512] f32
    const unsigned short* __restrict__ Bt,  // [32000,512] bf16
    float* __restrict__ Out,                // [2048,32000] logits
    float* __restrict__ pm,                 // [2048,256] partial max
    float* __restrict__ psum)               // [2048,256] partial sumexp
{
    __shared__ __align__(16) unsigned short Asm[128 * 64];
    __shared__ __align__(16) unsigned short Bsm[128 * 64];
    __shared__ float pml[8][64];
    __shared__ float psl[8][64];
    const int tid = threadIdx.x;
    const int lane = tid & 63, wid = tid >> 6;
    const int n0 = blockIdx.x * 128;
    const int wm = (wid >> 2) * 64, wn = (wid & 3) * 32;

    for (int mt = 0; mt < 16; mt++) {
        const int m0 = mt * 128;
        f32x4 acc[4][2];
#pragma unroll
        for (int i = 0; i < 4; i++)
#pragma unroll
            for (int j = 0; j < 2; j++) acc[i][j] = (f32x4){0.f, 0.f, 0.f, 0.f};

        for (int k0 = 0; k0 < 512; k0 += 64) {
            __syncthreads();
#pragma unroll
            for (int it = 0; it < 2; it++) {
                int q = (wid * 2 + it) * 64 + lane;
                int row = q >> 3;
                int cs = (q & 7) ^ (row & 7);
                const unsigned short* srcB = Bt + (size_t)(n0 + row) * 512 + k0 + cs * 8;
                __builtin_amdgcn_global_load_lds(
                    (const __attribute__((address_space(1))) unsigned int*)srcB,
                    (__attribute__((address_space(3))) unsigned int*)&Bsm[(wid * 2 + it) * 512],
                    16, 0, 0);
            }
#pragma unroll
            for (int it = 0; it < 2; it++) {
                int q = (wid * 2 + it) * 64 + lane;
                int row = q >> 3;
                int cs = q & 7;
                const float* s = Af + (size_t)(m0 + row) * 512 + k0 + cs * 8;
                float4 u0 = *(const float4*)s, u1 = *(const float4*)(s + 4);
                unsigned short c8[8];
                c8[0] = f2bf(u0.x); c8[1] = f2bf(u0.y); c8[2] = f2bf(u0.z); c8[3] = f2bf(u0.w);
                c8[4] = f2bf(u1.x); c8[5] = f2bf(u1.y); c8[6] = f2bf(u1.z); c8[7] = f2bf(u1.w);
                *(bf16x8*)&Asm[row * 64 + ((cs ^ (row & 7)) * 8)] = *(bf16x8*)c8;
            }
            __syncthreads();
#pragma unroll
            for (int kd = 0; kd < 2; kd++) {
                bf16x8 af[4], bfr[2];
#pragma unroll
                for (int i = 0; i < 4; i++) {
                    int rowA = wm + i * 16 + (lane & 15);
                    int ca = (kd * 4 + (lane >> 4)) ^ (rowA & 7);
                    af[i] = *(const bf16x8*)&Asm[rowA * 64 + ca * 8];
                }
#pragma unroll
                for (int j = 0; j < 2; j++) {
                    int rowB = wn + j * 16 + (lane & 15);
                    int cb = (kd * 4 + (lane >> 4)) ^ (rowB & 7);
                    bfr[j] = *(const bf16x8*)&Bsm[rowB * 64 + cb * 8];
                }
#pragma unroll
                for (int i = 0; i < 4; i++)
#pragma unroll
                    for (int j = 0; j < 2; j++)
                        acc[i][j] = __builtin_amdgcn_mfma_f32_16x16x32_bf16(af[i], bfr[j], acc[i][j], 0, 0, 0);
            }
        }
        // ---- per-row partial max / sumexp over this block's 128 cols ----
#pragma unroll
        for (int i = 0; i < 4; i++) {
#pragma unroll
            for (int r = 0; r < 4; r++) {
                float v0 = acc[i][0][r], v1 = acc[i][1][r];
                float mx = fmaxf(v0, v1);
                mx = fmaxf(mx, __shfl_xor(mx, 1));
                mx = fmaxf(mx, __shfl_xor(mx, 2));
                mx = fmaxf(mx, __shfl_xor(mx, 4));
                mx = fmaxf(mx, __shfl_xor(mx, 8));
                float s = __expf(v0 - mx) + __expf(v1 - mx);
                s += __shfl_xor(s, 1); s += __shfl_xor(s, 2);
                s += __shfl_xor(s, 4); s += __shfl_xor(s, 8);
                if ((lane & 15) == 0) {
                    int li = i * 16 + (lane >> 4) * 4 + r;
                    pml[wid][li] = mx;
                    psl[wid][li] = s;
                }
            }
        }
        __syncthreads();
        if (tid < 128) {
            int g = tid >> 6, lr = tid & 63;
            float m = pml[g * 4][lr];
            m = fmaxf(m, pml[g * 4 + 1][lr]);
            m = fmaxf(m, pml[g * 4 + 2][lr]);
            m = fmaxf(m, pml[g * 4 + 3][lr]);
            float s = 0.f;
#pragma unroll
            for (int ww = 0; ww < 4; ww++)
                s += psl[g * 4 + ww][lr] * __expf(pml[g * 4 + ww][lr] - m);
            pm[(size_t)(m0 + tid) * 256 + blockIdx.x] = m;
            psum[(size_t)(m0 + tid) * 256 + blockIdx.x] = s;
        }
        // ---- store logits ----
#pragma unroll
        for (int i = 0; i < 4; i++)
#pragma unroll
            for (int j = 0; j < 2; j++)
#pragma unroll
                for (int r = 0; r < 4; r++) {
                    int row = m0 + wm + i * 16 + (lane >> 4) * 4 + r;
                    int col = n0 + wn + j * 16 + (lane & 15);
                    Out[(size_t)row * VOCAB + col] = acc[i][j][r];
                }
    }
}

// ---------------- lse reduce: 250 partials per row -> lse[row] ----------------
__global__ __launch_bounds__(64) void lse_kernel(const float* __restrict__ pm,
                                                 const float* __restrict__ psum,
                                                 float* __restrict__ lse) {
    const int row = blockIdx.x, t = threadIdx.x;
    float m = -1e30f, s = 0.f;
    for (int nb = t; nb < 250; nb += 64) {
        float mm = pm[(size_t)row * 256 + nb];
        float ss = psum[(size_t)row * 256 + nb];
        float M = fmaxf(m, mm);
        s = s * __expf(m - M) + ss * __expf(mm - M);
        m = M;
    }
#pragma unroll
    for (int off = 32; off > 0; off >>= 1) {
        float mo = __shfl_xor(m, off), so = __shfl_xor(s, off);
        float M = fmaxf(m, mo);
        s = s * __expf(m - M) + so * __expf(mo - M);
        m = M;
    }
    if (t == 0) lse[row] = m + __logf(s);
}

// ---------------- subtract lse (in-place on logits) ----------------
__global__ __launch_bounds__(256) void sub_kernel(float* __restrict__ out,
                                                  const float* __restrict__ lse) {
    const int row = blockIdx.x;
    const float l = lse[row];
    float4* p = (float4*)(out + (size_t)row * VOCAB);
    for (int i = threadIdx.x; i < VOCAB / 4; i += 256) {
        float4 v = p[i];
        p[i] = make_float4(v.x - l, v.y - l, v.z - l, v.w - l);
    }
}

// ---------------- orchestration ----------------
extern "C" void kernel_launch(void* const* d_in, const int* in_sizes, int n_in,
                              void* d_out, int out_size, void* d_ws, size_t ws_size,
                              hipStream_t stream) {
    const float* emb_src  = (const float*)d_in[0];
    const float* emb_tgt  = (const float*)d_in[1];
    const float* pos_emb  = (const float*)d_in[2];
    const float* time_emb = (const float*)d_in[3];
    const float* Wqkv_e   = (const float*)d_in[4];
    const float* Wo_e     = (const float*)d_in[5];
    const float* W1_e     = (const float*)d_in[6];
    const float* W2_e     = (const float*)d_in[7];
    const float* Wqkv_d   = (const float*)d_in[8];
    const float* Wo_d     = (const float*)d_in[9];
    const float* W1_d     = (const float*)d_in[10];
    const float* W2_d     = (const float*)d_in[11];
    const float* Wq_x     = (const float*)d_in[12];
    const float* Wkv_x    = (const float*)d_in[13];
    const float* Wo_x     = (const float*)d_in[14];
    const float* Wgen     = (const float*)d_in[15];
    const int* src_tokens = (const int*)d_in[16];
    const int* tgt_tokens = (const int*)d_in[17];
    const int* src_pos    = (const int*)d_in[18];
    const int* tgt_pos    = (const int*)d_in[19];

    char* w = (char*)d_ws;
    float* x_e = (float*)(w);                                     // 4MB
    float* x_d = (float*)(w + (4u << 20));                        // 4MB
    unsigned short* qkv_bf = (unsigned short*)(w + (8u << 20));   // 6MB
    unsigned short* kvx_bf = (unsigned short*)(w + (14u << 20));  // 4MB
    unsigned short* o_bf   = (unsigned short*)(w + (18u << 20));  // 2MB
    unsigned short* q_bf   = (unsigned short*)(w + (20u << 20));  // 2MB
    unsigned short* hid_bf = (unsigned short*)(w + (22u << 20));  // 8MB
    float* pm   = (float*)(w + (30u << 20));                      // 2MB [2048,256]
    float* psum = (float*)(w + (32u << 20));                      // 2MB
    float* lse  = (float*)(w + (34u << 20));                      // 8KB
    unsigned short* wts    = (unsigned short*)(w + (35u << 20));  // ~47.4MB

    unsigned short* WqkvE_t = wts;
    unsigned short* WoE_t   = WqkvE_t + 786432;
    unsigned short* W1E_t   = WoE_t   + 262144;
    unsigned short* W2E_t   = W1E_t   + 1048576;
    unsigned short* WqkvD_t = W2E_t   + 1048576;
    unsigned short* WoD_t   = WqkvD_t + 786432;
    unsigned short* W1D_t   = WoD_t   + 262144;
    unsigned short* W2D_t   = W1D_t   + 1048576;
    unsigned short* WqX_t   = W2D_t   + 1048576;
    unsigned short* WkvX_t  = WqX_t   + 262144;
    unsigned short* WoX_t   = WkvX_t  + 524288;
    unsigned short* Wgen_t  = WoX_t   + 262144;

    float* out = (float*)d_out;

    WTab tab;
    auto set = [&](int i, const float* s, unsigned short* d, int K, int N, int t0) {
        tab.d[i].src = s; tab.d[i].dst = d; tab.d[i].K = K; tab.d[i].N = N;
        tab.d[i].t0 = t0; tab.d[i].pad = 0;
    };
    set(0,  Wqkv_e, WqkvE_t, 512, 1536, 0);
    set(1,  Wo_e,   WoE_t,   512, 512,  768);
    set(2,  W1_e,   W1E_t,   512, 2048, 1024);
    set(3,  W2_e,   W2E_t,   2048, 512, 2048);
    set(4,  Wqkv_d, WqkvD_t, 512, 1536, 3072);
    set(5,  Wo_d,   WoD_t,   512, 512,  3840);
    set(6,  W1_d,   W1D_t,   512, 2048, 4096);
    set(7,  W2_d,   W2D_t,   2048, 512, 5120);
    set(8,  Wq_x,   WqX_t,   512, 512,  6144);
    set(9,  Wkv_x,  WkvX_t,  512, 1024, 6400);
    set(10, Wo_x,   WoX_t,   512, 512,  6912);
    set(11, Wgen,   Wgen_t,  512, 32000, 7168);
    wconv_all<<<23168, 256, 0, stream>>>(tab);

    const int n4 = NTOK * (DIM / 4);
    dim3 eb(256), eg((n4 + 255) / 256);
    embed_kernel<<<eg, eb, 0, stream>>>(emb_src, src_tokens, pos_emb, src_pos, x_e, n4);
    embed_kernel<<<eg, eb, 0, stream>>>(emb_tgt, tgt_tokens, pos_emb, tgt_pos, x_d, n4);

    const dim3 gQKV(1536 / 128, NTOK / 128), gFF(DFF / 128, NTOK / 128),
               gKV(1024 / 128, NTOK / 128),  gQX(512 / 64, NTOK / 128);
    const int gLN = NTOK / 16;  // 128 blocks

    // -------- encoder --------
    for (int t = 0; t < DEPTH; t++) {
        const float* trow = time_emb + (size_t)t * DIM;
        gemm_u<2, 3, 128><<<gQKV, 256, 0, stream>>>(x_e, WqkvE_t, nullptr, qkv_bf, pos_emb, trow, NTOK, 1536, 512);
        attn_mfma<0><<<256, 128, 0, stream>>>(qkv_bf, 1536, qkv_bf + 512, 1536, qkv_bf + 1024, 1536, o_bf);
        gemm_ln<<<gLN, 256, 0, stream>>>(o_bf, WoE_t, x_e, 512);
        gemm_u<1, 1, 128><<<gFF, 256, 0, stream>>>(x_e, W1E_t, nullptr, hid_bf, nullptr, nullptr, NTOK, DFF, 512);
        gemm_ln<<<gLN, 256, 0, stream>>>(hid_bf, W2E_t, x_e, 2048);
    }

    // cross-attn K/V from final encoder state
    gemm_u<1, 3, 128><<<gKV, 256, 0, stream>>>(x_e, WkvX_t, nullptr, kvx_bf, nullptr, nullptr, NTOK, 1024, 512);

    // -------- decoder --------
    for (int t = 0; t < DEPTH; t++) {
        const float* trow = time_emb + (size_t)t * DIM;
        gemm_u<2, 3, 128><<<gQKV, 256, 0, stream>>>(x_d, WqkvD_t, nullptr, qkv_bf, pos_emb, trow, NTOK, 1536, 512);
        attn_mfma<1><<<256, 128, 0, stream>>>(qkv_bf, 1536, qkv_bf + 512, 1536, qkv_bf + 1024, 1536, o_bf);
        gemm_ln<<<gLN, 256, 0, stream>>>(o_bf, WoD_t, x_d, 512);

        gemm_u<2, 3, 64><<<gQX, 256, 0, stream>>>(x_d, WqX_t, nullptr, q_bf, pos_emb, trow, NTOK, 512, 512);
        attn_mfma<0><<<256, 128, 0, stream>>>(q_bf, 512, kvx_bf, 1024, kvx_bf + 512, 1024, o_bf);
        gemm_ln<<<gLN, 256, 0, stream>>>(o_bf, WoX_t, x_d, 512);

        gemm_u<1, 1, 128><<<gFF, 256, 0, stream>>>(x_d, W1D_t, nullptr, hid_bf, nullptr, nullptr, NTOK, DFF, 512);
        gemm_ln<<<gLN, 256, 0, stream>>>(hid_bf, W2D_t, x_d, 2048);
    }

    // -------- generator + log_softmax --------
    gemm_gen<<<250, 512, 0, stream>>>(x_d, Wgen_t, out, pm, psum);
    lse_kernel<<<NTOK, 64, 0, stream>>>(pm, psum, lse);
    sub_kernel<<<NTOK, 256, 0, stream>>>(out, lse);
}

// Round 6
// 2137.477 us; speedup vs baseline: 3.7629x; 1.1223x over previous
//
#include <hip/hip_runtime.h>
#include <hip/hip_bf16.h>
#include <math.h>

#define H 8
#define DK 64
#define DIM 512
#define DFF 2048
#define DEPTH 8
#define VOCAB 32000
#define NTOK 2048

typedef float f32x4 __attribute__((ext_vector_type(4)));
typedef short bf16x8 __attribute__((ext_vector_type(8)));

static __device__ __forceinline__ unsigned short f2bf(float f) {
    unsigned u = __float_as_uint(f);
    return (unsigned short)((u + 0x7FFFu + ((u >> 16) & 1u)) >> 16);
}

// ---------------- embed ----------------
__global__ void embed_kernel(const float* __restrict__ emb, const int* __restrict__ tok,
                             const float* __restrict__ pos, const int* __restrict__ pidx,
                             float* __restrict__ out, int n4) {
    int idx = blockIdx.x * blockDim.x + threadIdx.x;
    if (idx >= n4) return;
    int i = idx >> 7, d = idx & 127;
    float4 a = ((const float4*)emb)[(size_t)tok[i] * 128 + d];
    float4 b = ((const float4*)pos)[(size_t)pidx[i] * 128 + d];
    ((float4*)out)[idx] = make_float4(a.x + b.x, a.y + b.y, a.z + b.z, a.w + b.w);
}

// ---------------- batched weight convert+transpose ----------------
struct WD { const float* src; unsigned short* dst; int K; int N; int t0; int pad; };
struct WTab { WD d[12]; };

__global__ __launch_bounds__(256) void wconv_all(WTab tab) {
    __shared__ float t[32][33];
    const int bid = blockIdx.x;
    int w = 0;
#pragma unroll
    for (int i = 1; i < 12; i++) if (bid >= tab.d[i].t0) w = i;
    const float* W = tab.d[w].src;
    unsigned short* Wt = tab.d[w].dst;
    const int K = tab.d[w].K, N = tab.d[w].N;
    const int lt = bid - tab.d[w].t0;
    const int txc = N >> 5;
    const int n0 = (lt % txc) << 5, k0 = (lt / txc) << 5;
    const int tid = threadIdx.x;
    const int tx = tid & 31, ty = tid >> 5;
#pragma unroll
    for (int i = 0; i < 32; i += 8)
        t[ty + i][tx] = W[(size_t)(k0 + ty + i) * N + n0 + tx];
    __syncthreads();
#pragma unroll
    for (int i = 0; i < 32; i += 8)
        Wt[(size_t)(n0 + ty + i) * K + k0 + tx] = f2bf(t[tx][ty + i]);
}

// ---------------- unified bf16 MFMA GEMM (f32 A): C = A' @ Bt^T ----------------
// AMODE 1: A f32 -> bf16 during staging. AMODE 2: + pos[row&127] + trow.
// EPI 1: relu->bf16; 3: bf16.  BN: 128 or 64.
template<int AMODE, int EPI, int BN>
__global__ __launch_bounds__(256) void gemm_u(
    const float* __restrict__ Af,
    const unsigned short* __restrict__ Bt,
    unsigned short* __restrict__ Cb,
    const float* __restrict__ pos,
    const float* __restrict__ trow,
    int M, int N, int K)
{
    constexpr int JN = BN / 32;
    constexpr int BIT = BN / 32;
    __shared__ __align__(16) unsigned short Asm[128 * 64];
    __shared__ __align__(16) unsigned short Bsm[BN * 64];
    const int tid = threadIdx.x;
    const int lane = tid & 63, wid = tid >> 6;
    const int m0 = blockIdx.y * 128, n0 = blockIdx.x * BN;
    const int wm = (wid >> 1) * 64, wn = (wid & 1) * (BN / 2);

    f32x4 acc[4][JN];
#pragma unroll
    for (int i = 0; i < 4; i++)
#pragma unroll
        for (int j = 0; j < JN; j++)
            acc[i][j] = (f32x4){0.f, 0.f, 0.f, 0.f};

    for (int k0 = 0; k0 < K; k0 += 64) {
        if (k0) __syncthreads();
#pragma unroll
        for (int it = 0; it < BIT; it++) {
            int q = (wid * BIT + it) * 64 + lane;
            int row = q >> 3;
            int cs = (q & 7) ^ (row & 7);
            const unsigned short* srcB = Bt + (size_t)(n0 + row) * K + k0 + cs * 8;
            __builtin_amdgcn_global_load_lds(
                (const __attribute__((address_space(1))) unsigned int*)srcB,
                (__attribute__((address_space(3))) unsigned int*)&Bsm[(wid * BIT + it) * 512],
                16, 0, 0);
        }
#pragma unroll
        for (int it = 0; it < 4; it++) {
            int q = (wid * 4 + it) * 64 + lane;
            int row = q >> 3;
            int cs = q & 7;
            const float* s = Af + (size_t)(m0 + row) * K + k0 + cs * 8;
            float4 u0 = *(const float4*)s, u1 = *(const float4*)(s + 4);
            if (AMODE == 2) {
                const float* pp = pos + (size_t)((m0 + row) & 127) * DIM + k0 + cs * 8;
                const float* tt = trow + k0 + cs * 8;
                float4 p0 = *(const float4*)pp, p1 = *(const float4*)(pp + 4);
                float4 t0 = *(const float4*)tt, t1 = *(const float4*)(tt + 4);
                u0.x += p0.x + t0.x; u0.y += p0.y + t0.y; u0.z += p0.z + t0.z; u0.w += p0.w + t0.w;
                u1.x += p1.x + t1.x; u1.y += p1.y + t1.y; u1.z += p1.z + t1.z; u1.w += p1.w + t1.w;
            }
            unsigned short c8[8];
            c8[0] = f2bf(u0.x); c8[1] = f2bf(u0.y); c8[2] = f2bf(u0.z); c8[3] = f2bf(u0.w);
            c8[4] = f2bf(u1.x); c8[5] = f2bf(u1.y); c8[6] = f2bf(u1.z); c8[7] = f2bf(u1.w);
            *(bf16x8*)&Asm[row * 64 + ((cs ^ (row & 7)) * 8)] = *(bf16x8*)c8;
        }
        __syncthreads();
#pragma unroll
        for (int kk = 0; kk < 2; kk++) {
            bf16x8 af[4], bfr[JN];
#pragma unroll
            for (int i = 0; i < 4; i++) {
                int rowA = wm + i * 16 + (lane & 15);
                int ca = (kk * 4 + (lane >> 4)) ^ (rowA & 7);
                af[i] = *(const bf16x8*)&Asm[rowA * 64 + ca * 8];
            }
#pragma unroll
            for (int j = 0; j < JN; j++) {
                int rowB = wn + j * 16 + (lane & 15);
                int cb = (kk * 4 + (lane >> 4)) ^ (rowB & 7);
                bfr[j] = *(const bf16x8*)&Bsm[rowB * 64 + cb * 8];
            }
#pragma unroll
            for (int i = 0; i < 4; i++)
#pragma unroll
                for (int j = 0; j < JN; j++)
                    acc[i][j] = __builtin_amdgcn_mfma_f32_16x16x32_bf16(af[i], bfr[j], acc[i][j], 0, 0, 0);
        }
    }
#pragma unroll
    for (int i = 0; i < 4; i++)
#pragma unroll
        for (int j = 0; j < JN; j++)
#pragma unroll
            for (int r = 0; r < 4; r++) {
                int row = m0 + wm + i * 16 + (lane >> 4) * 4 + r;
                int col = n0 + wn + j * 16 + (lane & 15);
                size_t idx = (size_t)row * N + col;
                float v = acc[i][j][r];
                if (EPI == 1) Cb[idx] = f2bf(fmaxf(v, 0.f));
                if (EPI == 3) Cb[idx] = f2bf(v);
            }
}

// ---------------- bf16-A 64x64 GEMM with residual: C = R + A @ Bt^T (f32) ----------------
// 4 waves, wave = 32x32 (2x2 frags). LDS 16KB -> high occupancy, 256+ blocks.
__global__ __launch_bounds__(256) void gemm_bb(
    const unsigned short* __restrict__ A,   // [M,K] bf16
    const unsigned short* __restrict__ Bt,  // [N,K] bf16
    const float* __restrict__ R,            // [M,N] residual
    float* __restrict__ Cf,                 // [M,N] f32 out
    int M, int N, int K)
{
    __shared__ __align__(16) unsigned short Asm[64 * 64];
    __shared__ __align__(16) unsigned short Bsm[64 * 64];
    const int tid = threadIdx.x;
    const int lane = tid & 63, wid = tid >> 6;
    const int m0 = blockIdx.y * 64, n0 = blockIdx.x * 64;
    const int wm = (wid >> 1) * 32, wn = (wid & 1) * 32;

    f32x4 acc[2][2];
#pragma unroll
    for (int i = 0; i < 2; i++)
#pragma unroll
        for (int j = 0; j < 2; j++) acc[i][j] = (f32x4){0.f, 0.f, 0.f, 0.f};

    for (int k0 = 0; k0 < K; k0 += 64) {
        if (k0) __syncthreads();
#pragma unroll
        for (int it = 0; it < 2; it++) {
            int q = it * 256 + tid;
            int row = q >> 3;
            int cs = (q & 7) ^ (row & 7);
            const unsigned short* srcA = A + (size_t)(m0 + row) * K + k0 + cs * 8;
            const unsigned short* srcB = Bt + (size_t)(n0 + row) * K + k0 + cs * 8;
            __builtin_amdgcn_global_load_lds(
                (const __attribute__((address_space(1))) unsigned int*)srcA,
                (__attribute__((address_space(3))) unsigned int*)&Asm[(it * 256 + wid * 64) * 8],
                16, 0, 0);
            __builtin_amdgcn_global_load_lds(
                (const __attribute__((address_space(1))) unsigned int*)srcB,
                (__attribute__((address_space(3))) unsigned int*)&Bsm[(it * 256 + wid * 64) * 8],
                16, 0, 0);
        }
        __syncthreads();
#pragma unroll
        for (int kd = 0; kd < 2; kd++) {
            bf16x8 af[2], bfr[2];
#pragma unroll
            for (int i = 0; i < 2; i++) {
                int rowA = wm + i * 16 + (lane & 15);
                int ca = (kd * 4 + (lane >> 4)) ^ (rowA & 7);
                af[i] = *(const bf16x8*)&Asm[rowA * 64 + ca * 8];
                int rowB = wn + i * 16 + (lane & 15);
                int cb = (kd * 4 + (lane >> 4)) ^ (rowB & 7);
                bfr[i] = *(const bf16x8*)&Bsm[rowB * 64 + cb * 8];
            }
#pragma unroll
            for (int i = 0; i < 2; i++)
#pragma unroll
                for (int j = 0; j < 2; j++)
                    acc[i][j] = __builtin_amdgcn_mfma_f32_16x16x32_bf16(af[i], bfr[j], acc[i][j], 0, 0, 0);
        }
    }
#pragma unroll
    for (int i = 0; i < 2; i++)
#pragma unroll
        for (int j = 0; j < 2; j++)
#pragma unroll
            for (int r = 0; r < 4; r++) {
                int row = m0 + wm + i * 16 + (lane >> 4) * 4 + r;
                int col = n0 + wn + j * 16 + (lane & 15);
                size_t idx = (size_t)row * N + col;
                Cf[idx] = acc[i][j][r] + R[idx];
            }
}

// ---------------- LayerNorm (f32 -> f32) ----------------
__global__ __launch_bounds__(64) void ln_kernel(const float* __restrict__ in,
                                                float* __restrict__ out) {
    const int row = blockIdx.x, lane = threadIdx.x;
    const float* p = in + (size_t)row * DIM;
    float x[8];
#pragma unroll
    for (int i = 0; i < 8; i++) x[i] = p[lane + i * 64];
    float s = 0.f;
#pragma unroll
    for (int i = 0; i < 8; i++) s += x[i];
#pragma unroll
    for (int off = 32; off > 0; off >>= 1) s += __shfl_xor(s, off);
    const float m = s * (1.f / 512.f);
    float v = 0.f;
#pragma unroll
    for (int i = 0; i < 8; i++) { float d = x[i] - m; v += d * d; }
#pragma unroll
    for (int off = 32; off > 0; off >>= 1) v += __shfl_xor(v, off);
    v *= (1.f / 512.f);
    const float inv = 1.f / sqrtf(v + 1e-5f);
    float* q = out + (size_t)row * DIM;
#pragma unroll
    for (int i = 0; i < 8; i++) q[lane + i * 64] = (x[i] - m) * inv;
}

// ---------------- MFMA attention: block = (b, h, q-half), 2 waves ----------------
template<int CAUSAL>
__global__ __launch_bounds__(128) void attn_mfma(
    const unsigned short* __restrict__ Qb, int ldq,
    const unsigned short* __restrict__ Kb, int ldk,
    const unsigned short* __restrict__ Vb, int ldv,
    unsigned short* __restrict__ O)
{
    __shared__ __align__(16) unsigned short Ks[128 * 64];
    __shared__ __align__(16) unsigned short Vt[64 * 132];
    __shared__ __align__(16) unsigned short Ps[2][32 * 64];
    const int tid = threadIdx.x;
    const int lane = tid & 63, wid = tid >> 6;
    const int blk = blockIdx.x;
    const int qh = blk & 1;
    const int h = (blk >> 1) & 7;
    const int b = blk >> 4;
    const int tok0 = b * 128;
    const int wq = qh * 64 + wid * 32;
    const int kl = (CAUSAL && qh == 0) ? 64 : 128;

    if (tid < kl) {
        const unsigned short* Kg = Kb + (size_t)(tok0 + tid) * ldk + h * 64;
        const unsigned short* Vg = Vb + (size_t)(tok0 + tid) * ldv + h * 64;
        int r = tid;
#pragma unroll
        for (int c = 0; c < 8; c++) {
            bf16x8 kv = *(const bf16x8*)&Kg[c * 8];
            *(bf16x8*)&Ks[r * 64 + ((c ^ (r & 7)) * 8)] = kv;
            bf16x8 vv = *(const bf16x8*)&Vg[c * 8];
#pragma unroll
            for (int j = 0; j < 8; j++)
                Vt[(c * 8 + j) * 132 + r] = (unsigned short)vv[j];
        }
    }

    bf16x8 qa[2][2];
    {
        const unsigned short* Qg = Qb + (size_t)tok0 * ldq + h * 64;
#pragma unroll
        for (int i = 0; i < 2; i++)
#pragma unroll
            for (int kd = 0; kd < 2; kd++) {
                int qr = wq + i * 16 + (lane & 15);
                qa[i][kd] = *(const bf16x8*)&Qg[(size_t)qr * ldq + kd * 32 + (lane >> 4) * 8];
            }
    }
    __syncthreads();

    const int jmax = CAUSAL ? ((wq >> 4) + 2) : 8;
    const int kcmax = CAUSAL ? ((wq >> 5) + 1) : 4;

    float zr[2][4];
#pragma unroll
    for (int i = 0; i < 2; i++)
#pragma unroll
        for (int rr = 0; rr < 4; rr++) zr[i][rr] = 0.f;

    f32x4 oacc[2][4];
#pragma unroll
    for (int i = 0; i < 2; i++)
#pragma unroll
        for (int dt = 0; dt < 4; dt++) oacc[i][dt] = (f32x4){0.f, 0.f, 0.f, 0.f};

    for (int kb = 0; kb < 2; kb++) {
        int j0 = kb * 4;
        if (j0 >= jmax) break;
        int jn = jmax - j0; if (jn > 4) jn = 4;
        f32x4 sacc[2][4];
#pragma unroll
        for (int i = 0; i < 2; i++)
#pragma unroll
            for (int j = 0; j < 4; j++) sacc[i][j] = (f32x4){0.f, 0.f, 0.f, 0.f};
#pragma unroll 2
        for (int kd = 0; kd < 2; kd++) {
            for (int jj = 0; jj < jn; jj++) {
                int kr = (j0 + jj) * 16 + (lane & 15);
                int ch = (kd * 4 + (lane >> 4)) ^ (kr & 7);
                bf16x8 kf = *(const bf16x8*)&Ks[kr * 64 + ch * 8];
                sacc[0][jj] = __builtin_amdgcn_mfma_f32_16x16x32_bf16(qa[0][kd], kf, sacc[0][jj], 0, 0, 0);
                sacc[1][jj] = __builtin_amdgcn_mfma_f32_16x16x32_bf16(qa[1][kd], kf, sacc[1][jj], 0, 0, 0);
            }
        }
#pragma unroll
        for (int i = 0; i < 2; i++) {
            int qbase = wq + i * 16 + (lane >> 4) * 4;
            for (int jj = 0; jj < jn; jj++) {
                int kcol = (j0 + jj) * 16 + (lane & 15);
#pragma unroll
                for (int rr = 0; rr < 4; rr++) {
                    float p = __expf(sacc[i][jj][rr] * 0.125f);
                    if (CAUSAL && kcol > qbase + rr) p = 0.f;
                    zr[i][rr] += p;
                    int prow = i * 16 + (lane >> 4) * 4 + rr;
                    int ch = ((jj * 2 + ((lane & 15) >> 3)) ^ (prow & 7));
                    Ps[wid][prow * 64 + ch * 8 + (lane & 7)] = f2bf(p);
                }
            }
        }
        int kcn = kcmax - kb * 2; if (kcn > 2) kcn = 2;
        for (int kcl = 0; kcl < kcn; kcl++) {
            bf16x8 pa[2];
#pragma unroll
            for (int i = 0; i < 2; i++) {
                int prow = i * 16 + (lane & 15);
                int ch = (kcl * 4 + (lane >> 4)) ^ (prow & 7);
                pa[i] = *(const bf16x8*)&Ps[wid][prow * 64 + ch * 8];
            }
            int kcg = kb * 2 + kcl;
#pragma unroll
            for (int dt = 0; dt < 4; dt++) {
                int d = dt * 16 + (lane & 15);
                bf16x8 vf = *(const bf16x8*)&Vt[d * 132 + (kcg * 4 + (lane >> 4)) * 8];
                oacc[0][dt] = __builtin_amdgcn_mfma_f32_16x16x32_bf16(pa[0], vf, oacc[0][dt], 0, 0, 0);
                oacc[1][dt] = __builtin_amdgcn_mfma_f32_16x16x32_bf16(pa[1], vf, oacc[1][dt], 0, 0, 0);
            }
        }
    }
#pragma unroll
    for (int i = 0; i < 2; i++)
#pragma unroll
        for (int rr = 0; rr < 4; rr++) {
            float z = zr[i][rr];
            z += __shfl_xor(z, 1); z += __shfl_xor(z, 2);
            z += __shfl_xor(z, 4); z += __shfl_xor(z, 8);
            zr[i][rr] = 1.f / (z + 1e-9f);
        }
#pragma unroll
    for (int i = 0; i < 2; i++)
#pragma unroll
        for (int dt = 0; dt < 4; dt++)
#pragma unroll
            for (int rr = 0; rr < 4; rr++) {
                int qrow = tok0 + wq + i * 16 + (lane >> 4) * 4 + rr;
                O[(size_t)qrow * DIM + h * 64 + dt * 16 + (lane & 15)] =
                    f2bf(oacc[i][dt][rr] * zr[i][rr]);
            }
}

// ---------------- generator: tiled 128x128 GEMM + lse partials ----------------
// grid (250, 16), 4 waves. Stores f32 logits; per-row partial max/sumexp over 128 cols.
__global__ __launch_bounds__(256) void gemm_gen(
    const float* __restrict__ Af,           // [2048,512] f32
    const unsigned short* __restrict__ Bt,  // [32000,512] bf16
    float* __restrict__ Out,                // [2048,32000]
    float* __restrict__ pm,                 // [2048,256]
    float* __restrict__ psum)               // [2048,256]
{
    __shared__ __align__(16) unsigned short Asm[128 * 64];
    __shared__ __align__(16) unsigned short Bsm[128 * 64];
    __shared__ float pml[4][64];
    __shared__ float psl[4][64];
    const int tid = threadIdx.x;
    const int lane = tid & 63, wid = tid >> 6;
    const int m0 = blockIdx.y * 128, n0 = blockIdx.x * 128;
    const int wm = (wid >> 1) * 64, wn = (wid & 1) * 64;

    f32x4 acc[4][4];
#pragma unroll
    for (int i = 0; i < 4; i++)
#pragma unroll
        for (int j = 0; j < 4; j++) acc[i][j] = (f32x4){0.f, 0.f, 0.f, 0.f};

    for (int k0 = 0; k0 < 512; k0 += 64) {
        if (k0) __syncthreads();
#pragma unroll
        for (int it = 0; it < 4; it++) {
            int q = (wid * 4 + it) * 64 + lane;
            int row = q >> 3;
            int cs = (q & 7) ^ (row & 7);
            const unsigned short* srcB = Bt + (size_t)(n0 + row) * 512 + k0 + cs * 8;
            __builtin_amdgcn_global_load_lds(
                (const __attribute__((address_space(1))) unsigned int*)srcB,
                (__attribute__((address_space(3))) unsigned int*)&Bsm[(wid * 4 + it) * 512],
                16, 0, 0);
        }
#pragma unroll
        for (int it = 0; it < 4; it++) {
            int q = (wid * 4 + it) * 64 + lane;
            int row = q >> 3;
            int cs = q & 7;
            const float* s = Af + (size_t)(m0 + row) * 512 + k0 + cs * 8;
            float4 u0 = *(const float4*)s, u1 = *(const float4*)(s + 4);
            unsigned short c8[8];
            c8[0] = f2bf(u0.x); c8[1] = f2bf(u0.y); c8[2] = f2bf(u0.z); c8[3] = f2bf(u0.w);
            c8[4] = f2bf(u1.x); c8[5] = f2bf(u1.y); c8[6] = f2bf(u1.z); c8[7] = f2bf(u1.w);
            *(bf16x8*)&Asm[row * 64 + ((cs ^ (row & 7)) * 8)] = *(bf16x8*)c8;
        }
        __syncthreads();
#pragma unroll
        for (int kk = 0; kk < 2; kk++) {
            bf16x8 af[4], bfr[4];
#pragma unroll
            for (int i = 0; i < 4; i++) {
                int rowA = wm + i * 16 + (lane & 15);
                int ca = (kk * 4 + (lane >> 4)) ^ (rowA & 7);
                af[i] = *(const bf16x8*)&Asm[rowA * 64 + ca * 8];
                int rowB = wn + i * 16 + (lane & 15);
                int cb = (kk * 4 + (lane >> 4)) ^ (rowB & 7);
                bfr[i] = *(const bf16x8*)&Bsm[rowB * 64 + cb * 8];
            }
#pragma unroll
            for (int i = 0; i < 4; i++)
#pragma unroll
                for (int j = 0; j < 4; j++)
                    acc[i][j] = __builtin_amdgcn_mfma_f32_16x16x32_bf16(af[i], bfr[j], acc[i][j], 0, 0, 0);
        }
    }
    // ---- per-wave partial max/sumexp over its 64 cols, per row ----
#pragma unroll
    for (int i = 0; i < 4; i++) {
#pragma unroll
        for (int r = 0; r < 4; r++) {
            float mx = fmaxf(fmaxf(acc[i][0][r], acc[i][1][r]),
                             fmaxf(acc[i][2][r], acc[i][3][r]));
            mx = fmaxf(mx, __shfl_xor(mx, 1));
            mx = fmaxf(mx, __shfl_xor(mx, 2));
            mx = fmaxf(mx, __shfl_xor(mx, 4));
            mx = fmaxf(mx, __shfl_xor(mx, 8));
            float s = __expf(acc[i][0][r] - mx) + __expf(acc[i][1][r] - mx) +
                      __expf(acc[i][2][r] - mx) + __expf(acc[i][3][r] - mx);
            s += __shfl_xor(s, 1); s += __shfl_xor(s, 2);
            s += __shfl_xor(s, 4); s += __shfl_xor(s, 8);
            if ((lane & 15) == 0) {
                int li = i * 16 + (lane >> 4) * 4 + r;  // row within wave's 64
                pml[wid][li] = mx;
                psl[wid][li] = s;
            }
        }
    }
    __syncthreads();
    if (tid < 128) {
        int half = tid >> 6, lr = tid & 63;   // waves {0,1} rows 0-63, {2,3} rows 64-127
        int wa = half * 2, wb = half * 2 + 1;
        float ma = pml[wa][lr], mb = pml[wb][lr];
        float m = fmaxf(ma, mb);
        float s = psl[wa][lr] * __expf(ma - m) + psl[wb][lr] * __expf(mb - m);
        pm[(size_t)(m0 + tid) * 256 + blockIdx.x] = m;
        psum[(size_t)(m0 + tid) * 256 + blockIdx.x] = s;
    }
    // ---- store logits ----
#pragma unroll
    for (int i = 0; i < 4; i++)
#pragma unroll
        for (int j = 0; j < 4; j++)
#pragma unroll
            for (int r = 0; r < 4; r++) {
                int row = m0 + wm + i * 16 + (lane >> 4) * 4 + r;
                int col = n0 + wn + j * 16 + (lane & 15);
                Out[(size_t)row * VOCAB + col] = acc[i][j][r];
            }
}

// ---------------- lse reduce ----------------
__global__ __launch_bounds__(64) void lse_kernel(const float* __restrict__ pm,
                                                 const float* __restrict__ psum,
                                                 float* __restrict__ lse) {
    const int row = blockIdx.x, t = threadIdx.x;
    float m = -1e30f, s = 0.f;
    for (int nb = t; nb < 250; nb += 64) {
        float mm = pm[(size_t)row * 256 + nb];
        float ss = psum[(size_t)row * 256 + nb];
        float M = fmaxf(m, mm);
        s = s * __expf(m - M) + ss * __expf(mm - M);
        m = M;
    }
#pragma unroll
    for (int off = 32; off > 0; off >>= 1) {
        float mo = __shfl_xor(m, off), so = __shfl_xor(s, off);
        float M = fmaxf(m, mo);
        s = s * __expf(m - M) + so * __expf(mo - M);
        m = M;
    }
    if (t == 0) lse[row] = m + __logf(s);
}

// ---------------- subtract lse ----------------
__global__ __launch_bounds__(256) void sub_kernel(float* __restrict__ out,
                                                  const float* __restrict__ lse) {
    const int row = blockIdx.x;
    const float l = lse[row];
    float4* p = (float4*)(out + (size_t)row * VOCAB);
    for (int i = threadIdx.x; i < VOCAB / 4; i += 256) {
        float4 v = p[i];
        p[i] = make_float4(v.x - l, v.y - l, v.z - l, v.w - l);
    }
}

// ---------------- orchestration ----------------
extern "C" void kernel_launch(void* const* d_in, const int* in_sizes, int n_in,
                              void* d_out, int out_size, void* d_ws, size_t ws_size,
                              hipStream_t stream) {
    const float* emb_src  = (const float*)d_in[0];
    const float* emb_tgt  = (const float*)d_in[1];
    const float* pos_emb  = (const float*)d_in[2];
    const float* time_emb = (const float*)d_in[3];
    const float* Wqkv_e   = (const float*)d_in[4];
    const float* Wo_e     = (const float*)d_in[5];
    const float* W1_e     = (const float*)d_in[6];
    const float* W2_e     = (const float*)d_in[7];
    const float* Wqkv_d   = (const float*)d_in[8];
    const float* Wo_d     = (const float*)d_in[9];
    const float* W1_d     = (const float*)d_in[10];
    const float* W2_d     = (const float*)d_in[11];
    const float* Wq_x     = (const float*)d_in[12];
    const float* Wkv_x    = (const float*)d_in[13];
    const float* Wo_x     = (const float*)d_in[14];
    const float* Wgen     = (const float*)d_in[15];
    const int* src_tokens = (const int*)d_in[16];
    const int* tgt_tokens = (const int*)d_in[17];
    const int* src_pos    = (const int*)d_in[18];
    const int* tgt_pos    = (const int*)d_in[19];

    char* w = (char*)d_ws;
    float* x_e = (float*)(w);                                     // 4MB
    float* x_d = (float*)(w + (4u << 20));                        // 4MB
    float* tmp = (float*)(w + (8u << 20));                        // 4MB
    unsigned short* qkv_bf = (unsigned short*)(w + (12u << 20));  // 6MB
    unsigned short* kvx_bf = (unsigned short*)(w + (18u << 20));  // 4MB
    unsigned short* o_bf   = (unsigned short*)(w + (22u << 20));  // 2MB
    unsigned short* q_bf   = (unsigned short*)(w + (24u << 20));  // 2MB
    unsigned short* hid_bf = (unsigned short*)(w + (26u << 20));  // 8MB
    float* pm   = (float*)(w + (34u << 20));                      // 2MB
    float* psum = (float*)(w + (36u << 20));                      // 2MB
    float* lse  = (float*)(w + (38u << 20));                      // 8KB
    unsigned short* wts    = (unsigned short*)(w + (39u << 20));  // ~47.4MB

    unsigned short* WqkvE_t = wts;
    unsigned short* WoE_t   = WqkvE_t + 786432;
    unsigned short* W1E_t   = WoE_t   + 262144;
    unsigned short* W2E_t   = W1E_t   + 1048576;
    unsigned short* WqkvD_t = W2E_t   + 1048576;
    unsigned short* WoD_t   = WqkvD_t + 786432;
    unsigned short* W1D_t   = WoD_t   + 262144;
    unsigned short* W2D_t   = W1D_t   + 1048576;
    unsigned short* WqX_t   = W2D_t   + 1048576;
    unsigned short* WkvX_t  = WqX_t   + 262144;
    unsigned short* WoX_t   = WkvX_t  + 524288;
    unsigned short* Wgen_t  = WoX_t   + 262144;

    float* out = (float*)d_out;

    WTab tab;
    auto set = [&](int i, const float* s, unsigned short* d, int K, int N, int t0) {
        tab.d[i].src = s; tab.d[i].dst = d; tab.d[i].K = K; tab.d[i].N = N;
        tab.d[i].t0 = t0; tab.d[i].pad = 0;
    };
    set(0,  Wqkv_e, WqkvE_t, 512, 1536, 0);
    set(1,  Wo_e,   WoE_t,   512, 512,  768);
    set(2,  W1_e,   W1E_t,   512, 2048, 1024);
    set(3,  W2_e,   W2E_t,   2048, 512, 2048);
    set(4,  Wqkv_d, WqkvD_t, 512, 1536, 3072);
    set(5,  Wo_d,   WoD_t,   512, 512,  3840);
    set(6,  W1_d,   W1D_t,   512, 2048, 4096);
    set(7,  W2_d,   W2D_t,   2048, 512, 5120);
    set(8,  Wq_x,   WqX_t,   512, 512,  6144);
    set(9,  Wkv_x,  WkvX_t,  512, 1024, 6400);
    set(10, Wo_x,   WoX_t,   512, 512,  6912);
    set(11, Wgen,   Wgen_t,  512, 32000, 7168);
    wconv_all<<<23168, 256, 0, stream>>>(tab);

    const int n4 = NTOK * (DIM / 4);
    dim3 eb(256), eg((n4 + 255) / 256);
    embed_kernel<<<eg, eb, 0, stream>>>(emb_src, src_tokens, pos_emb, src_pos, x_e, n4);
    embed_kernel<<<eg, eb, 0, stream>>>(emb_tgt, tgt_tokens, pos_emb, tgt_pos, x_d, n4);

    const dim3 gQKV(1536 / 128, NTOK / 128), gFF(DFF / 128, NTOK / 128),
               gKV(1024 / 128, NTOK / 128),  gQX(512 / 64, NTOK / 128),
               g64(512 / 64, NTOK / 64);     // 8 x 32 = 256 blocks

    // -------- encoder --------
    for (int t = 0; t < DEPTH; t++) {
        const float* trow = time_emb + (size_t)t * DIM;
        gemm_u<2, 3, 128><<<gQKV, 256, 0, stream>>>(x_e, WqkvE_t, qkv_bf, pos_emb, trow, NTOK, 1536, 512);
        attn_mfma<0><<<256, 128, 0, stream>>>(qkv_bf, 1536, qkv_bf + 512, 1536, qkv_bf + 1024, 1536, o_bf);
        gemm_bb<<<g64, 256, 0, stream>>>(o_bf, WoE_t, x_e, tmp, NTOK, 512, 512);
        ln_kernel<<<NTOK, 64, 0, stream>>>(tmp, x_e);
        gemm_u<1, 1, 128><<<gFF, 256, 0, stream>>>(x_e, W1E_t, hid_bf, nullptr, nullptr, NTOK, DFF, 512);
        gemm_bb<<<g64, 256, 0, stream>>>(hid_bf, W2E_t, x_e, tmp, NTOK, 512, 2048);
        ln_kernel<<<NTOK, 64, 0, stream>>>(tmp, x_e);
    }

    // cross-attn K/V from final encoder state
    gemm_u<1, 3, 128><<<gKV, 256, 0, stream>>>(x_e, WkvX_t, kvx_bf, nullptr, nullptr, NTOK, 1024, 512);

    // -------- decoder --------
    for (int t = 0; t < DEPTH; t++) {
        const float* trow = time_emb + (size_t)t * DIM;
        gemm_u<2, 3, 128><<<gQKV, 256, 0, stream>>>(x_d, WqkvD_t, qkv_bf, pos_emb, trow, NTOK, 1536, 512);
        attn_mfma<1><<<256, 128, 0, stream>>>(qkv_bf, 1536, qkv_bf + 512, 1536, qkv_bf + 1024, 1536, o_bf);
        gemm_bb<<<g64, 256, 0, stream>>>(o_bf, WoD_t, x_d, tmp, NTOK, 512, 512);
        ln_kernel<<<NTOK, 64, 0, stream>>>(tmp, x_d);

        gemm_u<2, 3, 64><<<gQX, 256, 0, stream>>>(x_d, WqX_t, q_bf, pos_emb, trow, NTOK, 512, 512);
        attn_mfma<0><<<256, 128, 0, stream>>>(q_bf, 512, kvx_bf, 1024, kvx_bf + 512, 1024, o_bf);
        gemm_bb<<<g64, 256, 0, stream>>>(o_bf, WoX_t, x_d, tmp, NTOK, 512, 512);
        ln_kernel<<<NTOK, 64, 0, stream>>>(tmp, x_d);

        gemm_u<1, 1, 128><<<gFF, 256, 0, stream>>>(x_d, W1D_t, hid_bf, nullptr, nullptr, NTOK, DFF, 512);
        gemm_bb<<<g64, 256, 0, stream>>>(hid_bf, W2D_t, x_d, tmp, NTOK, 512, 2048);
        ln_kernel<<<NTOK, 64, 0, stream>>>(tmp, x_d);
    }

    // -------- generator + log_softmax --------
    gemm_gen<<<dim3(250, 16), 256, 0, stream>>>(x_d, Wgen_t, out, pm, psum);
    lse_kernel<<<NTOK, 64, 0, stream>>>(pm, psum, lse);
    sub_kernel<<<NTOK, 256, 0, stream>>>(out, lse);
}

// Round 7
// 2053.044 us; speedup vs baseline: 3.9176x; 1.0411x over previous
//
#include <hip/hip_runtime.h>
#include <hip/hip_bf16.h>
#include <math.h>

#define H 8
#define DK 64
#define DIM 512
#define DFF 2048
#define DEPTH 8
#define VOCAB 32000
#define NTOK 2048

typedef float f32x4 __attribute__((ext_vector_type(4)));
typedef short bf16x8 __attribute__((ext_vector_type(8)));

static __device__ __forceinline__ unsigned short f2bf(float f) {
    unsigned u = __float_as_uint(f);
    return (unsigned short)((u + 0x7FFFu + ((u >> 16) & 1u)) >> 16);
}

#define GLL(src, dst) __builtin_amdgcn_global_load_lds( \
    (const __attribute__((address_space(1))) unsigned int*)(src), \
    (__attribute__((address_space(3))) unsigned int*)(dst), 16, 0, 0)

// ---------------- embed ----------------
__global__ void embed_kernel(const float* __restrict__ emb, const int* __restrict__ tok,
                             const float* __restrict__ pos, const int* __restrict__ pidx,
                             float* __restrict__ out, int n4) {
    int idx = blockIdx.x * blockDim.x + threadIdx.x;
    if (idx >= n4) return;
    int i = idx >> 7, d = idx & 127;
    float4 a = ((const float4*)emb)[(size_t)tok[i] * 128 + d];
    float4 b = ((const float4*)pos)[(size_t)pidx[i] * 128 + d];
    ((float4*)out)[idx] = make_float4(a.x + b.x, a.y + b.y, a.z + b.z, a.w + b.w);
}

// ---------------- batched weight convert+transpose ----------------
struct WD { const float* src; unsigned short* dst; int K; int N; int t0; int pad; };
struct WTab { WD d[12]; };

__global__ __launch_bounds__(256) void wconv_all(WTab tab) {
    __shared__ float t[32][33];
    const int bid = blockIdx.x;
    int w = 0;
#pragma unroll
    for (int i = 1; i < 12; i++) if (bid >= tab.d[i].t0) w = i;
    const float* W = tab.d[w].src;
    unsigned short* Wt = tab.d[w].dst;
    const int K = tab.d[w].K, N = tab.d[w].N;
    const int lt = bid - tab.d[w].t0;
    const int txc = N >> 5;
    const int n0 = (lt % txc) << 5, k0 = (lt / txc) << 5;
    const int tid = threadIdx.x;
    const int tx = tid & 31, ty = tid >> 5;
#pragma unroll
    for (int i = 0; i < 32; i += 8)
        t[ty + i][tx] = W[(size_t)(k0 + ty + i) * N + n0 + tx];
    __syncthreads();
#pragma unroll
    for (int i = 0; i < 32; i += 8)
        Wt[(size_t)(n0 + ty + i) * K + k0 + tx] = f2bf(t[tx][ty + i]);
}

// ---------------- gemm_u: C = A' @ Bt^T (f32 A staged to bf16) ----------------
// EPI 1: relu->bf16; 3: bf16.
template<int EPI>
__global__ __launch_bounds__(256) void gemm_u(
    const float* __restrict__ Af,
    const unsigned short* __restrict__ Bt,
    unsigned short* __restrict__ Cb,
    int M, int N, int K)
{
    __shared__ __align__(16) unsigned short Asm[128 * 64];
    __shared__ __align__(16) unsigned short Bsm[128 * 64];
    const int tid = threadIdx.x;
    const int lane = tid & 63, wid = tid >> 6;
    const int m0 = blockIdx.y * 128, n0 = blockIdx.x * 128;
    const int wm = (wid >> 1) * 64, wn = (wid & 1) * 64;

    f32x4 acc[4][4];
#pragma unroll
    for (int i = 0; i < 4; i++)
#pragma unroll
        for (int j = 0; j < 4; j++) acc[i][j] = (f32x4){0.f, 0.f, 0.f, 0.f};

    for (int k0 = 0; k0 < K; k0 += 64) {
        if (k0) __syncthreads();
#pragma unroll
        for (int it = 0; it < 4; it++) {
            int q = (wid * 4 + it) * 64 + lane;
            int row = q >> 3;
            int cs = (q & 7) ^ (row & 7);
            GLL(Bt + (size_t)(n0 + row) * K + k0 + cs * 8, &Bsm[(wid * 4 + it) * 512]);
        }
#pragma unroll
        for (int it = 0; it < 4; it++) {
            int q = (wid * 4 + it) * 64 + lane;
            int row = q >> 3;
            int cs = q & 7;
            const float* s = Af + (size_t)(m0 + row) * K + k0 + cs * 8;
            float4 u0 = *(const float4*)s, u1 = *(const float4*)(s + 4);
            unsigned short c8[8];
            c8[0] = f2bf(u0.x); c8[1] = f2bf(u0.y); c8[2] = f2bf(u0.z); c8[3] = f2bf(u0.w);
            c8[4] = f2bf(u1.x); c8[5] = f2bf(u1.y); c8[6] = f2bf(u1.z); c8[7] = f2bf(u1.w);
            *(bf16x8*)&Asm[row * 64 + ((cs ^ (row & 7)) * 8)] = *(bf16x8*)c8;
        }
        __syncthreads();
#pragma unroll
        for (int kk = 0; kk < 2; kk++) {
            bf16x8 af[4], bfr[4];
#pragma unroll
            for (int i = 0; i < 4; i++) {
                int rowA = wm + i * 16 + (lane & 15);
                int ca = (kk * 4 + (lane >> 4)) ^ (rowA & 7);
                af[i] = *(const bf16x8*)&Asm[rowA * 64 + ca * 8];
                int rowB = wn + i * 16 + (lane & 15);
                int cb = (kk * 4 + (lane >> 4)) ^ (rowB & 7);
                bfr[i] = *(const bf16x8*)&Bsm[rowB * 64 + cb * 8];
            }
#pragma unroll
            for (int i = 0; i < 4; i++)
#pragma unroll
                for (int j = 0; j < 4; j++)
                    acc[i][j] = __builtin_amdgcn_mfma_f32_16x16x32_bf16(af[i], bfr[j], acc[i][j], 0, 0, 0);
        }
    }
#pragma unroll
    for (int i = 0; i < 4; i++)
#pragma unroll
        for (int j = 0; j < 4; j++)
#pragma unroll
            for (int r = 0; r < 4; r++) {
                int row = m0 + wm + i * 16 + (lane >> 4) * 4 + r;
                int col = n0 + wn + j * 16 + (lane & 15);
                size_t idx = (size_t)row * N + col;
                float v = acc[i][j][r];
                if (EPI == 1) Cb[idx] = f2bf(fmaxf(v, 0.f));
                if (EPI == 3) Cb[idx] = f2bf(v);
            }
}

// ---------------- gemm_bb: C = R + A @ Bt^T (bf16 A, 64x64 tile, f32 out) ----------------
__global__ __launch_bounds__(256) void gemm_bb(
    const unsigned short* __restrict__ A,
    const unsigned short* __restrict__ Bt,
    const float* __restrict__ R,
    float* __restrict__ Cf,
    int M, int N, int K)
{
    __shared__ __align__(16) unsigned short Asm[64 * 64];
    __shared__ __align__(16) unsigned short Bsm[64 * 64];
    const int tid = threadIdx.x;
    const int lane = tid & 63, wid = tid >> 6;
    const int m0 = blockIdx.y * 64, n0 = blockIdx.x * 64;
    const int wm = (wid >> 1) * 32, wn = (wid & 1) * 32;

    f32x4 acc[2][2];
#pragma unroll
    for (int i = 0; i < 2; i++)
#pragma unroll
        for (int j = 0; j < 2; j++) acc[i][j] = (f32x4){0.f, 0.f, 0.f, 0.f};

    for (int k0 = 0; k0 < K; k0 += 64) {
        if (k0) __syncthreads();
#pragma unroll
        for (int it = 0; it < 2; it++) {
            int q = it * 256 + tid;
            int row = q >> 3;
            int cs = (q & 7) ^ (row & 7);
            GLL(A + (size_t)(m0 + row) * K + k0 + cs * 8, &Asm[(it * 256 + wid * 64) * 8]);
            GLL(Bt + (size_t)(n0 + row) * K + k0 + cs * 8, &Bsm[(it * 256 + wid * 64) * 8]);
        }
        __syncthreads();
#pragma unroll
        for (int kd = 0; kd < 2; kd++) {
            bf16x8 af[2], bfr[2];
#pragma unroll
            for (int i = 0; i < 2; i++) {
                int rowA = wm + i * 16 + (lane & 15);
                int ca = (kd * 4 + (lane >> 4)) ^ (rowA & 7);
                af[i] = *(const bf16x8*)&Asm[rowA * 64 + ca * 8];
                int rowB = wn + i * 16 + (lane & 15);
                int cb = (kd * 4 + (lane >> 4)) ^ (rowB & 7);
                bfr[i] = *(const bf16x8*)&Bsm[rowB * 64 + cb * 8];
            }
#pragma unroll
            for (int i = 0; i < 2; i++)
#pragma unroll
                for (int j = 0; j < 2; j++)
                    acc[i][j] = __builtin_amdgcn_mfma_f32_16x16x32_bf16(af[i], bfr[j], acc[i][j], 0, 0, 0);
        }
    }
#pragma unroll
    for (int i = 0; i < 2; i++)
#pragma unroll
        for (int j = 0; j < 2; j++)
#pragma unroll
            for (int r = 0; r < 4; r++) {
                int row = m0 + wm + i * 16 + (lane >> 4) * 4 + r;
                int col = n0 + wn + j * 16 + (lane & 15);
                size_t idx = (size_t)row * N + col;
                Cf[idx] = acc[i][j][r] + R[idx];
            }
}

// ---------------- LayerNorm (f32 -> f32) ----------------
__global__ __launch_bounds__(64) void ln_kernel(const float* __restrict__ in,
                                                float* __restrict__ out) {
    const int row = blockIdx.x, lane = threadIdx.x;
    const float* p = in + (size_t)row * DIM;
    float x[8];
#pragma unroll
    for (int i = 0; i < 8; i++) x[i] = p[lane + i * 64];
    float s = 0.f;
#pragma unroll
    for (int i = 0; i < 8; i++) s += x[i];
#pragma unroll
    for (int off = 32; off > 0; off >>= 1) s += __shfl_xor(s, off);
    const float m = s * (1.f / 512.f);
    float v = 0.f;
#pragma unroll
    for (int i = 0; i < 8; i++) { float d = x[i] - m; v += d * d; }
#pragma unroll
    for (int off = 32; off > 0; off >>= 1) v += __shfl_xor(v, off);
    v *= (1.f / 512.f);
    const float inv = 1.f / sqrtf(v + 1e-5f);
    float* q = out + (size_t)row * DIM;
#pragma unroll
    for (int i = 0; i < 8; i++) q[lane + i * 64] = (x[i] - m) * inv;
}

// ---------------- shared attention core (phase 2) ----------------
// Qs/Ks: [128][64] chunk-swizzled bf16; Vt: [64][132] V^T; Psw: this wave's 32x64 P buf.
template<int CAUSAL>
static __device__ __forceinline__ void attn_core(
    const unsigned short* Qs, const unsigned short* Ks, const unsigned short* Vt,
    unsigned short* Psw, int wq, int lane, int tok0, int h,
    unsigned short* __restrict__ O)
{
    bf16x8 qa[2][2];
#pragma unroll
    for (int i = 0; i < 2; i++)
#pragma unroll
        for (int kd = 0; kd < 2; kd++) {
            int qr = wq + i * 16 + (lane & 15);
            int ch = (kd * 4 + (lane >> 4)) ^ (qr & 7);
            qa[i][kd] = *(const bf16x8*)&Qs[qr * 64 + ch * 8];
        }

    const int jmax = CAUSAL ? ((wq >> 4) + 2) : 8;
    const int kcmax = CAUSAL ? ((wq >> 5) + 1) : 4;

    float zr[2][4];
#pragma unroll
    for (int i = 0; i < 2; i++)
#pragma unroll
        for (int rr = 0; rr < 4; rr++) zr[i][rr] = 0.f;
    f32x4 oacc[2][4];
#pragma unroll
    for (int i = 0; i < 2; i++)
#pragma unroll
        for (int dt = 0; dt < 4; dt++) oacc[i][dt] = (f32x4){0.f, 0.f, 0.f, 0.f};

    for (int kb = 0; kb < 2; kb++) {
        int j0 = kb * 4;
        if (j0 >= jmax) break;
        int jn = jmax - j0; if (jn > 4) jn = 4;
        f32x4 sacc[2][4];
#pragma unroll
        for (int i = 0; i < 2; i++)
#pragma unroll
            for (int j = 0; j < 4; j++) sacc[i][j] = (f32x4){0.f, 0.f, 0.f, 0.f};
#pragma unroll 2
        for (int kd = 0; kd < 2; kd++) {
            for (int jj = 0; jj < jn; jj++) {
                int kr = (j0 + jj) * 16 + (lane & 15);
                int ch = (kd * 4 + (lane >> 4)) ^ (kr & 7);
                bf16x8 kf = *(const bf16x8*)&Ks[kr * 64 + ch * 8];
                sacc[0][jj] = __builtin_amdgcn_mfma_f32_16x16x32_bf16(qa[0][kd], kf, sacc[0][jj], 0, 0, 0);
                sacc[1][jj] = __builtin_amdgcn_mfma_f32_16x16x32_bf16(qa[1][kd], kf, sacc[1][jj], 0, 0, 0);
            }
        }
#pragma unroll
        for (int i = 0; i < 2; i++) {
            int qbase = wq + i * 16 + (lane >> 4) * 4;
            for (int jj = 0; jj < jn; jj++) {
                int kcol = (j0 + jj) * 16 + (lane & 15);
#pragma unroll
                for (int rr = 0; rr < 4; rr++) {
                    float p = __expf(sacc[i][jj][rr] * 0.125f);
                    if (CAUSAL && kcol > qbase + rr) p = 0.f;
                    zr[i][rr] += p;
                    int prow = i * 16 + (lane >> 4) * 4 + rr;
                    int ch = ((jj * 2 + ((lane & 15) >> 3)) ^ (prow & 7));
                    Psw[prow * 64 + ch * 8 + (lane & 7)] = f2bf(p);
                }
            }
        }
        int kcn = kcmax - kb * 2; if (kcn > 2) kcn = 2;
        for (int kcl = 0; kcl < kcn; kcl++) {
            bf16x8 pa[2];
#pragma unroll
            for (int i = 0; i < 2; i++) {
                int prow = i * 16 + (lane & 15);
                int ch = (kcl * 4 + (lane >> 4)) ^ (prow & 7);
                pa[i] = *(const bf16x8*)&Psw[prow * 64 + ch * 8];
            }
            int kcg = kb * 2 + kcl;
#pragma unroll
            for (int dt = 0; dt < 4; dt++) {
                int d = dt * 16 + (lane & 15);
                bf16x8 vf = *(const bf16x8*)&Vt[d * 132 + (kcg * 4 + (lane >> 4)) * 8];
                oacc[0][dt] = __builtin_amdgcn_mfma_f32_16x16x32_bf16(pa[0], vf, oacc[0][dt], 0, 0, 0);
                oacc[1][dt] = __builtin_amdgcn_mfma_f32_16x16x32_bf16(pa[1], vf, oacc[1][dt], 0, 0, 0);
            }
        }
    }
#pragma unroll
    for (int i = 0; i < 2; i++)
#pragma unroll
        for (int rr = 0; rr < 4; rr++) {
            float z = zr[i][rr];
            z += __shfl_xor(z, 1); z += __shfl_xor(z, 2);
            z += __shfl_xor(z, 4); z += __shfl_xor(z, 8);
            zr[i][rr] = 1.f / (z + 1e-9f);
        }
#pragma unroll
    for (int i = 0; i < 2; i++)
#pragma unroll
        for (int dt = 0; dt < 4; dt++)
#pragma unroll
            for (int rr = 0; rr < 4; rr++) {
                int qrow = tok0 + wq + i * 16 + (lane >> 4) * 4 + rr;
                O[(size_t)qrow * DIM + h * 64 + dt * 16 + (lane & 15)] =
                    f2bf(oacc[i][dt][rr] * zr[i][rr]);
            }
}

// ---------------- fused QKV-GEMM + self-attention ----------------
// block = (b,h), 4 waves. Phase 1: [128 tok x 192] = xp @ Wqkv head-slice.
// Phase 1.5: acc -> LDS (swizzled Q/K, transposed V). Phase 2: attention.
template<int CAUSAL>
__global__ __launch_bounds__(256) void fused_attn(
    const float* __restrict__ Xf,
    const float* __restrict__ pos,
    const float* __restrict__ trow,
    const unsigned short* __restrict__ WqkvT,   // [1536,512] bf16
    unsigned short* __restrict__ O)
{
    __shared__ __align__(16) unsigned short smem[33024];  // 64.5 KB, phase-aliased
    unsigned short* Asm = smem;             // [128*64]  (phase 1)
    unsigned short* Bsm = smem + 8192;      // [192*64]  (phase 1)
    unsigned short* Qs  = smem;             // [128*64]  (phase 2)
    unsigned short* Ks  = smem + 8192;      // [128*64]
    unsigned short* Vt  = smem + 16384;     // [64*132]
    const int tid = threadIdx.x;
    const int lane = tid & 63, wid = tid >> 6;
    unsigned short* Psw = smem + 24832 + wid * 2048;
    const int b = blockIdx.x >> 3, h = blockIdx.x & 7;
    const int tok0 = b * 128;
    const int wq = wid * 32;

    f32x4 acc[2][12];   // cols: 0-3 Q, 4-7 K, 8-11 V
#pragma unroll
    for (int i = 0; i < 2; i++)
#pragma unroll
        for (int c = 0; c < 12; c++) acc[i][c] = (f32x4){0.f, 0.f, 0.f, 0.f};

    for (int k0 = 0; k0 < 512; k0 += 64) {
        if (k0) __syncthreads();
        // B: 192 rows (Q/K/V head slices of WqkvT), 1536 chunks
#pragma unroll
        for (int it = 0; it < 6; it++) {
            int q = it * 256 + tid;
            int r = q >> 3;
            int cs = (q & 7) ^ (r & 7);
            int srow = (r < 64) ? (h * 64 + r)
                     : (r < 128) ? (512 + h * 64 + (r - 64))
                                 : (1024 + h * 64 + (r - 128));
            GLL(WqkvT + (size_t)srow * 512 + k0 + cs * 8, &Bsm[(it * 256 + wid * 64) * 8]);
        }
        // A: xp = x + pos + time, reg-staged to bf16 swizzled
#pragma unroll
        for (int it = 0; it < 4; it++) {
            int q = (wid * 4 + it) * 64 + lane;
            int row = q >> 3;
            int cs = q & 7;
            const float* s = Xf + (size_t)(tok0 + row) * 512 + k0 + cs * 8;
            const float* pp = pos + (size_t)row * 512 + k0 + cs * 8;
            const float* tt = trow + k0 + cs * 8;
            float4 u0 = *(const float4*)s, u1 = *(const float4*)(s + 4);
            float4 p0 = *(const float4*)pp, p1 = *(const float4*)(pp + 4);
            float4 t0 = *(const float4*)tt, t1 = *(const float4*)(tt + 4);
            u0.x += p0.x + t0.x; u0.y += p0.y + t0.y; u0.z += p0.z + t0.z; u0.w += p0.w + t0.w;
            u1.x += p1.x + t1.x; u1.y += p1.y + t1.y; u1.z += p1.z + t1.z; u1.w += p1.w + t1.w;
            unsigned short c8[8];
            c8[0] = f2bf(u0.x); c8[1] = f2bf(u0.y); c8[2] = f2bf(u0.z); c8[3] = f2bf(u0.w);
            c8[4] = f2bf(u1.x); c8[5] = f2bf(u1.y); c8[6] = f2bf(u1.z); c8[7] = f2bf(u1.w);
            *(bf16x8*)&Asm[row * 64 + ((cs ^ (row & 7)) * 8)] = *(bf16x8*)c8;
        }
        __syncthreads();
#pragma unroll
        for (int kk = 0; kk < 2; kk++) {
            bf16x8 af[2];
#pragma unroll
            for (int i = 0; i < 2; i++) {
                int rowA = wq + i * 16 + (lane & 15);
                int ca = (kk * 4 + (lane >> 4)) ^ (rowA & 7);
                af[i] = *(const bf16x8*)&Asm[rowA * 64 + ca * 8];
            }
#pragma unroll
            for (int c = 0; c < 12; c++) {
                int rowB = c * 16 + (lane & 15);
                int cb = (kk * 4 + (lane >> 4)) ^ (rowB & 7);
                bf16x8 bfr = *(const bf16x8*)&Bsm[rowB * 64 + cb * 8];
                acc[0][c] = __builtin_amdgcn_mfma_f32_16x16x32_bf16(af[0], bfr, acc[0][c], 0, 0, 0);
                acc[1][c] = __builtin_amdgcn_mfma_f32_16x16x32_bf16(af[1], bfr, acc[1][c], 0, 0, 0);
            }
        }
    }
    __syncthreads();
    // phase 1.5: acc -> LDS. C-layout: token = wq+i*16+(lane>>4)*4+r, col = (c&3)*16+(lane&15)
#pragma unroll
    for (int i = 0; i < 2; i++)
#pragma unroll
        for (int c = 0; c < 12; c++)
#pragma unroll
            for (int r = 0; r < 4; r++) {
                int token = wq + i * 16 + (lane >> 4) * 4 + r;
                int col = (c & 3) * 16 + (lane & 15);
                unsigned short v = f2bf(acc[i][c][r]);
                if (c < 4)      Qs[token * 64 + (((col >> 3) ^ (token & 7)) * 8) + (col & 7)] = v;
                else if (c < 8) Ks[token * 64 + (((col >> 3) ^ (token & 7)) * 8) + (col & 7)] = v;
                else            Vt[col * 132 + token] = v;
            }
    __syncthreads();
    attn_core<CAUSAL>(Qs, Ks, Vt, Psw, wq, lane, tok0, h, O);
}

// ---------------- fused Q-GEMM + cross-attention ----------------
// block = (b,h), 4 waves. Phase 1: Q = xp @ Wq_x head-slice; K/V from kvx_bf.
__global__ __launch_bounds__(256) void fused_xattn(
    const float* __restrict__ Xf,
    const float* __restrict__ pos,
    const float* __restrict__ trow,
    const unsigned short* __restrict__ WqT,     // [512,512] bf16
    const unsigned short* __restrict__ kvx,     // [2048,1024] bf16
    unsigned short* __restrict__ O)
{
    __shared__ __align__(16) unsigned short smem[33024];
    unsigned short* Asm = smem;
    unsigned short* Bsm = smem + 8192;          // [64*64] (phase 1)
    unsigned short* Qs  = smem;
    unsigned short* Ks  = smem + 8192;
    unsigned short* Vt  = smem + 16384;
    const int tid = threadIdx.x;
    const int lane = tid & 63, wid = tid >> 6;
    unsigned short* Psw = smem + 24832 + wid * 2048;
    const int b = blockIdx.x >> 3, h = blockIdx.x & 7;
    const int tok0 = b * 128;
    const int wq = wid * 32;

    f32x4 acc[2][4];
#pragma unroll
    for (int i = 0; i < 2; i++)
#pragma unroll
        for (int c = 0; c < 4; c++) acc[i][c] = (f32x4){0.f, 0.f, 0.f, 0.f};

    for (int k0 = 0; k0 < 512; k0 += 64) {
        if (k0) __syncthreads();
#pragma unroll
        for (int it = 0; it < 2; it++) {
            int q = it * 256 + tid;
            int r = q >> 3;
            int cs = (q & 7) ^ (r & 7);
            GLL(WqT + (size_t)(h * 64 + r) * 512 + k0 + cs * 8, &Bsm[(it * 256 + wid * 64) * 8]);
        }
#pragma unroll
        for (int it = 0; it < 4; it++) {
            int q = (wid * 4 + it) * 64 + lane;
            int row = q >> 3;
            int cs = q & 7;
            const float* s = Xf + (size_t)(tok0 + row) * 512 + k0 + cs * 8;
            const float* pp = pos + (size_t)row * 512 + k0 + cs * 8;
            const float* tt = trow + k0 + cs * 8;
            float4 u0 = *(const float4*)s, u1 = *(const float4*)(s + 4);
            float4 p0 = *(const float4*)pp, p1 = *(const float4*)(pp + 4);
            float4 t0 = *(const float4*)tt, t1 = *(const float4*)(tt + 4);
            u0.x += p0.x + t0.x; u0.y += p0.y + t0.y; u0.z += p0.z + t0.z; u0.w += p0.w + t0.w;
            u1.x += p1.x + t1.x; u1.y += p1.y + t1.y; u1.z += p1.z + t1.z; u1.w += p1.w + t1.w;
            unsigned short c8[8];
            c8[0] = f2bf(u0.x); c8[1] = f2bf(u0.y); c8[2] = f2bf(u0.z); c8[3] = f2bf(u0.w);
            c8[4] = f2bf(u1.x); c8[5] = f2bf(u1.y); c8[6] = f2bf(u1.z); c8[7] = f2bf(u1.w);
            *(bf16x8*)&Asm[row * 64 + ((cs ^ (row & 7)) * 8)] = *(bf16x8*)c8;
        }
        __syncthreads();
#pragma unroll
        for (int kk = 0; kk < 2; kk++) {
            bf16x8 af[2];
#pragma unroll
            for (int i = 0; i < 2; i++) {
                int rowA = wq + i * 16 + (lane & 15);
                int ca = (kk * 4 + (lane >> 4)) ^ (rowA & 7);
                af[i] = *(const bf16x8*)&Asm[rowA * 64 + ca * 8];
            }
#pragma unroll
            for (int c = 0; c < 4; c++) {
                int rowB = c * 16 + (lane & 15);
                int cb = (kk * 4 + (lane >> 4)) ^ (rowB & 7);
                bf16x8 bfr = *(const bf16x8*)&Bsm[rowB * 64 + cb * 8];
                acc[0][c] = __builtin_amdgcn_mfma_f32_16x16x32_bf16(af[0], bfr, acc[0][c], 0, 0, 0);
                acc[1][c] = __builtin_amdgcn_mfma_f32_16x16x32_bf16(af[1], bfr, acc[1][c], 0, 0, 0);
            }
        }
    }
    __syncthreads();
    // Q -> LDS; K/V staged from global kvx
#pragma unroll
    for (int i = 0; i < 2; i++)
#pragma unroll
        for (int c = 0; c < 4; c++)
#pragma unroll
            for (int r = 0; r < 4; r++) {
                int token = wq + i * 16 + (lane >> 4) * 4 + r;
                int col = c * 16 + (lane & 15);
                Qs[token * 64 + (((col >> 3) ^ (token & 7)) * 8) + (col & 7)] = f2bf(acc[i][c][r]);
            }
    {
        int r = tid >> 1, cb = (tid & 1) * 4;
        const unsigned short* Kg = kvx + (size_t)(tok0 + r) * 1024 + h * 64;
        const unsigned short* Vg = Kg + 512;
#pragma unroll
        for (int c = cb; c < cb + 4; c++) {
            bf16x8 kv = *(const bf16x8*)&Kg[c * 8];
            *(bf16x8*)&Ks[r * 64 + ((c ^ (r & 7)) * 8)] = kv;
            bf16x8 vv = *(const bf16x8*)&Vg[c * 8];
#pragma unroll
            for (int j = 0; j < 8; j++)
                Vt[(c * 8 + j) * 132 + r] = (unsigned short)vv[j];
        }
    }
    __syncthreads();
    attn_core<0>(Qs, Ks, Vt, Psw, wq, lane, tok0, h, O);
}

// ---------------- generator: tiled GEMM + lse partials (m-fastest grid) ----------------
__global__ __launch_bounds__(256) void gemm_gen(
    const float* __restrict__ Af,
    const unsigned short* __restrict__ Bt,
    float* __restrict__ Out,
    float* __restrict__ pm,
    float* __restrict__ psum)
{
    __shared__ __align__(16) unsigned short Asm[128 * 64];
    __shared__ __align__(16) unsigned short Bsm[128 * 64];
    __shared__ float pml[4][64];
    __shared__ float psl[4][64];
    const int tid = threadIdx.x;
    const int lane = tid & 63, wid = tid >> 6;
    const int m0 = blockIdx.x * 128, n0 = blockIdx.y * 128;  // x = m fastest -> B-slab reuse
    const int wm = (wid >> 1) * 64, wn = (wid & 1) * 64;

    f32x4 acc[4][4];
#pragma unroll
    for (int i = 0; i < 4; i++)
#pragma unroll
        for (int j = 0; j < 4; j++) acc[i][j] = (f32x4){0.f, 0.f, 0.f, 0.f};

    for (int k0 = 0; k0 < 512; k0 += 64) {
        if (k0) __syncthreads();
#pragma unroll
        for (int it = 0; it < 4; it++) {
            int q = (wid * 4 + it) * 64 + lane;
            int row = q >> 3;
            int cs = (q & 7) ^ (row & 7);
            GLL(Bt + (size_t)(n0 + row) * 512 + k0 + cs * 8, &Bsm[(wid * 4 + it) * 512]);
        }
#pragma unroll
        for (int it = 0; it < 4; it++) {
            int q = (wid * 4 + it) * 64 + lane;
            int row = q >> 3;
            int cs = q & 7;
            const float* s = Af + (size_t)(m0 + row) * 512 + k0 + cs * 8;
            float4 u0 = *(const float4*)s, u1 = *(const float4*)(s + 4);
            unsigned short c8[8];
            c8[0] = f2bf(u0.x); c8[1] = f2bf(u0.y); c8[2] = f2bf(u0.z); c8[3] = f2bf(u0.w);
            c8[4] = f2bf(u1.x); c8[5] = f2bf(u1.y); c8[6] = f2bf(u1.z); c8[7] = f2bf(u1.w);
            *(bf16x8*)&Asm[row * 64 + ((cs ^ (row & 7)) * 8)] = *(bf16x8*)c8;
        }
        __syncthreads();
#pragma unroll
        for (int kk = 0; kk < 2; kk++) {
            bf16x8 af[4], bfr[4];
#pragma unroll
            for (int i = 0; i < 4; i++) {
                int rowA = wm + i * 16 + (lane & 15);
                int ca = (kk * 4 + (lane >> 4)) ^ (rowA & 7);
                af[i] = *(const bf16x8*)&Asm[rowA * 64 + ca * 8];
                int rowB = wn + i * 16 + (lane & 15);
                int cb = (kk * 4 + (lane >> 4)) ^ (rowB & 7);
                bfr[i] = *(const bf16x8*)&Bsm[rowB * 64 + cb * 8];
            }
#pragma unroll
            for (int i = 0; i < 4; i++)
#pragma unroll
                for (int j = 0; j < 4; j++)
                    acc[i][j] = __builtin_amdgcn_mfma_f32_16x16x32_bf16(af[i], bfr[j], acc[i][j], 0, 0, 0);
        }
    }
#pragma unroll
    for (int i = 0; i < 4; i++) {
#pragma unroll
        for (int r = 0; r < 4; r++) {
            float mx = fmaxf(fmaxf(acc[i][0][r], acc[i][1][r]),
                             fmaxf(acc[i][2][r], acc[i][3][r]));
            mx = fmaxf(mx, __shfl_xor(mx, 1));
            mx = fmaxf(mx, __shfl_xor(mx, 2));
            mx = fmaxf(mx, __shfl_xor(mx, 4));
            mx = fmaxf(mx, __shfl_xor(mx, 8));
            float s = __expf(acc[i][0][r] - mx) + __expf(acc[i][1][r] - mx) +
                      __expf(acc[i][2][r] - mx) + __expf(acc[i][3][r] - mx);
            s += __shfl_xor(s, 1); s += __shfl_xor(s, 2);
            s += __shfl_xor(s, 4); s += __shfl_xor(s, 8);
            if ((lane & 15) == 0) {
                int li = i * 16 + (lane >> 4) * 4 + r;
                pml[wid][li] = mx;
                psl[wid][li] = s;
            }
        }
    }
    __syncthreads();
    if (tid < 128) {
        int half = tid >> 6, lr = tid & 63;
        int wa = half * 2, wb = half * 2 + 1;
        float ma = pml[wa][lr], mb = pml[wb][lr];
        float m = fmaxf(ma, mb);
        float s = psl[wa][lr] * __expf(ma - m) + psl[wb][lr] * __expf(mb - m);
        pm[(size_t)(m0 + tid) * 256 + blockIdx.y] = m;
        psum[(size_t)(m0 + tid) * 256 + blockIdx.y] = s;
    }
#pragma unroll
    for (int i = 0; i < 4; i++)
#pragma unroll
        for (int j = 0; j < 4; j++)
#pragma unroll
            for (int r = 0; r < 4; r++) {
                int row = m0 + wm + i * 16 + (lane >> 4) * 4 + r;
                int col = n0 + wn + j * 16 + (lane & 15);
                Out[(size_t)row * VOCAB + col] = acc[i][j][r];
            }
}

// ---------------- lse reduce ----------------
__global__ __launch_bounds__(64) void lse_kernel(const float* __restrict__ pm,
                                                 const float* __restrict__ psum,
                                                 float* __restrict__ lse) {
    const int row = blockIdx.x, t = threadIdx.x;
    float m = -1e30f, s = 0.f;
    for (int nb = t; nb < 250; nb += 64) {
        float mm = pm[(size_t)row * 256 + nb];
        float ss = psum[(size_t)row * 256 + nb];
        float M = fmaxf(m, mm);
        s = s * __expf(m - M) + ss * __expf(mm - M);
        m = M;
    }
#pragma unroll
    for (int off = 32; off > 0; off >>= 1) {
        float mo = __shfl_xor(m, off), so = __shfl_xor(s, off);
        float M = fmaxf(m, mo);
        s = s * __expf(m - M) + so * __expf(mo - M);
        m = M;
    }
    if (t == 0) lse[row] = m + __logf(s);
}

// ---------------- subtract lse ----------------
__global__ __launch_bounds__(256) void sub_kernel(float* __restrict__ out,
                                                  const float* __restrict__ lse) {
    const int row = blockIdx.x;
    const float l = lse[row];
    float4* p = (float4*)(out + (size_t)row * VOCAB);
    for (int i = threadIdx.x; i < VOCAB / 4; i += 256) {
        float4 v = p[i];
        p[i] = make_float4(v.x - l, v.y - l, v.z - l, v.w - l);
    }
}

// ---------------- orchestration ----------------
extern "C" void kernel_launch(void* const* d_in, const int* in_sizes, int n_in,
                              void* d_out, int out_size, void* d_ws, size_t ws_size,
                              hipStream_t stream) {
    const float* emb_src  = (const float*)d_in[0];
    const float* emb_tgt  = (const float*)d_in[1];
    const float* pos_emb  = (const float*)d_in[2];
    const float* time_emb = (const float*)d_in[3];
    const float* Wqkv_e   = (const float*)d_in[4];
    const float* Wo_e     = (const float*)d_in[5];
    const float* W1_e     = (const float*)d_in[6];
    const float* W2_e     = (const float*)d_in[7];
    const float* Wqkv_d   = (const float*)d_in[8];
    const float* Wo_d     = (const float*)d_in[9];
    const float* W1_d     = (const float*)d_in[10];
    const float* W2_d     = (const float*)d_in[11];
    const float* Wq_x     = (const float*)d_in[12];
    const float* Wkv_x    = (const float*)d_in[13];
    const float* Wo_x     = (const float*)d_in[14];
    const float* Wgen     = (const float*)d_in[15];
    const int* src_tokens = (const int*)d_in[16];
    const int* tgt_tokens = (const int*)d_in[17];
    const int* src_pos    = (const int*)d_in[18];
    const int* tgt_pos    = (const int*)d_in[19];

    char* w = (char*)d_ws;
    float* x_e = (float*)(w);                                     // 4MB
    float* x_d = (float*)(w + (4u << 20));                        // 4MB
    float* tmp = (float*)(w + (8u << 20));                        // 4MB
    unsigned short* kvx_bf = (unsigned short*)(w + (12u << 20));  // 4MB
    unsigned short* o_bf   = (unsigned short*)(w + (16u << 20));  // 2MB
    unsigned short* hid_bf = (unsigned short*)(w + (18u << 20));  // 8MB
    float* pm   = (float*)(w + (26u << 20));                      // 2MB
    float* psum = (float*)(w + (28u << 20));                      // 2MB
    float* lse  = (float*)(w + (30u << 20));                      // 8KB
    unsigned short* wts    = (unsigned short*)(w + (31u << 20));  // ~47.4MB

    unsigned short* WqkvE_t = wts;
    unsigned short* WoE_t   = WqkvE_t + 786432;
    unsigned short* W1E_t   = WoE_t   + 262144;
    unsigned short* W2E_t   = W1E_t   + 1048576;
    unsigned short* WqkvD_t = W2E_t   + 1048576;
    unsigned short* WoD_t   = WqkvD_t + 786432;
    unsigned short* W1D_t   = WoD_t   + 262144;
    unsigned short* W2D_t   = W1D_t   + 1048576;
    unsigned short* WqX_t   = W2D_t   + 1048576;
    unsigned short* WkvX_t  = WqX_t   + 262144;
    unsigned short* WoX_t   = WkvX_t  + 524288;
    unsigned short* Wgen_t  = WoX_t   + 262144;

    float* out = (float*)d_out;

    WTab tab;
    auto set = [&](int i, const float* s, unsigned short* d, int K, int N, int t0) {
        tab.d[i].src = s; tab.d[i].dst = d; tab.d[i].K = K; tab.d[i].N = N;
        tab.d[i].t0 = t0; tab.d[i].pad = 0;
    };
    set(0,  Wqkv_e, WqkvE_t, 512, 1536, 0);
    set(1,  Wo_e,   WoE_t,   512, 512,  768);
    set(2,  W1_e,   W1E_t,   512, 2048, 1024);
    set(3,  W2_e,   W2E_t,   2048, 512, 2048);
    set(4,  Wqkv_d, WqkvD_t, 512, 1536, 3072);
    set(5,  Wo_d,   WoD_t,   512, 512,  3840);
    set(6,  W1_d,   W1D_t,   512, 2048, 4096);
    set(7,  W2_d,   W2D_t,   2048, 512, 5120);
    set(8,  Wq_x,   WqX_t,   512, 512,  6144);
    set(9,  Wkv_x,  WkvX_t,  512, 1024, 6400);
    set(10, Wo_x,   WoX_t,   512, 512,  6912);
    set(11, Wgen,   Wgen_t,  512, 32000, 7168);
    wconv_all<<<23168, 256, 0, stream>>>(tab);

    const int n4 = NTOK * (DIM / 4);
    dim3 eb(256), eg((n4 + 255) / 256);
    embed_kernel<<<eg, eb, 0, stream>>>(emb_src, src_tokens, pos_emb, src_pos, x_e, n4);
    embed_kernel<<<eg, eb, 0, stream>>>(emb_tgt, tgt_tokens, pos_emb, tgt_pos, x_d, n4);

    const dim3 gFF(DFF / 128, NTOK / 128), gKV(1024 / 128, NTOK / 128),
               g64(512 / 64, NTOK / 64);

    // -------- encoder --------
    for (int t = 0; t < DEPTH; t++) {
        const float* trow = time_emb + (size_t)t * DIM;
        fused_attn<0><<<128, 256, 0, stream>>>(x_e, pos_emb, trow, WqkvE_t, o_bf);
        gemm_bb<<<g64, 256, 0, stream>>>(o_bf, WoE_t, x_e, tmp, NTOK, 512, 512);
        ln_kernel<<<NTOK, 64, 0, stream>>>(tmp, x_e);
        gemm_u<1><<<gFF, 256, 0, stream>>>(x_e, W1E_t, hid_bf, NTOK, DFF, 512);
        gemm_bb<<<g64, 256, 0, stream>>>(hid_bf, W2E_t, x_e, tmp, NTOK, 512, 2048);
        ln_kernel<<<NTOK, 64, 0, stream>>>(tmp, x_e);
    }

    // cross-attn K/V from final encoder state (hoisted)
    gemm_u<3><<<gKV, 256, 0, stream>>>(x_e, WkvX_t, kvx_bf, NTOK, 1024, 512);

    // -------- decoder --------
    for (int t = 0; t < DEPTH; t++) {
        const float* trow = time_emb + (size_t)t * DIM;
        fused_attn<1><<<128, 256, 0, stream>>>(x_d, pos_emb, trow, WqkvD_t, o_bf);
        gemm_bb<<<g64, 256, 0, stream>>>(o_bf, WoD_t, x_d, tmp, NTOK, 512, 512);
        ln_kernel<<<NTOK, 64, 0, stream>>>(tmp, x_d);

        fused_xattn<<<128, 256, 0, stream>>>(x_d, pos_emb, trow, WqX_t, kvx_bf, o_bf);
        gemm_bb<<<g64, 256, 0, stream>>>(o_bf, WoX_t, x_d, tmp, NTOK, 512, 512);
        ln_kernel<<<NTOK, 64, 0, stream>>>(tmp, x_d);

        gemm_u<1><<<gFF, 256, 0, stream>>>(x_d, W1D_t, hid_bf, NTOK, DFF, 512);
        gemm_bb<<<g64, 256, 0, stream>>>(hid_bf, W2D_t, x_d, tmp, NTOK, 512, 2048);
        ln_kernel<<<NTOK, 64, 0, stream>>>(tmp, x_d);
    }

    // -------- generator + log_softmax --------
    gemm_gen<<<dim3(16, 250), 256, 0, stream>>>(x_d, Wgen_t, out, pm, psum);
    lse_kernel<<<NTOK, 64, 0, stream>>>(pm, psum, lse);
    sub_kernel<<<NTOK, 256, 0, stream>>>(out, lse);
}

// Round 8
// 1855.018 us; speedup vs baseline: 4.3358x; 1.1068x over previous
//
#include <hip/hip_runtime.h>
#include <hip/hip_bf16.h>
#include <math.h>

#define H 8
#define DK 64
#define DIM 512
#define DFF 2048
#define DEPTH 8
#define VOCAB 32000
#define NTOK 2048

typedef float f32x4 __attribute__((ext_vector_type(4)));
typedef short bf16x8 __attribute__((ext_vector_type(8)));

static __device__ __forceinline__ unsigned short f2bf(float f) {
    unsigned u = __float_as_uint(f);
    return (unsigned short)((u + 0x7FFFu + ((u >> 16) & 1u)) >> 16);
}

#define GLL(src, dst) __builtin_amdgcn_global_load_lds( \
    (const __attribute__((address_space(1))) unsigned int*)(src), \
    (__attribute__((address_space(3))) unsigned int*)(dst), 16, 0, 0)

// ---------------- embed ----------------
__global__ void embed_kernel(const float* __restrict__ emb, const int* __restrict__ tok,
                             const float* __restrict__ pos, const int* __restrict__ pidx,
                             float* __restrict__ out, int n4) {
    int idx = blockIdx.x * blockDim.x + threadIdx.x;
    if (idx >= n4) return;
    int i = idx >> 7, d = idx & 127;
    float4 a = ((const float4*)emb)[(size_t)tok[i] * 128 + d];
    float4 b = ((const float4*)pos)[(size_t)pidx[i] * 128 + d];
    ((float4*)out)[idx] = make_float4(a.x + b.x, a.y + b.y, a.z + b.z, a.w + b.w);
}

// ---------------- batched weight convert+transpose ----------------
struct WD { const float* src; unsigned short* dst; int K; int N; int t0; int pad; };
struct WTab { WD d[12]; };

__global__ __launch_bounds__(256) void wconv_all(WTab tab) {
    __shared__ float t[32][33];
    const int bid = blockIdx.x;
    int w = 0;
#pragma unroll
    for (int i = 1; i < 12; i++) if (bid >= tab.d[i].t0) w = i;
    const float* W = tab.d[w].src;
    unsigned short* Wt = tab.d[w].dst;
    const int K = tab.d[w].K, N = tab.d[w].N;
    const int lt = bid - tab.d[w].t0;
    const int txc = N >> 5;
    const int n0 = (lt % txc) << 5, k0 = (lt / txc) << 5;
    const int tid = threadIdx.x;
    const int tx = tid & 31, ty = tid >> 5;
#pragma unroll
    for (int i = 0; i < 32; i += 8)
        t[ty + i][tx] = W[(size_t)(k0 + ty + i) * N + n0 + tx];
    __syncthreads();
#pragma unroll
    for (int i = 0; i < 32; i += 8)
        Wt[(size_t)(n0 + ty + i) * K + k0 + tx] = f2bf(t[tx][ty + i]);
}

// ---------------- gemm_rb: C = A @ Bt^T (bf16 A via GLL, 128x128 tile) ----------------
// EPI 1: relu->bf16; 3: bf16.
template<int EPI>
__global__ __launch_bounds__(256) void gemm_rb(
    const unsigned short* __restrict__ A,
    const unsigned short* __restrict__ Bt,
    unsigned short* __restrict__ Cb,
    int M, int N, int K)
{
    __shared__ __align__(16) unsigned short Asm[128 * 64];
    __shared__ __align__(16) unsigned short Bsm[128 * 64];
    const int tid = threadIdx.x;
    const int lane = tid & 63, wid = tid >> 6;
    const int m0 = blockIdx.y * 128, n0 = blockIdx.x * 128;
    const int wm = (wid >> 1) * 64, wn = (wid & 1) * 64;

    f32x4 acc[4][4];
#pragma unroll
    for (int i = 0; i < 4; i++)
#pragma unroll
        for (int j = 0; j < 4; j++) acc[i][j] = (f32x4){0.f, 0.f, 0.f, 0.f};

    for (int k0 = 0; k0 < K; k0 += 64) {
        if (k0) __syncthreads();
#pragma unroll
        for (int it = 0; it < 4; it++) {
            int q = (wid * 4 + it) * 64 + lane;
            int row = q >> 3;
            int cs = (q & 7) ^ (row & 7);
            GLL(Bt + (size_t)(n0 + row) * K + k0 + cs * 8, &Bsm[(wid * 4 + it) * 512]);
            GLL(A + (size_t)(m0 + row) * K + k0 + cs * 8, &Asm[(wid * 4 + it) * 512]);
        }
        __syncthreads();
#pragma unroll
        for (int kk = 0; kk < 2; kk++) {
            bf16x8 af[4], bfr[4];
#pragma unroll
            for (int i = 0; i < 4; i++) {
                int rowA = wm + i * 16 + (lane & 15);
                int ca = (kk * 4 + (lane >> 4)) ^ (rowA & 7);
                af[i] = *(const bf16x8*)&Asm[rowA * 64 + ca * 8];
                int rowB = wn + i * 16 + (lane & 15);
                int cb = (kk * 4 + (lane >> 4)) ^ (rowB & 7);
                bfr[i] = *(const bf16x8*)&Bsm[rowB * 64 + cb * 8];
            }
#pragma unroll
            for (int i = 0; i < 4; i++)
#pragma unroll
                for (int j = 0; j < 4; j++)
                    acc[i][j] = __builtin_amdgcn_mfma_f32_16x16x32_bf16(af[i], bfr[j], acc[i][j], 0, 0, 0);
        }
    }
#pragma unroll
    for (int i = 0; i < 4; i++)
#pragma unroll
        for (int j = 0; j < 4; j++)
#pragma unroll
            for (int r = 0; r < 4; r++) {
                int row = m0 + wm + i * 16 + (lane >> 4) * 4 + r;
                int col = n0 + wn + j * 16 + (lane & 15);
                size_t idx = (size_t)row * N + col;
                float v = acc[i][j][r];
                if (EPI == 1) Cb[idx] = f2bf(fmaxf(v, 0.f));
                if (EPI == 3) Cb[idx] = f2bf(v);
            }
}

// ---------------- gemm_bb: C = R + A @ Bt^T (bf16 A, 64x64 tile, f32 out) ----------------
__global__ __launch_bounds__(256) void gemm_bb(
    const unsigned short* __restrict__ A,
    const unsigned short* __restrict__ Bt,
    const float* __restrict__ R,
    float* __restrict__ Cf,
    int M, int N, int K)
{
    __shared__ __align__(16) unsigned short Asm[64 * 64];
    __shared__ __align__(16) unsigned short Bsm[64 * 64];
    const int tid = threadIdx.x;
    const int lane = tid & 63, wid = tid >> 6;
    const int m0 = blockIdx.y * 64, n0 = blockIdx.x * 64;
    const int wm = (wid >> 1) * 32, wn = (wid & 1) * 32;

    f32x4 acc[2][2];
#pragma unroll
    for (int i = 0; i < 2; i++)
#pragma unroll
        for (int j = 0; j < 2; j++) acc[i][j] = (f32x4){0.f, 0.f, 0.f, 0.f};

    for (int k0 = 0; k0 < K; k0 += 64) {
        if (k0) __syncthreads();
#pragma unroll
        for (int it = 0; it < 2; it++) {
            int q = it * 256 + tid;
            int row = q >> 3;
            int cs = (q & 7) ^ (row & 7);
            GLL(A + (size_t)(m0 + row) * K + k0 + cs * 8, &Asm[(it * 256 + wid * 64) * 8]);
            GLL(Bt + (size_t)(n0 + row) * K + k0 + cs * 8, &Bsm[(it * 256 + wid * 64) * 8]);
        }
        __syncthreads();
#pragma unroll
        for (int kd = 0; kd < 2; kd++) {
            bf16x8 af[2], bfr[2];
#pragma unroll
            for (int i = 0; i < 2; i++) {
                int rowA = wm + i * 16 + (lane & 15);
                int ca = (kd * 4 + (lane >> 4)) ^ (rowA & 7);
                af[i] = *(const bf16x8*)&Asm[rowA * 64 + ca * 8];
                int rowB = wn + i * 16 + (lane & 15);
                int cb = (kd * 4 + (lane >> 4)) ^ (rowB & 7);
                bfr[i] = *(const bf16x8*)&Bsm[rowB * 64 + cb * 8];
            }
#pragma unroll
            for (int i = 0; i < 2; i++)
#pragma unroll
                for (int j = 0; j < 2; j++)
                    acc[i][j] = __builtin_amdgcn_mfma_f32_16x16x32_bf16(af[i], bfr[j], acc[i][j], 0, 0, 0);
        }
    }
#pragma unroll
    for (int i = 0; i < 2; i++)
#pragma unroll
        for (int j = 0; j < 2; j++)
#pragma unroll
            for (int r = 0; r < 4; r++) {
                int row = m0 + wm + i * 16 + (lane >> 4) * 4 + r;
                int col = n0 + wn + j * 16 + (lane & 15);
                size_t idx = (size_t)row * N + col;
                Cf[idx] = acc[i][j][r] + R[idx];
            }
}

// ---------------- LayerNorm (f32 -> f32 + bf16 mirror) ----------------
__global__ __launch_bounds__(64) void ln_kernel(const float* __restrict__ in,
                                                float* __restrict__ out,
                                                unsigned short* __restrict__ outb) {
    const int row = blockIdx.x, lane = threadIdx.x;
    const float* p = in + (size_t)row * DIM;
    float x[8];
#pragma unroll
    for (int i = 0; i < 8; i++) x[i] = p[lane + i * 64];
    float s = 0.f;
#pragma unroll
    for (int i = 0; i < 8; i++) s += x[i];
#pragma unroll
    for (int off = 32; off > 0; off >>= 1) s += __shfl_xor(s, off);
    const float m = s * (1.f / 512.f);
    float v = 0.f;
#pragma unroll
    for (int i = 0; i < 8; i++) { float d = x[i] - m; v += d * d; }
#pragma unroll
    for (int off = 32; off > 0; off >>= 1) v += __shfl_xor(v, off);
    v *= (1.f / 512.f);
    const float inv = 1.f / sqrtf(v + 1e-5f);
    float* q = out + (size_t)row * DIM;
    unsigned short* qb = outb + (size_t)row * DIM;
#pragma unroll
    for (int i = 0; i < 8; i++) {
        float y = (x[i] - m) * inv;
        q[lane + i * 64] = y;
        qb[lane + i * 64] = f2bf(y);
    }
}

// ---------------- attention core, 16 q-rows per wave ----------------
template<int CAUSAL>
static __device__ __forceinline__ void attn_core16(
    const unsigned short* Qs, const unsigned short* Ks, const unsigned short* Vt,
    unsigned short* Psw, int wq, int lane, int tok0, int h,
    unsigned short* __restrict__ O)
{
    bf16x8 qa[2];
#pragma unroll
    for (int kd = 0; kd < 2; kd++) {
        int qr = wq + (lane & 15);
        int ch = (kd * 4 + (lane >> 4)) ^ (qr & 7);
        qa[kd] = *(const bf16x8*)&Qs[qr * 64 + ch * 8];
    }
    const int kcmax = CAUSAL ? ((wq >> 5) + 1) : 4;
    const int jmax = CAUSAL ? (kcmax * 2) : 8;

    float zr[4] = {0.f, 0.f, 0.f, 0.f};
    f32x4 oacc[4];
#pragma unroll
    for (int dt = 0; dt < 4; dt++) oacc[dt] = (f32x4){0.f, 0.f, 0.f, 0.f};

    for (int kb = 0; kb < 2; kb++) {
        int j0 = kb * 4;
        if (j0 >= jmax) break;
        int jn = jmax - j0; if (jn > 4) jn = 4;
        f32x4 sacc[4];
#pragma unroll
        for (int j = 0; j < 4; j++) sacc[j] = (f32x4){0.f, 0.f, 0.f, 0.f};
#pragma unroll 2
        for (int kd = 0; kd < 2; kd++) {
            for (int jj = 0; jj < jn; jj++) {
                int kr = (j0 + jj) * 16 + (lane & 15);
                int ch = (kd * 4 + (lane >> 4)) ^ (kr & 7);
                bf16x8 kf = *(const bf16x8*)&Ks[kr * 64 + ch * 8];
                sacc[jj] = __builtin_amdgcn_mfma_f32_16x16x32_bf16(qa[kd], kf, sacc[jj], 0, 0, 0);
            }
        }
        int qbase = wq + (lane >> 4) * 4;
        for (int jj = 0; jj < jn; jj++) {
            int kcol = (j0 + jj) * 16 + (lane & 15);
#pragma unroll
            for (int rr = 0; rr < 4; rr++) {
                float p = __expf(sacc[jj][rr] * 0.125f);
                if (CAUSAL && kcol > qbase + rr) p = 0.f;
                zr[rr] += p;
                int prow = (lane >> 4) * 4 + rr;
                int ch = ((jj * 2 + ((lane & 15) >> 3)) ^ (prow & 7));
                Psw[prow * 64 + ch * 8 + (lane & 7)] = f2bf(p);
            }
        }
        int kcn = kcmax - kb * 2; if (kcn > 2) kcn = 2;
        for (int kcl = 0; kcl < kcn; kcl++) {
            bf16x8 pa;
            {
                int prow = lane & 15;
                int ch = (kcl * 4 + (lane >> 4)) ^ (prow & 7);
                pa = *(const bf16x8*)&Psw[prow * 64 + ch * 8];
            }
            int kcg = kb * 2 + kcl;
#pragma unroll
            for (int dt = 0; dt < 4; dt++) {
                int d = dt * 16 + (lane & 15);
                bf16x8 vf = *(const bf16x8*)&Vt[d * 132 + (kcg * 4 + (lane >> 4)) * 8];
                oacc[dt] = __builtin_amdgcn_mfma_f32_16x16x32_bf16(pa, vf, oacc[dt], 0, 0, 0);
            }
        }
    }
#pragma unroll
    for (int rr = 0; rr < 4; rr++) {
        float z = zr[rr];
        z += __shfl_xor(z, 1); z += __shfl_xor(z, 2);
        z += __shfl_xor(z, 4); z += __shfl_xor(z, 8);
        zr[rr] = 1.f / (z + 1e-9f);
    }
#pragma unroll
    for (int dt = 0; dt < 4; dt++)
#pragma unroll
        for (int rr = 0; rr < 4; rr++) {
            int qrow = tok0 + wq + (lane >> 4) * 4 + rr;
            O[(size_t)qrow * DIM + h * 64 + dt * 16 + (lane & 15)] =
                f2bf(oacc[dt][rr] * zr[rr]);
        }
}

// ---------------- fused QKV-GEMM + self-attention (8 waves) ----------------
template<int CAUSAL>
__global__ __launch_bounds__(512) void fused_attn(
    const float* __restrict__ Xf,
    const float* __restrict__ pos,
    const float* __restrict__ trow,
    const unsigned short* __restrict__ WqkvT,   // [1536,512] bf16
    unsigned short* __restrict__ O)
{
    __shared__ __align__(16) unsigned short smem[33024];  // 64.5 KB
    unsigned short* Asm = smem;             // [128*64]  (phase 1)
    unsigned short* Bsm = smem + 8192;      // [192*64]  (phase 1)
    unsigned short* Qs  = smem;             // phase 2
    unsigned short* Ks  = smem + 8192;
    unsigned short* Vt  = smem + 16384;     // [64*132]
    const int tid = threadIdx.x;
    const int lane = tid & 63, wid = tid >> 6;
    unsigned short* Psw = smem + 24832 + wid * 1024;   // 16x64 per wave
    const int b = blockIdx.x >> 3, h = blockIdx.x & 7;
    const int tok0 = b * 128;
    const int wq = wid * 16;

    f32x4 acc[12];   // cols: 0-3 Q, 4-7 K, 8-11 V
#pragma unroll
    for (int c = 0; c < 12; c++) acc[c] = (f32x4){0.f, 0.f, 0.f, 0.f};

    for (int k0 = 0; k0 < 512; k0 += 64) {
        if (k0) __syncthreads();
#pragma unroll
        for (int it = 0; it < 3; it++) {
            int q = it * 512 + wid * 64 + lane;
            int r = q >> 3;
            int cs = (q & 7) ^ (r & 7);
            int srow = (r < 64) ? (h * 64 + r)
                     : (r < 128) ? (512 + h * 64 + (r - 64))
                                 : (1024 + h * 64 + (r - 128));
            GLL(WqkvT + (size_t)srow * 512 + k0 + cs * 8, &Bsm[(it * 512 + wid * 64) * 8]);
        }
#pragma unroll
        for (int it = 0; it < 2; it++) {
            int q = it * 512 + tid;
            int row = q >> 3;
            int cs = q & 7;
            const float* s = Xf + (size_t)(tok0 + row) * 512 + k0 + cs * 8;
            const float* pp = pos + (size_t)row * 512 + k0 + cs * 8;
            const float* tt = trow + k0 + cs * 8;
            float4 u0 = *(const float4*)s, u1 = *(const float4*)(s + 4);
            float4 p0 = *(const float4*)pp, p1 = *(const float4*)(pp + 4);
            float4 t0 = *(const float4*)tt, t1 = *(const float4*)(tt + 4);
            u0.x += p0.x + t0.x; u0.y += p0.y + t0.y; u0.z += p0.z + t0.z; u0.w += p0.w + t0.w;
            u1.x += p1.x + t1.x; u1.y += p1.y + t1.y; u1.z += p1.z + t1.z; u1.w += p1.w + t1.w;
            unsigned short c8[8];
            c8[0] = f2bf(u0.x); c8[1] = f2bf(u0.y); c8[2] = f2bf(u0.z); c8[3] = f2bf(u0.w);
            c8[4] = f2bf(u1.x); c8[5] = f2bf(u1.y); c8[6] = f2bf(u1.z); c8[7] = f2bf(u1.w);
            *(bf16x8*)&Asm[row * 64 + ((cs ^ (row & 7)) * 8)] = *(bf16x8*)c8;
        }
        __syncthreads();
#pragma unroll
        for (int kk = 0; kk < 2; kk++) {
            int rowA = wq + (lane & 15);
            int ca = (kk * 4 + (lane >> 4)) ^ (rowA & 7);
            bf16x8 af = *(const bf16x8*)&Asm[rowA * 64 + ca * 8];
#pragma unroll
            for (int c = 0; c < 12; c++) {
                int rowB = c * 16 + (lane & 15);
                int cb = (kk * 4 + (lane >> 4)) ^ (rowB & 7);
                bf16x8 bfr = *(const bf16x8*)&Bsm[rowB * 64 + cb * 8];
                acc[c] = __builtin_amdgcn_mfma_f32_16x16x32_bf16(af, bfr, acc[c], 0, 0, 0);
            }
        }
    }
    __syncthreads();
    // phase 1.5: acc -> LDS. token = wq + (lane>>4)*4 + r, col = (c&3)*16 + (lane&15)
#pragma unroll
    for (int c = 0; c < 12; c++)
#pragma unroll
        for (int r = 0; r < 4; r++) {
            int token = wq + (lane >> 4) * 4 + r;
            int col = (c & 3) * 16 + (lane & 15);
            unsigned short v = f2bf(acc[c][r]);
            if (c < 4)      Qs[token * 64 + (((col >> 3) ^ (token & 7)) * 8) + (col & 7)] = v;
            else if (c < 8) Ks[token * 64 + (((col >> 3) ^ (token & 7)) * 8) + (col & 7)] = v;
            else            Vt[col * 132 + token] = v;
        }
    __syncthreads();
    attn_core16<CAUSAL>(Qs, Ks, Vt, Psw, wq, lane, tok0, h, O);
}

// ---------------- fused Q-GEMM + cross-attention (8 waves) ----------------
__global__ __launch_bounds__(512) void fused_xattn(
    const float* __restrict__ Xf,
    const float* __restrict__ pos,
    const float* __restrict__ trow,
    const unsigned short* __restrict__ WqT,     // [512,512] bf16
    const unsigned short* __restrict__ kvx,     // [2048,1024] bf16
    unsigned short* __restrict__ O)
{
    __shared__ __align__(16) unsigned short smem[33024];
    unsigned short* Asm = smem;
    unsigned short* Bsm = smem + 8192;          // [64*64]
    unsigned short* Qs  = smem;
    unsigned short* Ks  = smem + 8192;
    unsigned short* Vt  = smem + 16384;
    const int tid = threadIdx.x;
    const int lane = tid & 63, wid = tid >> 6;
    unsigned short* Psw = smem + 24832 + wid * 1024;
    const int b = blockIdx.x >> 3, h = blockIdx.x & 7;
    const int tok0 = b * 128;
    const int wq = wid * 16;

    f32x4 acc[4];
#pragma unroll
    for (int c = 0; c < 4; c++) acc[c] = (f32x4){0.f, 0.f, 0.f, 0.f};

    for (int k0 = 0; k0 < 512; k0 += 64) {
        if (k0) __syncthreads();
        {
            int q = wid * 64 + lane;
            int r = q >> 3;
            int cs = (q & 7) ^ (r & 7);
            GLL(WqT + (size_t)(h * 64 + r) * 512 + k0 + cs * 8, &Bsm[(wid * 64) * 8]);
        }
#pragma unroll
        for (int it = 0; it < 2; it++) {
            int q = it * 512 + tid;
            int row = q >> 3;
            int cs = q & 7;
            const float* s = Xf + (size_t)(tok0 + row) * 512 + k0 + cs * 8;
            const float* pp = pos + (size_t)row * 512 + k0 + cs * 8;
            const float* tt = trow + k0 + cs * 8;
            float4 u0 = *(const float4*)s, u1 = *(const float4*)(s + 4);
            float4 p0 = *(const float4*)pp, p1 = *(const float4*)(pp + 4);
            float4 t0 = *(const float4*)tt, t1 = *(const float4*)(tt + 4);
            u0.x += p0.x + t0.x; u0.y += p0.y + t0.y; u0.z += p0.z + t0.z; u0.w += p0.w + t0.w;
            u1.x += p1.x + t1.x; u1.y += p1.y + t1.y; u1.z += p1.z + t1.z; u1.w += p1.w + t1.w;
            unsigned short c8[8];
            c8[0] = f2bf(u0.x); c8[1] = f2bf(u0.y); c8[2] = f2bf(u0.z); c8[3] = f2bf(u0.w);
            c8[4] = f2bf(u1.x); c8[5] = f2bf(u1.y); c8[6] = f2bf(u1.z); c8[7] = f2bf(u1.w);
            *(bf16x8*)&Asm[row * 64 + ((cs ^ (row & 7)) * 8)] = *(bf16x8*)c8;
        }
        __syncthreads();
#pragma unroll
        for (int kk = 0; kk < 2; kk++) {
            int rowA = wq + (lane & 15);
            int ca = (kk * 4 + (lane >> 4)) ^ (rowA & 7);
            bf16x8 af = *(const bf16x8*)&Asm[rowA * 64 + ca * 8];
#pragma unroll
            for (int c = 0; c < 4; c++) {
                int rowB = c * 16 + (lane & 15);
                int cb = (kk * 4 + (lane >> 4)) ^ (rowB & 7);
                bf16x8 bfr = *(const bf16x8*)&Bsm[rowB * 64 + cb * 8];
                acc[c] = __builtin_amdgcn_mfma_f32_16x16x32_bf16(af, bfr, acc[c], 0, 0, 0);
            }
        }
    }
    __syncthreads();
#pragma unroll
    for (int c = 0; c < 4; c++)
#pragma unroll
        for (int r = 0; r < 4; r++) {
            int token = wq + (lane >> 4) * 4 + r;
            int col = c * 16 + (lane & 15);
            Qs[token * 64 + (((col >> 3) ^ (token & 7)) * 8) + (col & 7)] = f2bf(acc[c][r]);
        }
    {
        int r = tid >> 2, c0 = (tid & 3) * 2;
        const unsigned short* Kg = kvx + (size_t)(tok0 + r) * 1024 + h * 64;
        const unsigned short* Vg = Kg + 512;
#pragma unroll
        for (int c = c0; c < c0 + 2; c++) {
            bf16x8 kv = *(const bf16x8*)&Kg[c * 8];
            *(bf16x8*)&Ks[r * 64 + ((c ^ (r & 7)) * 8)] = kv;
            bf16x8 vv = *(const bf16x8*)&Vg[c * 8];
#pragma unroll
            for (int j = 0; j < 8; j++)
                Vt[(c * 8 + j) * 132 + r] = (unsigned short)vv[j];
        }
    }
    __syncthreads();
    attn_core16<0>(Qs, Ks, Vt, Psw, wq, lane, tok0, h, O);
}

// ---------------- generator: tiled GEMM (bf16 A) + lse partials ----------------
__global__ __launch_bounds__(256) void gemm_gen(
    const unsigned short* __restrict__ Ab,  // [2048,512] bf16
    const unsigned short* __restrict__ Bt,  // [32000,512] bf16
    float* __restrict__ Out,
    float* __restrict__ pm,
    float* __restrict__ psum)
{
    __shared__ __align__(16) unsigned short Asm[128 * 64];
    __shared__ __align__(16) unsigned short Bsm[128 * 64];
    __shared__ float pml[4][64];
    __shared__ float psl[4][64];
    const int tid = threadIdx.x;
    const int lane = tid & 63, wid = tid >> 6;
    const int m0 = blockIdx.x * 128, n0 = blockIdx.y * 128;  // m fastest -> B-slab reuse
    const int wm = (wid >> 1) * 64, wn = (wid & 1) * 64;

    f32x4 acc[4][4];
#pragma unroll
    for (int i = 0; i < 4; i++)
#pragma unroll
        for (int j = 0; j < 4; j++) acc[i][j] = (f32x4){0.f, 0.f, 0.f, 0.f};

    for (int k0 = 0; k0 < 512; k0 += 64) {
        if (k0) __syncthreads();
#pragma unroll
        for (int it = 0; it < 4; it++) {
            int q = (wid * 4 + it) * 64 + lane;
            int row = q >> 3;
            int cs = (q & 7) ^ (row & 7);
            GLL(Bt + (size_t)(n0 + row) * 512 + k0 + cs * 8, &Bsm[(wid * 4 + it) * 512]);
            GLL(Ab + (size_t)(m0 + row) * 512 + k0 + cs * 8, &Asm[(wid * 4 + it) * 512]);
        }
        __syncthreads();
#pragma unroll
        for (int kk = 0; kk < 2; kk++) {
            bf16x8 af[4], bfr[4];
#pragma unroll
            for (int i = 0; i < 4; i++) {
                int rowA = wm + i * 16 + (lane & 15);
                int ca = (kk * 4 + (lane >> 4)) ^ (rowA & 7);
                af[i] = *(const bf16x8*)&Asm[rowA * 64 + ca * 8];
                int rowB = wn + i * 16 + (lane & 15);
                int cb = (kk * 4 + (lane >> 4)) ^ (rowB & 7);
                bfr[i] = *(const bf16x8*)&Bsm[rowB * 64 + cb * 8];
            }
#pragma unroll
            for (int i = 0; i < 4; i++)
#pragma unroll
                for (int j = 0; j < 4; j++)
                    acc[i][j] = __builtin_amdgcn_mfma_f32_16x16x32_bf16(af[i], bfr[j], acc[i][j], 0, 0, 0);
        }
    }
#pragma unroll
    for (int i = 0; i < 4; i++) {
#pragma unroll
        for (int r = 0; r < 4; r++) {
            float mx = fmaxf(fmaxf(acc[i][0][r], acc[i][1][r]),
                             fmaxf(acc[i][2][r], acc[i][3][r]));
            mx = fmaxf(mx, __shfl_xor(mx, 1));
            mx = fmaxf(mx, __shfl_xor(mx, 2));
            mx = fmaxf(mx, __shfl_xor(mx, 4));
            mx = fmaxf(mx, __shfl_xor(mx, 8));
            float s = __expf(acc[i][0][r] - mx) + __expf(acc[i][1][r] - mx) +
                      __expf(acc[i][2][r] - mx) + __expf(acc[i][3][r] - mx);
            s += __shfl_xor(s, 1); s += __shfl_xor(s, 2);
            s += __shfl_xor(s, 4); s += __shfl_xor(s, 8);
            if ((lane & 15) == 0) {
                int li = i * 16 + (lane >> 4) * 4 + r;
                pml[wid][li] = mx;
                psl[wid][li] = s;
            }
        }
    }
    __syncthreads();
    if (tid < 128) {
        int half = tid >> 6, lr = tid & 63;
        int wa = half * 2, wb = half * 2 + 1;
        float ma = pml[wa][lr], mb = pml[wb][lr];
        float m = fmaxf(ma, mb);
        float s = psl[wa][lr] * __expf(ma - m) + psl[wb][lr] * __expf(mb - m);
        pm[(size_t)(m0 + tid) * 256 + blockIdx.y] = m;
        psum[(size_t)(m0 + tid) * 256 + blockIdx.y] = s;
    }
#pragma unroll
    for (int i = 0; i < 4; i++)
#pragma unroll
        for (int j = 0; j < 4; j++)
#pragma unroll
            for (int r = 0; r < 4; r++) {
                int row = m0 + wm + i * 16 + (lane >> 4) * 4 + r;
                int col = n0 + wn + j * 16 + (lane & 15);
                Out[(size_t)row * VOCAB + col] = acc[i][j][r];
            }
}

// ---------------- lse reduce ----------------
__global__ __launch_bounds__(64) void lse_kernel(const float* __restrict__ pm,
                                                 const float* __restrict__ psum,
                                                 float* __restrict__ lse) {
    const int row = blockIdx.x, t = threadIdx.x;
    float m = -1e30f, s = 0.f;
    for (int nb = t; nb < 250; nb += 64) {
        float mm = pm[(size_t)row * 256 + nb];
        float ss = psum[(size_t)row * 256 + nb];
        float M = fmaxf(m, mm);
        s = s * __expf(m - M) + ss * __expf(mm - M);
        m = M;
    }
#pragma unroll
    for (int off = 32; off > 0; off >>= 1) {
        float mo = __shfl_xor(m, off), so = __shfl_xor(s, off);
        float M = fmaxf(m, mo);
        s = s * __expf(m - M) + so * __expf(mo - M);
        m = M;
    }
    if (t == 0) lse[row] = m + __logf(s);
}

// ---------------- subtract lse ----------------
__global__ __launch_bounds__(256) void sub_kernel(float* __restrict__ out,
                                                  const float* __restrict__ lse) {
    const int row = blockIdx.x;
    const float l = lse[row];
    float4* p = (float4*)(out + (size_t)row * VOCAB);
    for (int i = threadIdx.x; i < VOCAB / 4; i += 256) {
        float4 v = p[i];
        p[i] = make_float4(v.x - l, v.y - l, v.z - l, v.w - l);
    }
}

// ---------------- orchestration ----------------
extern "C" void kernel_launch(void* const* d_in, const int* in_sizes, int n_in,
                              void* d_out, int out_size, void* d_ws, size_t ws_size,
                              hipStream_t stream) {
    const float* emb_src  = (const float*)d_in[0];
    const float* emb_tgt  = (const float*)d_in[1];
    const float* pos_emb  = (const float*)d_in[2];
    const float* time_emb = (const float*)d_in[3];
    const float* Wqkv_e   = (const float*)d_in[4];
    const float* Wo_e     = (const float*)d_in[5];
    const float* W1_e     = (const float*)d_in[6];
    const float* W2_e     = (const float*)d_in[7];
    const float* Wqkv_d   = (const float*)d_in[8];
    const float* Wo_d     = (const float*)d_in[9];
    const float* W1_d     = (const float*)d_in[10];
    const float* W2_d     = (const float*)d_in[11];
    const float* Wq_x     = (const float*)d_in[12];
    const float* Wkv_x    = (const float*)d_in[13];
    const float* Wo_x     = (const float*)d_in[14];
    const float* Wgen     = (const float*)d_in[15];
    const int* src_tokens = (const int*)d_in[16];
    const int* tgt_tokens = (const int*)d_in[17];
    const int* src_pos    = (const int*)d_in[18];
    const int* tgt_pos    = (const int*)d_in[19];

    char* w = (char*)d_ws;
    float* x_e = (float*)(w);                                     // 4MB
    float* x_d = (float*)(w + (4u << 20));                        // 4MB
    float* tmp = (float*)(w + (8u << 20));                        // 4MB
    unsigned short* kvx_bf = (unsigned short*)(w + (12u << 20));  // 4MB
    unsigned short* o_bf   = (unsigned short*)(w + (16u << 20));  // 2MB
    unsigned short* hid_bf = (unsigned short*)(w + (18u << 20));  // 8MB
    float* pm   = (float*)(w + (26u << 20));                      // 2MB
    float* psum = (float*)(w + (28u << 20));                      // 2MB
    float* lse  = (float*)(w + (30u << 20));                      // 8KB
    unsigned short* xe_bf = (unsigned short*)(w + (31u << 20));   // 2MB
    unsigned short* xd_bf = (unsigned short*)(w + (33u << 20));   // 2MB
    unsigned short* wts   = (unsigned short*)(w + (35u << 20));   // ~47.4MB

    unsigned short* WqkvE_t = wts;
    unsigned short* WoE_t   = WqkvE_t + 786432;
    unsigned short* W1E_t   = WoE_t   + 262144;
    unsigned short* W2E_t   = W1E_t   + 1048576;
    unsigned short* WqkvD_t = W2E_t   + 1048576;
    unsigned short* WoD_t   = WqkvD_t + 786432;
    unsigned short* W1D_t   = WoD_t   + 262144;
    unsigned short* W2D_t   = W1D_t   + 1048576;
    unsigned short* WqX_t   = W2D_t   + 1048576;
    unsigned short* WkvX_t  = WqX_t   + 262144;
    unsigned short* WoX_t   = WkvX_t  + 524288;
    unsigned short* Wgen_t  = WoX_t   + 262144;

    float* out = (float*)d_out;

    WTab tab;
    auto set = [&](int i, const float* s, unsigned short* d, int K, int N, int t0) {
        tab.d[i].src = s; tab.d[i].dst = d; tab.d[i].K = K; tab.d[i].N = N;
        tab.d[i].t0 = t0; tab.d[i].pad = 0;
    };
    set(0,  Wqkv_e, WqkvE_t, 512, 1536, 0);
    set(1,  Wo_e,   WoE_t,   512, 512,  768);
    set(2,  W1_e,   W1E_t,   512, 2048, 1024);
    set(3,  W2_e,   W2E_t,   2048, 512, 2048);
    set(4,  Wqkv_d, WqkvD_t, 512, 1536, 3072);
    set(5,  Wo_d,   WoD_t,   512, 512,  3840);
    set(6,  W1_d,   W1D_t,   512, 2048, 4096);
    set(7,  W2_d,   W2D_t,   2048, 512, 5120);
    set(8,  Wq_x,   WqX_t,   512, 512,  6144);
    set(9,  Wkv_x,  WkvX_t,  512, 1024, 6400);
    set(10, Wo_x,   WoX_t,   512, 512,  6912);
    set(11, Wgen,   Wgen_t,  512, 32000, 7168);
    wconv_all<<<23168, 256, 0, stream>>>(tab);

    const int n4 = NTOK * (DIM / 4);
    dim3 eb(256), eg((n4 + 255) / 256);
    embed_kernel<<<eg, eb, 0, stream>>>(emb_src, src_tokens, pos_emb, src_pos, x_e, n4);
    embed_kernel<<<eg, eb, 0, stream>>>(emb_tgt, tgt_tokens, pos_emb, tgt_pos, x_d, n4);

    const dim3 gFF(DFF / 128, NTOK / 128), gKV(1024 / 128, NTOK / 128),
               g64(512 / 64, NTOK / 64);

    // -------- encoder --------
    for (int t = 0; t < DEPTH; t++) {
        const float* trow = time_emb + (size_t)t * DIM;
        fused_attn<0><<<128, 512, 0, stream>>>(x_e, pos_emb, trow, WqkvE_t, o_bf);
        gemm_bb<<<g64, 256, 0, stream>>>(o_bf, WoE_t, x_e, tmp, NTOK, 512, 512);
        ln_kernel<<<NTOK, 64, 0, stream>>>(tmp, x_e, xe_bf);
        gemm_rb<1><<<gFF, 256, 0, stream>>>(xe_bf, W1E_t, hid_bf, NTOK, DFF, 512);
        gemm_bb<<<g64, 256, 0, stream>>>(hid_bf, W2E_t, x_e, tmp, NTOK, 512, 2048);
        ln_kernel<<<NTOK, 64, 0, stream>>>(tmp, x_e, xe_bf);
    }

    // cross-attn K/V from final encoder state (bf16 A)
    gemm_rb<3><<<gKV, 256, 0, stream>>>(xe_bf, WkvX_t, kvx_bf, NTOK, 1024, 512);

    // -------- decoder --------
    for (int t = 0; t < DEPTH; t++) {
        const float* trow = time_emb + (size_t)t * DIM;
        fused_attn<1><<<128, 512, 0, stream>>>(x_d, pos_emb, trow, WqkvD_t, o_bf);
        gemm_bb<<<g64, 256, 0, stream>>>(o_bf, WoD_t, x_d, tmp, NTOK, 512, 512);
        ln_kernel<<<NTOK, 64, 0, stream>>>(tmp, x_d, xd_bf);

        fused_xattn<<<128, 512, 0, stream>>>(x_d, pos_emb, trow, WqX_t, kvx_bf, o_bf);
        gemm_bb<<<g64, 256, 0, stream>>>(o_bf, WoX_t, x_d, tmp, NTOK, 512, 512);
        ln_kernel<<<NTOK, 64, 0, stream>>>(tmp, x_d, xd_bf);

        gemm_rb<1><<<gFF, 256, 0, stream>>>(xd_bf, W1D_t, hid_bf, NTOK, DFF, 512);
        gemm_bb<<<g64, 256, 0, stream>>>(hid_bf, W2D_t, x_d, tmp, NTOK, 512, 2048);
        ln_kernel<<<NTOK, 64, 0, stream>>>(tmp, x_d, xd_bf);
    }

    // -------- generator + log_softmax --------
    gemm_gen<<<dim3(16, 250), 256, 0, stream>>>(xd_bf, Wgen_t, out, pm, psum);
    lse_kernel<<<NTOK, 64, 0, stream>>>(pm, psum, lse);
    sub_kernel<<<NTOK, 256, 0, stream>>>(out, lse);
}